// Round 1
// baseline (697.990 us; speedup 1.0000x reference)
//
#include <hip/hip_runtime.h>
#include <math.h>

#define N_NODES 50000
#define N_EDGES 1600000
#define EA (N_EDGES + N_NODES)

// ---------------- GEMM: C[M][N] = A[M][128] * B[128][N] ----------------
template<int N>
__global__ void gemm_kernel(const float* __restrict__ A, const float* __restrict__ B,
                            float* __restrict__ C, int M) {
  constexpr int K  = 128;
  constexpr int BM = 64;
  constexpr int KB = 32;
  constexpr int TX = N / 4;          // threads along N (4 cols each)
  constexpr int TY = 256 / TX;
  constexpr int RPT = BM / TY;       // rows per thread
  __shared__ float As[BM][KB + 1];
  __shared__ float Bs[KB][N];
  const int t  = threadIdx.x;
  const int tx = t % TX, ty = t / TX;
  const int row0 = blockIdx.x * BM;

  float acc[RPT][4];
#pragma unroll
  for (int r = 0; r < RPT; ++r)
#pragma unroll
    for (int c = 0; c < 4; ++c) acc[r][c] = 0.f;

  for (int kc = 0; kc < K; kc += KB) {
    for (int i = t; i < BM * KB; i += 256) {
      int r = i / KB, c = i % KB;
      int gr = row0 + r;
      As[r][c] = (gr < M) ? A[gr * K + kc + c] : 0.f;
    }
    for (int i = t; i < KB * N; i += 256) {
      int r = i / N, c = i % N;
      Bs[r][c] = B[(kc + r) * N + c];
    }
    __syncthreads();
#pragma unroll
    for (int kk = 0; kk < KB; ++kk) {
      float b0 = Bs[kk][tx * 4 + 0], b1 = Bs[kk][tx * 4 + 1];
      float b2 = Bs[kk][tx * 4 + 2], b3 = Bs[kk][tx * 4 + 3];
#pragma unroll
      for (int r = 0; r < RPT; ++r) {
        float a = As[ty * RPT + r][kk];
        acc[r][0] += a * b0; acc[r][1] += a * b1;
        acc[r][2] += a * b2; acc[r][3] += a * b3;
      }
    }
    __syncthreads();
  }
  for (int r = 0; r < RPT; ++r) {
    int gr = row0 + ty * RPT + r;
    if (gr < M) {
      float4 v = make_float4(acc[r][0], acc[r][1], acc[r][2], acc[r][3]);
      *reinterpret_cast<float4*>(&C[gr * N + tx * 4]) = v;
    }
  }
}

// ------------- attention logits per node: al[n] = {src_h0, src_h1, dst_h0, dst_h1} -------------
__global__ void al1_kernel(const float* __restrict__ xp, const float* __restrict__ a_src,
                           const float* __restrict__ a_dst, float* __restrict__ al) {
  int wid = (blockIdx.x * blockDim.x + threadIdx.x) >> 6;
  int lane = threadIdx.x & 63;
  if (wid >= N_NODES) return;
  float x0 = xp[wid * 128 + lane];
  float x1 = xp[wid * 128 + 64 + lane];
  float s0 = x0 * a_src[lane];
  float s1 = x1 * a_src[64 + lane];
  float d0 = x0 * a_dst[lane];
  float d1 = x1 * a_dst[64 + lane];
  for (int off = 32; off >= 1; off >>= 1) {
    s0 += __shfl_xor(s0, off); s1 += __shfl_xor(s1, off);
    d0 += __shfl_xor(d0, off); d1 += __shfl_xor(d1, off);
  }
  if (lane == 0) {
    float4 v = make_float4(s0, s1, d0, d1);
    *reinterpret_cast<float4*>(&al[wid * 4]) = v;
  }
}

__global__ void al2_kernel(const float* __restrict__ xp, const float* __restrict__ a_src,
                           const float* __restrict__ a_dst, float* __restrict__ al) {
  int wid = (blockIdx.x * blockDim.x + threadIdx.x) >> 6;
  int lane = threadIdx.x & 63;
  if (wid >= N_NODES) return;
  int c = lane & 31;
  int head = lane >> 5;
  float x0 = xp[wid * 64 + lane];
  float s = x0 * a_src[head * 32 + c];
  float d = x0 * a_dst[head * 32 + c];
  for (int off = 16; off >= 1; off >>= 1) {
    s += __shfl_xor(s, off); d += __shfl_xor(d, off);
  }
  if ((lane & 31) == 0) {
    al[wid * 4 + head] = s;
    al[wid * 4 + 2 + head] = d;
  }
}

// ---------------- CSR build ----------------
__global__ void init_counts_kernel(int* __restrict__ counts) {
  int n = blockIdx.x * blockDim.x + threadIdx.x;
  if (n < N_NODES) counts[n] = 1;   // self loop
}

__global__ void hist_kernel(const int* __restrict__ dst, int* __restrict__ counts) {
  int e = blockIdx.x * blockDim.x + threadIdx.x;
  if (e < N_EDGES) atomicAdd(&counts[dst[e]], 1);
}

__global__ void scan_kernel(const int* __restrict__ counts, int* __restrict__ row_start, int n) {
  __shared__ int wsum[17];
  __shared__ int s_carry;
  const int t = threadIdx.x, lane = t & 63, wv = t >> 6;
  if (t == 0) s_carry = 0;
  __syncthreads();
  for (int base = 0; base < n; base += 1024) {
    int i = base + t;
    int v = (i < n) ? counts[i] : 0;
    int x = v;
    for (int off = 1; off < 64; off <<= 1) {
      int y = __shfl_up(x, off);
      if (lane >= off) x += y;
    }
    if (lane == 63) wsum[wv] = x;
    __syncthreads();
    if (t == 0) {
      int a = 0;
      for (int w = 0; w < 16; ++w) { int tp = wsum[w]; wsum[w] = a; a += tp; }
      wsum[16] = a;
    }
    __syncthreads();
    int excl = s_carry + wsum[wv] + x - v;
    if (i < n) row_start[i] = excl;
    __syncthreads();
    if (t == 0) s_carry += wsum[16];
    __syncthreads();
  }
  if (t == 0) row_start[n] = s_carry;
}

__global__ void place_self_kernel(const int* __restrict__ row_start, int* __restrict__ cursor,
                                  int* __restrict__ sorted_src) {
  int n = blockIdx.x * blockDim.x + threadIdx.x;
  if (n < N_NODES) {
    int rs = row_start[n];
    sorted_src[rs] = n;       // self loop first
    cursor[n] = rs + 1;
  }
}

__global__ void scatter_kernel(const int* __restrict__ src, const int* __restrict__ dst,
                               int* __restrict__ cursor, int* __restrict__ sorted_src) {
  int e = blockIdx.x * blockDim.x + threadIdx.x;
  if (e < N_EDGES) {
    int pos = atomicAdd(&cursor[dst[e]], 1);
    sorted_src[pos] = src[e];
  }
}

// ---------------- segment softmax + aggregate, one wave per dst node ----------------
template<int HC>
__global__ void agg_kernel(const float* __restrict__ xp, const float* __restrict__ al,
                           const int* __restrict__ row_start, const int* __restrict__ sorted_src,
                           const float* __restrict__ bias, float* __restrict__ out) {
  int wid = (blockIdx.x * blockDim.x + threadIdx.x) >> 6;
  int lane = threadIdx.x & 63;
  if (wid >= N_NODES) return;
  const int start = row_start[wid], end = row_start[wid + 1];
  const float ad0 = al[wid * 4 + 2], ad1 = al[wid * 4 + 3];

  // pass 1: segment max
  float m0 = -1e30f, m1 = -1e30f;
  for (int i = start + lane; i < end; i += 64) {
    int s = sorted_src[i];
    float4 a = *reinterpret_cast<const float4*>(&al[s * 4]);
    float l0 = a.x + ad0, l1 = a.y + ad1;
    l0 = l0 > 0.f ? l0 : 0.2f * l0;
    l1 = l1 > 0.f ? l1 : 0.2f * l1;
    m0 = fmaxf(m0, l0); m1 = fmaxf(m1, l1);
  }
  for (int off = 32; off >= 1; off >>= 1) {
    m0 = fmaxf(m0, __shfl_xor(m0, off));
    m1 = fmaxf(m1, __shfl_xor(m1, off));
  }
  // pass 2: denom
  float d0 = 0.f, d1 = 0.f;
  for (int i = start + lane; i < end; i += 64) {
    int s = sorted_src[i];
    float4 a = *reinterpret_cast<const float4*>(&al[s * 4]);
    float l0 = a.x + ad0, l1 = a.y + ad1;
    l0 = l0 > 0.f ? l0 : 0.2f * l0;
    l1 = l1 > 0.f ? l1 : 0.2f * l1;
    d0 += __expf(l0 - m0); d1 += __expf(l1 - m1);
  }
  for (int off = 32; off >= 1; off >>= 1) {
    d0 += __shfl_xor(d0, off); d1 += __shfl_xor(d1, off);
  }
  const float inv0 = 1.f / d0, inv1 = 1.f / d1;

  // pass 3: aggregate
  const int head = lane >> 5;
  const float mh = head ? m1 : m0;
  const float invh = head ? inv1 : inv0;
  const float adh = head ? ad1 : ad0;
  if (HC == 128) {
    float acc0 = 0.f, acc1 = 0.f;
    for (int i = start; i < end; ++i) {
      int s = sorted_src[i];
      float alv = al[s * 4 + head] + adh;
      alv = alv > 0.f ? alv : 0.2f * alv;
      float alpha = __expf(alv - mh) * invh;
      float2 v = *reinterpret_cast<const float2*>(&xp[s * 128 + lane * 2]);
      acc0 += alpha * v.x; acc1 += alpha * v.y;
    }
    float o0 = acc0 + bias[lane * 2];
    float o1 = acc1 + bias[lane * 2 + 1];
    o0 = o0 > 0.f ? o0 : __expf(o0) - 1.f;   // elu
    o1 = o1 > 0.f ? o1 : __expf(o1) - 1.f;
    *reinterpret_cast<float2*>(&out[wid * 128 + lane * 2]) = make_float2(o0, o1);
  } else {
    float acc = 0.f;
    for (int i = start; i < end; ++i) {
      int s = sorted_src[i];
      float alv = al[s * 4 + head] + adh;
      alv = alv > 0.f ? alv : 0.2f * alv;
      float alpha = __expf(alv - mh) * invh;
      acc += alpha * xp[s * 64 + lane];
    }
    float o = acc + bias[lane];
    o = o > 0.f ? o : __expf(o) - 1.f;       // elu
    out[wid * 64 + lane] = o;
  }
}

__global__ void copy4_kernel(const float4* __restrict__ in, float4* __restrict__ out, int n4) {
  int i = blockIdx.x * blockDim.x + threadIdx.x;
  if (i < n4) out[i] = in[i];
}

extern "C" void kernel_launch(void* const* d_in, const int* in_sizes, int n_in,
                              void* d_out, int out_size, void* d_ws, size_t ws_size,
                              hipStream_t stream) {
  const float* x      = (const float*)d_in[0];
  const int*   ei     = (const int*)d_in[1];
  const float* W1     = (const float*)d_in[2];
  const float* a_src1 = (const float*)d_in[3];
  const float* a_dst1 = (const float*)d_in[4];
  const float* b1     = (const float*)d_in[5];
  const float* W2     = (const float*)d_in[6];
  const float* a_src2 = (const float*)d_in[7];
  const float* a_dst2 = (const float*)d_in[8];
  const float* b2     = (const float*)d_in[9];
  float* out = (float*)d_out;

  char* ws = (char*)d_ws;
  size_t off = 0;
  auto alloc = [&](size_t bytes) {
    void* p = ws + off;
    off = (off + bytes + 255) & ~(size_t)255;
    return p;
  };
  float* xp1        = (float*)alloc((size_t)N_NODES * 128 * 4);
  float* h1         = (float*)alloc((size_t)N_NODES * 128 * 4);
  float* al1        = (float*)alloc((size_t)N_NODES * 4 * 4);
  float* al2        = (float*)alloc((size_t)N_NODES * 4 * 4);
  int*   counts     = (int*)alloc((size_t)N_NODES * 4);          // reused as cursor
  int*   row_start  = (int*)alloc((size_t)(N_NODES + 1) * 4);
  int*   sorted_src = (int*)alloc((size_t)EA * 4);
  float* xp2        = xp1;   // alias: xp1 dead after agg1

  const int* src = ei;
  const int* dst = ei + N_EDGES;

  const int nodeBlocks  = (N_NODES + 255) / 256;
  const int edgeBlocks  = (N_EDGES + 255) / 256;
  const int waveBlocks  = (N_NODES * 64) / 256;   // one wave per node, 256-thread blocks

  // ---- CSR by destination (shared by both layers) ----
  init_counts_kernel<<<nodeBlocks, 256, 0, stream>>>(counts);
  hist_kernel<<<edgeBlocks, 256, 0, stream>>>(dst, counts);
  scan_kernel<<<1, 1024, 0, stream>>>(counts, row_start, N_NODES);
  place_self_kernel<<<nodeBlocks, 256, 0, stream>>>(row_start, counts, sorted_src);
  scatter_kernel<<<edgeBlocks, 256, 0, stream>>>(src, dst, counts, sorted_src);

  // ---- layer 1 ----
  gemm_kernel<128><<<(N_NODES + 63) / 64, 256, 0, stream>>>(x, W1, xp1, N_NODES);
  al1_kernel<<<waveBlocks, 256, 0, stream>>>(xp1, a_src1, a_dst1, al1);
  agg_kernel<128><<<waveBlocks, 256, 0, stream>>>(xp1, al1, row_start, sorted_src, b1, h1);

  // ---- layer 2 ----
  gemm_kernel<64><<<(N_NODES + 63) / 64, 256, 0, stream>>>(h1, W2, xp2, N_NODES);
  al2_kernel<<<waveBlocks, 256, 0, stream>>>(xp2, a_src2, a_dst2, al2);
  agg_kernel<64><<<waveBlocks, 256, 0, stream>>>(xp2, al2, row_start, sorted_src, b2, out);

  // ---- encoded passthrough ----
  copy4_kernel<<<((N_NODES * 128 / 4) + 255) / 256, 256, 0, stream>>>(
      (const float4*)x, (float4*)(out + (size_t)N_NODES * 64), N_NODES * 128 / 4);
}

// Round 2
// 414.082 us; speedup vs baseline: 1.6856x; 1.6856x over previous
//
#include <hip/hip_runtime.h>
#include <math.h>

#define N_NODES 50000
#define N_EDGES 1600000
#define EA (N_EDGES + N_NODES)
#define MAXD 128

typedef unsigned int uint32;
typedef unsigned short ushort16;

__device__ inline ushort f2bf(float f) {
  uint32 u = __float_as_uint(f);
  u += 0x7fffu + ((u >> 16) & 1u);
  return (ushort)(u >> 16);
}
__device__ inline float blo(uint32 v) { return __uint_as_float(v << 16); }
__device__ inline float bhi(uint32 v) { return __uint_as_float(v & 0xffff0000u); }

// ---------------- GEMM + fused attention-logit epilogue ----------------
// C (bf16) [M][N] = A[M][128] * B[128][N];  al[n] = {src_h0,src_h1,dst_h0,dst_h1}
template<int N>
__global__ void gemm_al_kernel(const float* __restrict__ A, const float* __restrict__ B,
                               const float* __restrict__ asrc, const float* __restrict__ adst,
                               ushort* __restrict__ Cb, float* __restrict__ al, int M) {
  constexpr int K  = 128;
  constexpr int BM = 64;
  constexpr int KB = 32;
  constexpr int TX = N / 4;          // threads along N (4 cols each)
  constexpr int TY = 256 / TX;
  constexpr int RPT = BM / TY;       // rows per thread
  constexpr int RW = N / 8;          // threads per head group (16 or 8)
  __shared__ float As[BM][KB + 1];
  __shared__ float Bs[KB][N];
  const int t  = threadIdx.x;
  const int tx = t % TX, ty = t / TX;
  const int row0 = blockIdx.x * BM;

  float acc[RPT][4];
#pragma unroll
  for (int r = 0; r < RPT; ++r)
#pragma unroll
    for (int c = 0; c < 4; ++c) acc[r][c] = 0.f;

  for (int kc = 0; kc < K; kc += KB) {
    for (int i = t; i < BM * KB; i += 256) {
      int r = i / KB, c = i % KB;
      int gr = row0 + r;
      As[r][c] = (gr < M) ? A[gr * K + kc + c] : 0.f;
    }
    for (int i = t; i < KB * N; i += 256) {
      int r = i / N, c = i % N;
      Bs[r][c] = B[(kc + r) * N + c];
    }
    __syncthreads();
#pragma unroll
    for (int kk = 0; kk < KB; ++kk) {
      float b0 = Bs[kk][tx * 4 + 0], b1 = Bs[kk][tx * 4 + 1];
      float b2 = Bs[kk][tx * 4 + 2], b3 = Bs[kk][tx * 4 + 3];
#pragma unroll
      for (int r = 0; r < RPT; ++r) {
        float a = As[ty * RPT + r][kk];
        acc[r][0] += a * b0; acc[r][1] += a * b1;
        acc[r][2] += a * b2; acc[r][3] += a * b3;
      }
    }
    __syncthreads();
  }

  const int hd = tx / RW;
  float4 as4 = *reinterpret_cast<const float4*>(asrc + tx * 4);
  float4 ad4 = *reinterpret_cast<const float4*>(adst + tx * 4);
#pragma unroll
  for (int r = 0; r < RPT; ++r) {
    int gr = row0 + ty * RPT + r;
    float ps = acc[r][0] * as4.x + acc[r][1] * as4.y + acc[r][2] * as4.z + acc[r][3] * as4.w;
    float pd = acc[r][0] * ad4.x + acc[r][1] * ad4.y + acc[r][2] * ad4.z + acc[r][3] * ad4.w;
#pragma unroll
    for (int off = RW / 2; off >= 1; off >>= 1) {
      ps += __shfl_xor(ps, off);
      pd += __shfl_xor(pd, off);
    }
    if (gr < M) {
      ushort4 ub;
      ub.x = f2bf(acc[r][0]); ub.y = f2bf(acc[r][1]);
      ub.z = f2bf(acc[r][2]); ub.w = f2bf(acc[r][3]);
      *reinterpret_cast<ushort4*>(&Cb[(size_t)gr * N + tx * 4]) = ub;
      if ((tx & (RW - 1)) == 0) {
        al[gr * 4 + hd] = ps;
        al[gr * 4 + 2 + hd] = pd;
      }
    }
  }
}

// ---------------- CSR build ----------------
__global__ void init_counts_kernel(int* __restrict__ counts) {
  int n = blockIdx.x * blockDim.x + threadIdx.x;
  if (n < N_NODES) counts[n] = 1;   // self loop
}

__global__ void hist_kernel(const int* __restrict__ dst, int* __restrict__ counts) {
  int e = blockIdx.x * blockDim.x + threadIdx.x;
  if (e < N_EDGES) atomicAdd(&counts[dst[e]], 1);
}

__global__ void scanA_kernel(const int* __restrict__ counts, int* __restrict__ row_start,
                             int* __restrict__ bsum, int n) {
  __shared__ int wsh[4];
  const int t = threadIdx.x, lane = t & 63, wv = t >> 6;
  int i = blockIdx.x * 256 + t;
  int v = (i < n) ? counts[i] : 0;
  int x = v;
  for (int off = 1; off < 64; off <<= 1) {
    int y = __shfl_up(x, off);
    if (lane >= off) x += y;
  }
  if (lane == 63) wsh[wv] = x;
  __syncthreads();
  int wo = 0;
  for (int w = 0; w < wv; ++w) wo += wsh[w];
  if (i < n) row_start[i] = wo + x - v;
  if (t == 255) bsum[blockIdx.x] = wo + x;
}

__global__ void scanB_kernel(const int* __restrict__ bsum, int* __restrict__ boff,
                             int nb, int* __restrict__ total_out) {
  __shared__ int wsh[4];
  const int t = threadIdx.x, lane = t & 63, wv = t >> 6;
  int v = (t < nb) ? bsum[t] : 0;
  int x = v;
  for (int off = 1; off < 64; off <<= 1) {
    int y = __shfl_up(x, off);
    if (lane >= off) x += y;
  }
  if (lane == 63) wsh[wv] = x;
  __syncthreads();
  int wo = 0;
  for (int w = 0; w < wv; ++w) wo += wsh[w];
  if (t < nb) boff[t] = wo + x - v;
  if (t == 255) total_out[0] = wo + x;
}

__global__ void scanC_kernel(int* __restrict__ row_start, const int* __restrict__ boff, int n) {
  int i = blockIdx.x * 256 + threadIdx.x;
  if (i < n) row_start[i] += boff[blockIdx.x];
}

__global__ void place_self_kernel(const int* __restrict__ row_start, int* __restrict__ cursor,
                                  int* __restrict__ sorted_src) {
  int n = blockIdx.x * blockDim.x + threadIdx.x;
  if (n < N_NODES) {
    int rs = row_start[n];
    sorted_src[rs] = n;       // self loop first
    cursor[n] = rs + 1;
  }
}

__global__ void scatter_kernel(const int* __restrict__ src, const int* __restrict__ dst,
                               int* __restrict__ cursor, int* __restrict__ sorted_src) {
  int e = blockIdx.x * blockDim.x + threadIdx.x;
  if (e < N_EDGES) {
    int pos = atomicAdd(&cursor[dst[e]], 1);
    sorted_src[pos] = src[e];
  }
}

// ---------------- segment softmax + aggregate, one wave per dst node ----------------
template<int HC>
__global__ void agg_kernel(const ushort* __restrict__ xb, const float* __restrict__ al,
                           const int* __restrict__ row_start, const int* __restrict__ sorted_src,
                           const float* __restrict__ bias, float* __restrict__ out) {
  __shared__ float2 eL[4][MAXD];
  __shared__ int    sL[4][MAXD];
  const int wid = (blockIdx.x * blockDim.x + threadIdx.x) >> 6;
  const int lane = threadIdx.x & 63;
  const int wv = (threadIdx.x >> 6) & 3;
  if (wid >= N_NODES) return;
  const float4* al4 = (const float4*)al;
  const uint32* xb32 = (const uint32*)xb;
  const int start = row_start[wid], end = row_start[wid + 1], deg = end - start;
  float4 mya = al4[wid];
  const float ad0 = mya.z, ad1 = mya.w;

  float m0 = -1e30f, m1 = -1e30f;
  float d0 = 0.f, d1 = 0.f;
  float acc0 = 0.f, acc1 = 0.f;
  const int c = lane & 31, hh = lane >> 5;            // HC==64 mapping
  const int head64 = c >> 4;                          // head for cols 2c,2c+1
  const int head128 = lane >> 5;                      // head for cols 2*lane, 2*lane+1

  if (deg <= MAXD) {
    // pass 1: leaky logits + segment max, stage src ids + logits in LDS
    for (int i = start + lane; i < end; i += 64) {
      int s = sorted_src[i];
      float4 a = al4[s];
      float l0 = a.x + ad0; l0 = l0 > 0.f ? l0 : 0.2f * l0;
      float l1 = a.y + ad1; l1 = l1 > 0.f ? l1 : 0.2f * l1;
      int j = i - start;
      sL[wv][j] = s;
      eL[wv][j] = make_float2(l0, l1);
      m0 = fmaxf(m0, l0); m1 = fmaxf(m1, l1);
    }
    for (int off = 32; off >= 1; off >>= 1) {
      m0 = fmaxf(m0, __shfl_xor(m0, off));
      m1 = fmaxf(m1, __shfl_xor(m1, off));
    }
    // pass 2: exp + denom, overwrite LDS logits with exp values
    for (int i = start + lane; i < end; i += 64) {
      int j = i - start;
      float2 l = eL[wv][j];
      float e0 = __expf(l.x - m0), e1 = __expf(l.y - m1);
      eL[wv][j] = make_float2(e0, e1);
      d0 += e0; d1 += e1;
    }
    for (int off = 32; off >= 1; off >>= 1) {
      d0 += __shfl_xor(d0, off);
      d1 += __shfl_xor(d1, off);
    }
    const float inv0 = 1.f / d0, inv1 = 1.f / d1;
    // pass 3: weighted gather of bf16 rows
    if (HC == 128) {
      const float invh = head128 ? inv1 : inv0;
      int j = 0;
      for (; j + 2 <= deg; j += 2) {
        int s0 = sL[wv][j], s1 = sL[wv][j + 1];
        uint32 v0 = xb32[(size_t)s0 * 64 + lane];
        uint32 v1 = xb32[(size_t)s1 * 64 + lane];
        float2 e0 = eL[wv][j], e1 = eL[wv][j + 1];
        float a0 = (head128 ? e0.y : e0.x) * invh;
        float a1 = (head128 ? e1.y : e1.x) * invh;
        acc0 = fmaf(a0, blo(v0), fmaf(a1, blo(v1), acc0));
        acc1 = fmaf(a0, bhi(v0), fmaf(a1, bhi(v1), acc1));
      }
      if (j < deg) {
        int s0 = sL[wv][j];
        uint32 v0 = xb32[(size_t)s0 * 64 + lane];
        float2 e0 = eL[wv][j];
        float a0 = (head128 ? e0.y : e0.x) * invh;
        acc0 = fmaf(a0, blo(v0), acc0);
        acc1 = fmaf(a0, bhi(v0), acc1);
      }
    } else {
      // half-wave pair: half hh handles edges j+hh
      const float invh = head64 ? inv1 : inv0;
      for (int j = 0; j < deg; j += 2) {
        int jj = j + hh;
        float a0 = 0.f; uint32 v0 = 0;
        if (jj < deg) {
          int s = sL[wv][jj];
          v0 = xb32[(size_t)s * 32 + c];
          float2 e = eL[wv][jj];
          a0 = (head64 ? e.y : e.x) * invh;
        }
        acc0 = fmaf(a0, blo(v0), acc0);
        acc1 = fmaf(a0, bhi(v0), acc1);
      }
    }
  } else {
    // ----- fallback: deg > MAXD, recompute everything -----
    for (int i = start + lane; i < end; i += 64) {
      int s = sorted_src[i];
      float4 a = al4[s];
      float l0 = a.x + ad0; l0 = l0 > 0.f ? l0 : 0.2f * l0;
      float l1 = a.y + ad1; l1 = l1 > 0.f ? l1 : 0.2f * l1;
      m0 = fmaxf(m0, l0); m1 = fmaxf(m1, l1);
    }
    for (int off = 32; off >= 1; off >>= 1) {
      m0 = fmaxf(m0, __shfl_xor(m0, off));
      m1 = fmaxf(m1, __shfl_xor(m1, off));
    }
    for (int i = start + lane; i < end; i += 64) {
      int s = sorted_src[i];
      float4 a = al4[s];
      float l0 = a.x + ad0; l0 = l0 > 0.f ? l0 : 0.2f * l0;
      float l1 = a.y + ad1; l1 = l1 > 0.f ? l1 : 0.2f * l1;
      d0 += __expf(l0 - m0); d1 += __expf(l1 - m1);
    }
    for (int off = 32; off >= 1; off >>= 1) {
      d0 += __shfl_xor(d0, off);
      d1 += __shfl_xor(d1, off);
    }
    const float inv0 = 1.f / d0, inv1 = 1.f / d1;
    if (HC == 128) {
      const float invh = head128 ? inv1 : inv0;
      const float mh = head128 ? m1 : m0;
      const float adh = head128 ? ad1 : ad0;
      for (int i = start; i < end; ++i) {
        int s = sorted_src[i];
        float lv = al[s * 4 + head128] + adh;
        lv = lv > 0.f ? lv : 0.2f * lv;
        float a0 = __expf(lv - mh) * invh;
        uint32 v0 = xb32[(size_t)s * 64 + lane];
        acc0 = fmaf(a0, blo(v0), acc0);
        acc1 = fmaf(a0, bhi(v0), acc1);
      }
    } else {
      const float invh = head64 ? inv1 : inv0;
      const float mh = head64 ? m1 : m0;
      const float adh = head64 ? ad1 : ad0;
      for (int j = 0; j < deg; j += 2) {
        int jj = j + hh;
        float a0 = 0.f; uint32 v0 = 0;
        if (jj < deg) {
          int s = sorted_src[start + jj];
          float lv = al[s * 4 + head64] + adh;
          lv = lv > 0.f ? lv : 0.2f * lv;
          a0 = __expf(lv - mh) * invh;
          v0 = xb32[(size_t)s * 32 + c];
        }
        acc0 = fmaf(a0, blo(v0), acc0);
        acc1 = fmaf(a0, bhi(v0), acc1);
      }
    }
  }

  // ---- epilogue: bias + ELU + store ----
  if (HC == 128) {
    float o0 = acc0 + bias[lane * 2];
    float o1 = acc1 + bias[lane * 2 + 1];
    o0 = o0 > 0.f ? o0 : __expf(o0) - 1.f;
    o1 = o1 > 0.f ? o1 : __expf(o1) - 1.f;
    *reinterpret_cast<float2*>(&out[(size_t)wid * 128 + lane * 2]) = make_float2(o0, o1);
  } else {
    acc0 += __shfl_xor(acc0, 32);
    acc1 += __shfl_xor(acc1, 32);
    if (hh == 0) {
      float o0 = acc0 + bias[c * 2];
      float o1 = acc1 + bias[c * 2 + 1];
      o0 = o0 > 0.f ? o0 : __expf(o0) - 1.f;
      o1 = o1 > 0.f ? o1 : __expf(o1) - 1.f;
      *reinterpret_cast<float2*>(&out[(size_t)wid * 64 + c * 2]) = make_float2(o0, o1);
    }
  }
}

__global__ void copy4_kernel(const float4* __restrict__ in, float4* __restrict__ out, int n4) {
  int i = blockIdx.x * blockDim.x + threadIdx.x;
  if (i < n4) out[i] = in[i];
}

extern "C" void kernel_launch(void* const* d_in, const int* in_sizes, int n_in,
                              void* d_out, int out_size, void* d_ws, size_t ws_size,
                              hipStream_t stream) {
  const float* x      = (const float*)d_in[0];
  const int*   ei     = (const int*)d_in[1];
  const float* W1     = (const float*)d_in[2];
  const float* a_src1 = (const float*)d_in[3];
  const float* a_dst1 = (const float*)d_in[4];
  const float* b1     = (const float*)d_in[5];
  const float* W2     = (const float*)d_in[6];
  const float* a_src2 = (const float*)d_in[7];
  const float* a_dst2 = (const float*)d_in[8];
  const float* b2     = (const float*)d_in[9];
  float* out = (float*)d_out;

  char* ws = (char*)d_ws;
  size_t off = 0;
  auto alloc = [&](size_t bytes) {
    void* p = ws + off;
    off = (off + bytes + 255) & ~(size_t)255;
    return p;
  };
  ushort* xb1       = (ushort*)alloc((size_t)N_NODES * 128 * 2);
  float*  h1        = (float*)alloc((size_t)N_NODES * 128 * 4);
  ushort* xb2       = (ushort*)alloc((size_t)N_NODES * 64 * 2);
  float*  al1       = (float*)alloc((size_t)N_NODES * 4 * 4);
  float*  al2       = (float*)alloc((size_t)N_NODES * 4 * 4);
  int*    counts    = (int*)alloc((size_t)N_NODES * 4);          // reused as cursor
  int*    row_start = (int*)alloc((size_t)(N_NODES + 1) * 4);
  int*    bsum      = (int*)alloc(256 * 4);
  int*    boff      = (int*)alloc(256 * 4);
  int*    sorted_src= (int*)alloc((size_t)EA * 4);

  const int* src = ei;
  const int* dst = ei + N_EDGES;

  const int nodeBlocks = (N_NODES + 255) / 256;   // 196
  const int edgeBlocks = (N_EDGES + 255) / 256;
  const int waveBlocks = (N_NODES * 64) / 256;    // one wave per node

  // ---- CSR by destination (shared by both layers) ----
  init_counts_kernel<<<nodeBlocks, 256, 0, stream>>>(counts);
  hist_kernel<<<edgeBlocks, 256, 0, stream>>>(dst, counts);
  scanA_kernel<<<nodeBlocks, 256, 0, stream>>>(counts, row_start, bsum, N_NODES);
  scanB_kernel<<<1, 256, 0, stream>>>(bsum, boff, nodeBlocks, &row_start[N_NODES]);
  scanC_kernel<<<nodeBlocks, 256, 0, stream>>>(row_start, boff, N_NODES);
  place_self_kernel<<<nodeBlocks, 256, 0, stream>>>(row_start, counts, sorted_src);
  scatter_kernel<<<edgeBlocks, 256, 0, stream>>>(src, dst, counts, sorted_src);

  // ---- layer 1 ----
  gemm_al_kernel<128><<<(N_NODES + 63) / 64, 256, 0, stream>>>(x, W1, a_src1, a_dst1, xb1, al1, N_NODES);
  agg_kernel<128><<<waveBlocks, 256, 0, stream>>>(xb1, al1, row_start, sorted_src, b1, h1);

  // ---- layer 2 ----
  gemm_al_kernel<64><<<(N_NODES + 63) / 64, 256, 0, stream>>>(h1, W2, a_src2, a_dst2, xb2, al2, N_NODES);
  agg_kernel<64><<<waveBlocks, 256, 0, stream>>>(xb2, al2, row_start, sorted_src, b2, out);

  // ---- encoded passthrough ----
  copy4_kernel<<<((N_NODES * 128 / 4) + 255) / 256, 256, 0, stream>>>(
      (const float4*)x, (float4*)(out + (size_t)N_NODES * 64), N_NODES * 128 / 4);
}

// Round 3
// 350.021 us; speedup vs baseline: 1.9941x; 1.1830x over previous
//
#include <hip/hip_runtime.h>
#include <math.h>

#define N_NODES 50000
#define N_EDGES 1600000
#define EA (N_EDGES + N_NODES)
#define MAXD 128
#define NBUCK 196         // ceil(N_NODES / 256)
#define EPB 8192          // edges per workgroup in partition pass

typedef unsigned int uint32;

__device__ inline ushort f2bf(float f) {
  uint32 u = __float_as_uint(f);
  u += 0x7fffu + ((u >> 16) & 1u);
  return (ushort)(u >> 16);
}
__device__ inline float blo(uint32 v) { return __uint_as_float(v << 16); }
__device__ inline float bhi(uint32 v) { return __uint_as_float(v & 0xffff0000u); }

// ---------------- GEMM + fused attention-logit epilogue ----------------
template<int N>
__global__ void gemm_al_kernel(const float* __restrict__ A, const float* __restrict__ B,
                               const float* __restrict__ asrc, const float* __restrict__ adst,
                               ushort* __restrict__ Cb, float* __restrict__ al, int M) {
  constexpr int K  = 128;
  constexpr int BM = 64;
  constexpr int KB = 32;
  constexpr int TX = N / 4;
  constexpr int TY = 256 / TX;
  constexpr int RPT = BM / TY;
  constexpr int RW = N / 8;          // threads per head group
  __shared__ float As[BM][KB + 1];
  __shared__ float Bs[KB][N];
  const int t  = threadIdx.x;
  const int tx = t % TX, ty = t / TX;
  const int row0 = blockIdx.x * BM;

  float acc[RPT][4];
#pragma unroll
  for (int r = 0; r < RPT; ++r)
#pragma unroll
    for (int c = 0; c < 4; ++c) acc[r][c] = 0.f;

  for (int kc = 0; kc < K; kc += KB) {
    for (int i = t; i < BM * KB; i += 256) {
      int r = i / KB, c = i % KB;
      int gr = row0 + r;
      As[r][c] = (gr < M) ? A[gr * K + kc + c] : 0.f;
    }
    for (int i = t; i < KB * N; i += 256) {
      int r = i / N, c = i % N;
      Bs[r][c] = B[(kc + r) * N + c];
    }
    __syncthreads();
#pragma unroll
    for (int kk = 0; kk < KB; ++kk) {
      float b0 = Bs[kk][tx * 4 + 0], b1 = Bs[kk][tx * 4 + 1];
      float b2 = Bs[kk][tx * 4 + 2], b3 = Bs[kk][tx * 4 + 3];
#pragma unroll
      for (int r = 0; r < RPT; ++r) {
        float a = As[ty * RPT + r][kk];
        acc[r][0] += a * b0; acc[r][1] += a * b1;
        acc[r][2] += a * b2; acc[r][3] += a * b3;
      }
    }
    __syncthreads();
  }

  const int hd = tx / RW;
  float4 as4 = *reinterpret_cast<const float4*>(asrc + tx * 4);
  float4 ad4 = *reinterpret_cast<const float4*>(adst + tx * 4);
#pragma unroll
  for (int r = 0; r < RPT; ++r) {
    int gr = row0 + ty * RPT + r;
    float ps = acc[r][0] * as4.x + acc[r][1] * as4.y + acc[r][2] * as4.z + acc[r][3] * as4.w;
    float pd = acc[r][0] * ad4.x + acc[r][1] * ad4.y + acc[r][2] * ad4.z + acc[r][3] * ad4.w;
#pragma unroll
    for (int off = RW / 2; off >= 1; off >>= 1) {
      ps += __shfl_xor(ps, off);
      pd += __shfl_xor(pd, off);
    }
    if (gr < M) {
      ushort4 ub;
      ub.x = f2bf(acc[r][0]); ub.y = f2bf(acc[r][1]);
      ub.z = f2bf(acc[r][2]); ub.w = f2bf(acc[r][3]);
      *reinterpret_cast<ushort4*>(&Cb[(size_t)gr * N + tx * 4]) = ub;
      if ((tx & (RW - 1)) == 0) {
        al[gr * 4 + hd] = ps;
        al[gr * 4 + 2 + hd] = pd;
      }
    }
  }
}

// ---------------- CSR build ----------------
__global__ void init_counts_kernel(int* __restrict__ counts) {
  int n = blockIdx.x * blockDim.x + threadIdx.x;
  if (n < N_NODES) counts[n] = 1;   // self loop
}

__global__ void hist_kernel(const int* __restrict__ dst, int* __restrict__ counts) {
  int e = blockIdx.x * blockDim.x + threadIdx.x;
  if (e < N_EDGES) atomicAdd(&counts[dst[e]], 1);
}

__global__ void scanA_kernel(const int* __restrict__ counts, int* __restrict__ row_start,
                             int* __restrict__ bsum, int n) {
  __shared__ int wsh[4];
  const int t = threadIdx.x, lane = t & 63, wv = t >> 6;
  int i = blockIdx.x * 256 + t;
  int v = (i < n) ? counts[i] : 0;
  int x = v;
  for (int off = 1; off < 64; off <<= 1) {
    int y = __shfl_up(x, off);
    if (lane >= off) x += y;
  }
  if (lane == 63) wsh[wv] = x;
  __syncthreads();
  int wo = 0;
  for (int w = 0; w < wv; ++w) wo += wsh[w];
  if (i < n) row_start[i] = wo + x - v;
  if (t == 255) bsum[blockIdx.x] = wo + x;
}

__global__ void scanB_kernel(const int* __restrict__ bsum, int* __restrict__ boff,
                             int nb, int* __restrict__ total_out) {
  __shared__ int wsh[4];
  const int t = threadIdx.x, lane = t & 63, wv = t >> 6;
  int v = (t < nb) ? bsum[t] : 0;
  int x = v;
  for (int off = 1; off < 64; off <<= 1) {
    int y = __shfl_up(x, off);
    if (lane >= off) x += y;
  }
  if (lane == 63) wsh[wv] = x;
  __syncthreads();
  int wo = 0;
  for (int w = 0; w < wv; ++w) wo += wsh[w];
  if (t < nb) boff[t] = wo + x - v;
  if (t == 255) total_out[0] = wo + x;
}

__global__ void scanC_kernel(int* __restrict__ row_start, const int* __restrict__ boff, int n) {
  int i = blockIdx.x * 256 + threadIdx.x;
  if (i < n) row_start[i] += boff[blockIdx.x];
}

// bucket slice cursors: ebase[b] = row_start[256b] - 256b
__global__ void bucket_base_kernel(const int* __restrict__ row_start, int* __restrict__ bcur) {
  int b = blockIdx.x * blockDim.x + threadIdx.x;
  if (b < NBUCK) {
    int nb = b * 256; if (nb > N_NODES) nb = N_NODES;
    bcur[b] = row_start[nb] - nb;
  }
}

// ---- Pass A: partition edges into 196 coarse buckets (coalesced writes) ----
__global__ void partA_kernel(const int* __restrict__ src, const int* __restrict__ dst,
                             int* __restrict__ bcur, uint32* __restrict__ ebuf) {
  __shared__ int h[NBUCK];
  __shared__ int lo[NBUCK + 1];
  __shared__ int rank_[NBUCK];
  __shared__ int gbase[NBUCK];
  __shared__ uint32 staged[EPB];
  const int t = threadIdx.x;
  const int e0 = blockIdx.x * EPB;
  const int ne = min(EPB, N_EDGES - e0);

  for (int i = t; i < NBUCK; i += 256) h[i] = 0;
  __syncthreads();
  for (int i = t; i < ne; i += 256) {
    int d = dst[e0 + i];
    atomicAdd(&h[d >> 8], 1);
  }
  __syncthreads();
  if (t == 0) {
    int a = 0;
    for (int b = 0; b < NBUCK; ++b) { lo[b] = a; a += h[b]; }
    lo[NBUCK] = a;
  }
  __syncthreads();
  for (int i = t; i < NBUCK; i += 256) rank_[i] = lo[i];
  __syncthreads();
  for (int i = t; i < ne; i += 256) {
    int d = dst[e0 + i];
    int s = src[e0 + i];
    int b = d >> 8;
    int r = atomicAdd(&rank_[b], 1);
    staged[r] = ((uint32)s << 8) | (uint32)(d & 255);
  }
  __syncthreads();
  if (t < NBUCK) gbase[t] = atomicAdd(&bcur[t], h[t]);
  __syncthreads();
  // coalesced copy-out; bucket found by binary search over lo[]
  for (int i = t; i < ne; i += 256) {
    int a = 0, b = NBUCK;
    while (b - a > 1) { int mid = (a + b) >> 1; if (lo[mid] <= i) a = mid; else b = mid; }
    ebuf[gbase[a] + (i - lo[a])] = staged[i];
  }
}

// ---- Pass B: per-bucket local scatter, LDS cursors, self-loop folded in ----
__global__ void partB_kernel(const int* __restrict__ row_start, const uint32* __restrict__ ebuf,
                             int* __restrict__ sorted_src) {
  __shared__ int cur[256];
  const int b = blockIdx.x;
  const int t = threadIdx.x;
  const int nb = b * 256;
  const int nn = min(256, N_NODES - nb);
  int nb1 = nb + 256; if (nb1 > N_NODES) nb1 = N_NODES;
  const int eb = row_start[nb] - nb;
  const int ee = row_start[nb1] - nb1;
  if (t < nn) {
    int n = nb + t;
    int rs = row_start[n];
    sorted_src[rs] = n;       // self loop first
    cur[t] = rs + 1;
  }
  __syncthreads();
  for (int i = eb + t; i < ee; i += 256) {
    uint32 w = ebuf[i];
    int pos = atomicAdd(&cur[w & 255], 1);
    sorted_src[pos] = (int)(w >> 8);
  }
}

// ---------------- segment softmax + aggregate, one wave per dst node ----------------
template<int HC>
__global__ void agg_kernel(const ushort* __restrict__ xb, const float* __restrict__ al,
                           const int* __restrict__ row_start, const int* __restrict__ sorted_src,
                           const float* __restrict__ bias, float* __restrict__ out) {
  __shared__ float2 eL[4][MAXD];
  __shared__ int    sL[4][MAXD];
  const int wid = (blockIdx.x * blockDim.x + threadIdx.x) >> 6;
  const int lane = threadIdx.x & 63;
  const int wv = (threadIdx.x >> 6) & 3;
  if (wid >= N_NODES) return;
  const float4* al4 = (const float4*)al;
  const uint32* xb32 = (const uint32*)xb;
  const int start = row_start[wid], end = row_start[wid + 1], deg = end - start;
  float4 mya = al4[wid];
  const float ad0 = mya.z, ad1 = mya.w;

  float m0 = -1e30f, m1 = -1e30f;
  float d0 = 0.f, d1 = 0.f;
  float acc0 = 0.f, acc1 = 0.f;
  const int c = lane & 31, hh = lane >> 5;
  const int head64 = c >> 4;
  const int head128 = lane >> 5;

  if (deg <= MAXD) {
    for (int i = start + lane; i < end; i += 64) {
      int s = sorted_src[i];
      float4 a = al4[s];
      float l0 = a.x + ad0; l0 = l0 > 0.f ? l0 : 0.2f * l0;
      float l1 = a.y + ad1; l1 = l1 > 0.f ? l1 : 0.2f * l1;
      int j = i - start;
      sL[wv][j] = s;
      eL[wv][j] = make_float2(l0, l1);
      m0 = fmaxf(m0, l0); m1 = fmaxf(m1, l1);
    }
    for (int off = 32; off >= 1; off >>= 1) {
      m0 = fmaxf(m0, __shfl_xor(m0, off));
      m1 = fmaxf(m1, __shfl_xor(m1, off));
    }
    for (int i = start + lane; i < end; i += 64) {
      int j = i - start;
      float2 l = eL[wv][j];
      float e0 = __expf(l.x - m0), e1 = __expf(l.y - m1);
      eL[wv][j] = make_float2(e0, e1);
      d0 += e0; d1 += e1;
    }
    for (int off = 32; off >= 1; off >>= 1) {
      d0 += __shfl_xor(d0, off);
      d1 += __shfl_xor(d1, off);
    }
    const float inv0 = 1.f / d0, inv1 = 1.f / d1;
    if (HC == 128) {
      const float invh = head128 ? inv1 : inv0;
      int j = 0;
      for (; j + 2 <= deg; j += 2) {
        int s0 = sL[wv][j], s1 = sL[wv][j + 1];
        uint32 v0 = xb32[(size_t)s0 * 64 + lane];
        uint32 v1 = xb32[(size_t)s1 * 64 + lane];
        float2 e0 = eL[wv][j], e1 = eL[wv][j + 1];
        float a0 = (head128 ? e0.y : e0.x) * invh;
        float a1 = (head128 ? e1.y : e1.x) * invh;
        acc0 = fmaf(a0, blo(v0), fmaf(a1, blo(v1), acc0));
        acc1 = fmaf(a0, bhi(v0), fmaf(a1, bhi(v1), acc1));
      }
      if (j < deg) {
        int s0 = sL[wv][j];
        uint32 v0 = xb32[(size_t)s0 * 64 + lane];
        float2 e0 = eL[wv][j];
        float a0 = (head128 ? e0.y : e0.x) * invh;
        acc0 = fmaf(a0, blo(v0), acc0);
        acc1 = fmaf(a0, bhi(v0), acc1);
      }
    } else {
      const float invh = head64 ? inv1 : inv0;
      for (int j = 0; j < deg; j += 2) {
        int jj = j + hh;
        float a0 = 0.f; uint32 v0 = 0;
        if (jj < deg) {
          int s = sL[wv][jj];
          v0 = xb32[(size_t)s * 32 + c];
          float2 e = eL[wv][jj];
          a0 = (head64 ? e.y : e.x) * invh;
        }
        acc0 = fmaf(a0, blo(v0), acc0);
        acc1 = fmaf(a0, bhi(v0), acc1);
      }
    }
  } else {
    // fallback: deg > MAXD (not expected for this graph)
    for (int i = start + lane; i < end; i += 64) {
      int s = sorted_src[i];
      float4 a = al4[s];
      float l0 = a.x + ad0; l0 = l0 > 0.f ? l0 : 0.2f * l0;
      float l1 = a.y + ad1; l1 = l1 > 0.f ? l1 : 0.2f * l1;
      m0 = fmaxf(m0, l0); m1 = fmaxf(m1, l1);
    }
    for (int off = 32; off >= 1; off >>= 1) {
      m0 = fmaxf(m0, __shfl_xor(m0, off));
      m1 = fmaxf(m1, __shfl_xor(m1, off));
    }
    for (int i = start + lane; i < end; i += 64) {
      int s = sorted_src[i];
      float4 a = al4[s];
      float l0 = a.x + ad0; l0 = l0 > 0.f ? l0 : 0.2f * l0;
      float l1 = a.y + ad1; l1 = l1 > 0.f ? l1 : 0.2f * l1;
      d0 += __expf(l0 - m0); d1 += __expf(l1 - m1);
    }
    for (int off = 32; off >= 1; off >>= 1) {
      d0 += __shfl_xor(d0, off);
      d1 += __shfl_xor(d1, off);
    }
    const float inv0 = 1.f / d0, inv1 = 1.f / d1;
    if (HC == 128) {
      const float invh = head128 ? inv1 : inv0;
      const float mh = head128 ? m1 : m0;
      const float adh = head128 ? ad1 : ad0;
      for (int i = start; i < end; ++i) {
        int s = sorted_src[i];
        float lv = al[s * 4 + head128] + adh;
        lv = lv > 0.f ? lv : 0.2f * lv;
        float a0 = __expf(lv - mh) * invh;
        uint32 v0 = xb32[(size_t)s * 64 + lane];
        acc0 = fmaf(a0, blo(v0), acc0);
        acc1 = fmaf(a0, bhi(v0), acc1);
      }
    } else {
      const float invh = head64 ? inv1 : inv0;
      const float mh = head64 ? m1 : m0;
      const float adh = head64 ? ad1 : ad0;
      for (int j = 0; j < deg; j += 2) {
        int jj = j + hh;
        float a0 = 0.f; uint32 v0 = 0;
        if (jj < deg) {
          int s = sorted_src[start + jj];
          float lv = al[s * 4 + head64] + adh;
          lv = lv > 0.f ? lv : 0.2f * lv;
          a0 = __expf(lv - mh) * invh;
          v0 = xb32[(size_t)s * 32 + c];
        }
        acc0 = fmaf(a0, blo(v0), acc0);
        acc1 = fmaf(a0, bhi(v0), acc1);
      }
    }
  }

  if (HC == 128) {
    float o0 = acc0 + bias[lane * 2];
    float o1 = acc1 + bias[lane * 2 + 1];
    o0 = o0 > 0.f ? o0 : __expf(o0) - 1.f;
    o1 = o1 > 0.f ? o1 : __expf(o1) - 1.f;
    *reinterpret_cast<float2*>(&out[(size_t)wid * 128 + lane * 2]) = make_float2(o0, o1);
  } else {
    acc0 += __shfl_xor(acc0, 32);
    acc1 += __shfl_xor(acc1, 32);
    if (hh == 0) {
      float o0 = acc0 + bias[c * 2];
      float o1 = acc1 + bias[c * 2 + 1];
      o0 = o0 > 0.f ? o0 : __expf(o0) - 1.f;
      o1 = o1 > 0.f ? o1 : __expf(o1) - 1.f;
      *reinterpret_cast<float2*>(&out[(size_t)wid * 64 + c * 2]) = make_float2(o0, o1);
    }
  }
}

__global__ void copy4_kernel(const float4* __restrict__ in, float4* __restrict__ out, int n4) {
  int i = blockIdx.x * blockDim.x + threadIdx.x;
  if (i < n4) out[i] = in[i];
}

extern "C" void kernel_launch(void* const* d_in, const int* in_sizes, int n_in,
                              void* d_out, int out_size, void* d_ws, size_t ws_size,
                              hipStream_t stream) {
  const float* x      = (const float*)d_in[0];
  const int*   ei     = (const int*)d_in[1];
  const float* W1     = (const float*)d_in[2];
  const float* a_src1 = (const float*)d_in[3];
  const float* a_dst1 = (const float*)d_in[4];
  const float* b1     = (const float*)d_in[5];
  const float* W2     = (const float*)d_in[6];
  const float* a_src2 = (const float*)d_in[7];
  const float* a_dst2 = (const float*)d_in[8];
  const float* b2     = (const float*)d_in[9];
  float* out = (float*)d_out;

  char* ws = (char*)d_ws;
  size_t off = 0;
  auto alloc = [&](size_t bytes) {
    void* p = ws + off;
    off = (off + bytes + 255) & ~(size_t)255;
    return p;
  };
  ushort* xb1       = (ushort*)alloc((size_t)N_NODES * 128 * 2);
  float*  h1        = (float*)alloc((size_t)N_NODES * 128 * 4);
  ushort* xb2       = (ushort*)alloc((size_t)N_NODES * 64 * 2);
  float*  al1       = (float*)alloc((size_t)N_NODES * 4 * 4);
  float*  al2       = (float*)alloc((size_t)N_NODES * 4 * 4);
  int*    counts    = (int*)alloc((size_t)N_NODES * 4);
  int*    row_start = (int*)alloc((size_t)(N_NODES + 1) * 4);
  int*    bsum      = (int*)alloc(256 * 4);
  int*    boff      = (int*)alloc(256 * 4);
  int*    bcur      = (int*)alloc(NBUCK * 4);
  int*    sorted_src= (int*)alloc((size_t)EA * 4);
  uint32* ebuf      = (uint32*)h1;   // alias: h1 not live until agg1

  const int* src = ei;
  const int* dst = ei + N_EDGES;

  const int nodeBlocks = (N_NODES + 255) / 256;   // 196
  const int edgeBlocks = (N_EDGES + 255) / 256;
  const int waveBlocks = (N_NODES * 64) / 256;
  const int partBlocks = (N_EDGES + EPB - 1) / EPB;  // 196

  // ---- CSR by destination (two-level scatter) ----
  init_counts_kernel<<<nodeBlocks, 256, 0, stream>>>(counts);
  hist_kernel<<<edgeBlocks, 256, 0, stream>>>(dst, counts);
  scanA_kernel<<<nodeBlocks, 256, 0, stream>>>(counts, row_start, bsum, N_NODES);
  scanB_kernel<<<1, 256, 0, stream>>>(bsum, boff, nodeBlocks, &row_start[N_NODES]);
  scanC_kernel<<<nodeBlocks, 256, 0, stream>>>(row_start, boff, N_NODES);
  bucket_base_kernel<<<1, 256, 0, stream>>>(row_start, bcur);
  partA_kernel<<<partBlocks, 256, 0, stream>>>(src, dst, bcur, ebuf);
  partB_kernel<<<NBUCK, 256, 0, stream>>>(row_start, ebuf, sorted_src);

  // ---- layer 1 ----
  gemm_al_kernel<128><<<(N_NODES + 63) / 64, 256, 0, stream>>>(x, W1, a_src1, a_dst1, xb1, al1, N_NODES);
  agg_kernel<128><<<waveBlocks, 256, 0, stream>>>(xb1, al1, row_start, sorted_src, b1, h1);

  // ---- layer 2 ----
  gemm_al_kernel<64><<<(N_NODES + 63) / 64, 256, 0, stream>>>(h1, W2, a_src2, a_dst2, xb2, al2, N_NODES);
  agg_kernel<64><<<waveBlocks, 256, 0, stream>>>(xb2, al2, row_start, sorted_src, b2, out);

  // ---- encoded passthrough ----
  copy4_kernel<<<((N_NODES * 128 / 4) + 255) / 256, 256, 0, stream>>>(
      (const float4*)x, (float4*)(out + (size_t)N_NODES * 64), N_NODES * 128 / 4);
}

// Round 4
// 270.017 us; speedup vs baseline: 2.5850x; 1.2963x over previous
//
#include <hip/hip_runtime.h>
#include <math.h>

#define N_NODES 50000
#define N_EDGES 1600000
#define EA (N_EDGES + N_NODES)
#define MAXD 128
#define NBUCK 196         // ceil(N_NODES / 256)
#define EPB 4096          // edges per workgroup in partition pass

typedef unsigned int uint32;
typedef float f32x4 __attribute__((ext_vector_type(4)));
typedef short s16x8 __attribute__((ext_vector_type(8)));

__device__ inline ushort f2bf(float f) {
  uint32 u = __float_as_uint(f);
  u += 0x7fffu + ((u >> 16) & 1u);
  return (ushort)(u >> 16);
}
__device__ inline float blo(uint32 v) { return __uint_as_float(v << 16); }
__device__ inline float bhi(uint32 v) { return __uint_as_float(v & 0xffff0000u); }
__device__ inline uint32 pack2bf(float a, float b) {
  return (uint32)f2bf(a) | ((uint32)f2bf(b) << 16);
}

// ---------------- MFMA GEMM + fused attention-logit epilogue ----------------
// C(bf16)[M][N] = A[M][128] * B[128][N];  al[n] = {src_h0,src_h1,dst_h0,dst_h1}
// A fragment: row = lane&15, k = (lane>>4)*8 + j (8 contiguous bf16)
// C/D: col = lane&15, row = (lane>>4)*4 + reg    [verified layout, guide §3]
template<int N, bool ABF>
__global__ __launch_bounds__(256) void gemm_mfma_kernel(
    const void* __restrict__ Ap, const float* __restrict__ B,
    const float* __restrict__ asrc, const float* __restrict__ adst,
    ushort* __restrict__ Cb, float* __restrict__ al, int M) {
  constexpr int KK = 4;              // 128 / 32
  constexpr int NC = N / 16;         // 8 or 4 column fragments
  __shared__ uint32 Bl[KK * NC * 64 * 4];   // 16B chunk per (kk,c,lane)
  const int t = threadIdx.x;

  // ---- stage B as bf16 MFMA fragments (per-lane chunk order) ----
  for (int id = t; id < KK * NC * 64; id += 256) {
    int lane = id & 63;
    int cf = (id >> 6) % NC;
    int kk = (id >> 6) / NC;
    int col = cf * 16 + (lane & 15);
    int k0 = kk * 32 + (lane >> 4) * 8;
    uint32 w0 = pack2bf(B[(k0 + 0) * N + col], B[(k0 + 1) * N + col]);
    uint32 w1 = pack2bf(B[(k0 + 2) * N + col], B[(k0 + 3) * N + col]);
    uint32 w2 = pack2bf(B[(k0 + 4) * N + col], B[(k0 + 5) * N + col]);
    uint32 w3 = pack2bf(B[(k0 + 6) * N + col], B[(k0 + 7) * N + col]);
    *reinterpret_cast<uint4*>(&Bl[id * 4]) = make_uint4(w0, w1, w2, w3);
  }
  __syncthreads();

  const int w = t >> 6, lane = t & 63;
  const int l15 = lane & 15, g4 = lane >> 4;
  const int row0 = blockIdx.x * 64 + w * 16;
  int arow = row0 + l15; if (arow > M - 1) arow = M - 1;
  const int k0 = g4 * 8;

  f32x4 acc[NC];
#pragma unroll
  for (int c = 0; c < NC; ++c) acc[c] = f32x4{0.f, 0.f, 0.f, 0.f};

#pragma unroll
  for (int kk = 0; kk < KK; ++kk) {
    s16x8 af;
    if (ABF) {
      af = *reinterpret_cast<const s16x8*>((const ushort*)Ap + (size_t)arow * 128 + kk * 32 + k0);
    } else {
      const float* A = (const float*)Ap;
      float4 a0 = *reinterpret_cast<const float4*>(A + (size_t)arow * 128 + kk * 32 + k0);
      float4 a1 = *reinterpret_cast<const float4*>(A + (size_t)arow * 128 + kk * 32 + k0 + 4);
      union { uint32 u[4]; s16x8 v; } p;
      p.u[0] = pack2bf(a0.x, a0.y);
      p.u[1] = pack2bf(a0.z, a0.w);
      p.u[2] = pack2bf(a1.x, a1.y);
      p.u[3] = pack2bf(a1.z, a1.w);
      af = p.v;
    }
#pragma unroll
    for (int c = 0; c < NC; ++c) {
      s16x8 bf = *reinterpret_cast<const s16x8*>(&Bl[((kk * NC + c) * 64 + lane) * 4]);
      acc[c] = __builtin_amdgcn_mfma_f32_16x16x32_bf16(af, bf, acc[c], 0, 0, 0);
    }
  }

  // ---- epilogue: bf16 C store + fused attention logits ----
  float as_c[NC], ad_c[NC];
#pragma unroll
  for (int c = 0; c < NC; ++c) { as_c[c] = asrc[c * 16 + l15]; ad_c[c] = adst[c * 16 + l15]; }
#pragma unroll
  for (int reg = 0; reg < 4; ++reg) {
    int row = row0 + g4 * 4 + reg;
    bool ok = row < M;
    float ps0 = 0.f, ps1 = 0.f, pd0 = 0.f, pd1 = 0.f;
#pragma unroll
    for (int c = 0; c < NC; ++c) {
      float v = acc[c][reg];
      if (ok) Cb[(size_t)row * N + c * 16 + l15] = f2bf(v);
      if (c < NC / 2) { ps0 += v * as_c[c]; pd0 += v * ad_c[c]; }
      else            { ps1 += v * as_c[c]; pd1 += v * ad_c[c]; }
    }
#pragma unroll
    for (int off = 8; off >= 1; off >>= 1) {   // reduce within 16-lane col group
      ps0 += __shfl_xor(ps0, off); ps1 += __shfl_xor(ps1, off);
      pd0 += __shfl_xor(pd0, off); pd1 += __shfl_xor(pd1, off);
    }
    if (ok && l15 == 0)
      *reinterpret_cast<float4*>(&al[row * 4]) = make_float4(ps0, ps1, pd0, pd1);
  }
}

// ---------------- CSR build ----------------
__global__ void init_counts_kernel(int* __restrict__ counts) {
  int n = blockIdx.x * blockDim.x + threadIdx.x;
  if (n < N_NODES) counts[n] = 1;   // self loop
}

__global__ void hist_kernel(const int* __restrict__ dst, int* __restrict__ counts) {
  int e = (blockIdx.x * blockDim.x + threadIdx.x) * 4;
  if (e + 3 < N_EDGES) {
    int4 d = *reinterpret_cast<const int4*>(dst + e);
    atomicAdd(&counts[d.x], 1); atomicAdd(&counts[d.y], 1);
    atomicAdd(&counts[d.z], 1); atomicAdd(&counts[d.w], 1);
  } else {
    for (int k = e; k < N_EDGES; ++k) atomicAdd(&counts[dst[k]], 1);
  }
}

__global__ void scanA_kernel(const int* __restrict__ counts, int* __restrict__ row_start,
                             int* __restrict__ bsum, int n) {
  __shared__ int wsh[4];
  const int t = threadIdx.x, lane = t & 63, wv = t >> 6;
  int i = blockIdx.x * 256 + t;
  int v = (i < n) ? counts[i] : 0;
  int x = v;
  for (int off = 1; off < 64; off <<= 1) {
    int y = __shfl_up(x, off);
    if (lane >= off) x += y;
  }
  if (lane == 63) wsh[wv] = x;
  __syncthreads();
  int wo = 0;
  for (int w = 0; w < wv; ++w) wo += wsh[w];
  if (i < n) row_start[i] = wo + x - v;
  if (t == 255) bsum[blockIdx.x] = wo + x;
}

__global__ void scanB_kernel(const int* __restrict__ bsum, int* __restrict__ boff,
                             int nb, int* __restrict__ total_out) {
  __shared__ int wsh[4];
  const int t = threadIdx.x, lane = t & 63, wv = t >> 6;
  int v = (t < nb) ? bsum[t] : 0;
  int x = v;
  for (int off = 1; off < 64; off <<= 1) {
    int y = __shfl_up(x, off);
    if (lane >= off) x += y;
  }
  if (lane == 63) wsh[wv] = x;
  __syncthreads();
  int wo = 0;
  for (int w = 0; w < wv; ++w) wo += wsh[w];
  if (t < nb) boff[t] = wo + x - v;
  if (t == 255) total_out[0] = wo + x;
}

__global__ void scanC_kernel(int* __restrict__ row_start, const int* __restrict__ boff, int n) {
  int i = blockIdx.x * 256 + threadIdx.x;
  if (i < n) row_start[i] += boff[blockIdx.x];
}

__global__ void bucket_base_kernel(const int* __restrict__ row_start, int* __restrict__ bcur) {
  int b = blockIdx.x * blockDim.x + threadIdx.x;
  if (b < NBUCK) {
    int nb = b * 256; if (nb > N_NODES) nb = N_NODES;
    bcur[b] = row_start[nb] - nb;
  }
}

// ---- Pass A: partition edges into 196 coarse buckets (coalesced writes) ----
__global__ void partA_kernel(const int* __restrict__ src, const int* __restrict__ dst,
                             int* __restrict__ bcur, uint32* __restrict__ ebuf) {
  __shared__ int h[NBUCK];
  __shared__ int lo[NBUCK + 1];
  __shared__ int rank_[NBUCK];
  __shared__ int gbase[NBUCK];
  __shared__ uint32 staged[EPB];
  const int t = threadIdx.x;
  const int e0 = blockIdx.x * EPB;
  const int ne = min(EPB, N_EDGES - e0);

  for (int i = t; i < NBUCK; i += 256) h[i] = 0;
  __syncthreads();
  for (int i = t; i < ne; i += 256) {
    int d = dst[e0 + i];
    atomicAdd(&h[d >> 8], 1);
  }
  __syncthreads();
  if (t == 0) {
    int a = 0;
    for (int b = 0; b < NBUCK; ++b) { lo[b] = a; a += h[b]; }
    lo[NBUCK] = a;
  }
  __syncthreads();
  for (int i = t; i < NBUCK; i += 256) rank_[i] = lo[i];
  __syncthreads();
  for (int i = t; i < ne; i += 256) {
    int d = dst[e0 + i];
    int s = src[e0 + i];
    int b = d >> 8;
    int r = atomicAdd(&rank_[b], 1);
    staged[r] = ((uint32)s << 8) | (uint32)(d & 255);
  }
  __syncthreads();
  if (t < NBUCK) gbase[t] = atomicAdd(&bcur[t], h[t]);
  __syncthreads();
  for (int i = t; i < ne; i += 256) {
    int a = 0, b = NBUCK;
    while (b - a > 1) { int mid = (a + b) >> 1; if (lo[mid] <= i) a = mid; else b = mid; }
    ebuf[gbase[a] + (i - lo[a])] = staged[i];
  }
}

// ---- Pass B: per-bucket local scatter, LDS cursors, self-loop folded in ----
__global__ void partB_kernel(const int* __restrict__ row_start, const uint32* __restrict__ ebuf,
                             int* __restrict__ sorted_src) {
  __shared__ int cur[256];
  const int b = blockIdx.x;
  const int t = threadIdx.x;
  const int nb = b * 256;
  const int nn = min(256, N_NODES - nb);
  int nb1 = nb + 256; if (nb1 > N_NODES) nb1 = N_NODES;
  const int eb = row_start[nb] - nb;
  const int ee = row_start[nb1] - nb1;
  if (t < nn) {
    int n = nb + t;
    int rs = row_start[n];
    sorted_src[rs] = n;       // self loop first
    cur[t] = rs + 1;
  }
  __syncthreads();
  for (int i = eb + t; i < ee; i += 256) {
    uint32 w = ebuf[i];
    int pos = atomicAdd(&cur[w & 255], 1);
    sorted_src[pos] = (int)(w >> 8);
  }
}

// ---------------- segment softmax + aggregate, one wave per dst node ----------------
template<int HC, bool OUTBF>
__global__ void agg_kernel(const ushort* __restrict__ xb, const float* __restrict__ al,
                           const int* __restrict__ row_start, const int* __restrict__ sorted_src,
                           const float* __restrict__ bias, void* __restrict__ outp) {
  __shared__ float2 eL[4][MAXD];
  __shared__ int    sL[4][MAXD];
  const int wid = (blockIdx.x * blockDim.x + threadIdx.x) >> 6;
  const int lane = threadIdx.x & 63;
  const int wv = (threadIdx.x >> 6) & 3;
  if (wid >= N_NODES) return;
  const float4* al4 = (const float4*)al;
  const uint32* xb32 = (const uint32*)xb;
  const int start = row_start[wid], end = row_start[wid + 1], deg = end - start;
  float4 mya = al4[wid];
  const float ad0 = mya.z, ad1 = mya.w;

  float m0 = -1e30f, m1 = -1e30f;
  float d0 = 0.f, d1 = 0.f;
  float acc0 = 0.f, acc1 = 0.f;
  const int c = lane & 31, hh = lane >> 5;
  const int head64 = c >> 4;
  const int head128 = lane >> 5;

  if (deg <= MAXD) {
    for (int i = start + lane; i < end; i += 64) {
      int s = sorted_src[i];
      float4 a = al4[s];
      float l0 = a.x + ad0; l0 = l0 > 0.f ? l0 : 0.2f * l0;
      float l1 = a.y + ad1; l1 = l1 > 0.f ? l1 : 0.2f * l1;
      int j = i - start;
      sL[wv][j] = s;
      eL[wv][j] = make_float2(l0, l1);
      m0 = fmaxf(m0, l0); m1 = fmaxf(m1, l1);
    }
    for (int off = 32; off >= 1; off >>= 1) {
      m0 = fmaxf(m0, __shfl_xor(m0, off));
      m1 = fmaxf(m1, __shfl_xor(m1, off));
    }
    for (int i = start + lane; i < end; i += 64) {
      int j = i - start;
      float2 l = eL[wv][j];
      float e0 = __expf(l.x - m0), e1 = __expf(l.y - m1);
      eL[wv][j] = make_float2(e0, e1);
      d0 += e0; d1 += e1;
    }
    for (int off = 32; off >= 1; off >>= 1) {
      d0 += __shfl_xor(d0, off);
      d1 += __shfl_xor(d1, off);
    }
    const float inv0 = 1.f / d0, inv1 = 1.f / d1;
    // pass 2.5: normalize alphas in LDS (same-wave RAW, in-order LDS)
    for (int j = lane; j < deg; j += 64) {
      float2 e = eL[wv][j];
      eL[wv][j] = make_float2(e.x * inv0, e.y * inv1);
    }
    if (HC == 128) {
      float a0x = 0.f, a1x = 0.f;   // dual accumulators
      int j = 0;
      for (; j + 4 <= deg; j += 4) {
        int s0 = sL[wv][j],     s1 = sL[wv][j + 1];
        int s2 = sL[wv][j + 2], s3 = sL[wv][j + 3];
        uint32 v0 = xb32[(size_t)s0 * 64 + lane];
        uint32 v1 = xb32[(size_t)s1 * 64 + lane];
        uint32 v2 = xb32[(size_t)s2 * 64 + lane];
        uint32 v3 = xb32[(size_t)s3 * 64 + lane];
        float2 e0 = eL[wv][j],     e1 = eL[wv][j + 1];
        float2 e2 = eL[wv][j + 2], e3 = eL[wv][j + 3];
        float w0 = head128 ? e0.y : e0.x, w1 = head128 ? e1.y : e1.x;
        float w2 = head128 ? e2.y : e2.x, w3 = head128 ? e3.y : e3.x;
        acc0 = fmaf(w0, blo(v0), fmaf(w1, blo(v1), acc0));
        acc1 = fmaf(w0, bhi(v0), fmaf(w1, bhi(v1), acc1));
        a0x  = fmaf(w2, blo(v2), fmaf(w3, blo(v3), a0x));
        a1x  = fmaf(w2, bhi(v2), fmaf(w3, bhi(v3), a1x));
      }
      for (; j < deg; ++j) {
        int s0 = sL[wv][j];
        uint32 v0 = xb32[(size_t)s0 * 64 + lane];
        float2 e0 = eL[wv][j];
        float w0 = head128 ? e0.y : e0.x;
        acc0 = fmaf(w0, blo(v0), acc0);
        acc1 = fmaf(w0, bhi(v0), acc1);
      }
      acc0 += a0x; acc1 += a1x;
    } else {
      float a0x = 0.f, a1x = 0.f;
      int j = 0;
      for (; j + 4 <= deg; j += 4) {
        int jj0 = j + hh, jj1 = j + 2 + hh;
        int s0 = sL[wv][jj0], s1 = sL[wv][jj1];
        uint32 v0 = xb32[(size_t)s0 * 32 + c];
        uint32 v1 = xb32[(size_t)s1 * 32 + c];
        float2 e0 = eL[wv][jj0], e1 = eL[wv][jj1];
        float w0 = head64 ? e0.y : e0.x, w1 = head64 ? e1.y : e1.x;
        acc0 = fmaf(w0, blo(v0), acc0);
        acc1 = fmaf(w0, bhi(v0), acc1);
        a0x  = fmaf(w1, blo(v1), a0x);
        a1x  = fmaf(w1, bhi(v1), a1x);
      }
      for (; j < deg; j += 2) {
        int jj = j + hh;
        float w0 = 0.f; uint32 v0 = 0;
        if (jj < deg) {
          int s = sL[wv][jj];
          v0 = xb32[(size_t)s * 32 + c];
          float2 e = eL[wv][jj];
          w0 = head64 ? e.y : e.x;
        }
        acc0 = fmaf(w0, blo(v0), acc0);
        acc1 = fmaf(w0, bhi(v0), acc1);
      }
      acc0 += a0x; acc1 += a1x;
    }
  } else {
    // fallback: deg > MAXD
    for (int i = start + lane; i < end; i += 64) {
      int s = sorted_src[i];
      float4 a = al4[s];
      float l0 = a.x + ad0; l0 = l0 > 0.f ? l0 : 0.2f * l0;
      float l1 = a.y + ad1; l1 = l1 > 0.f ? l1 : 0.2f * l1;
      m0 = fmaxf(m0, l0); m1 = fmaxf(m1, l1);
    }
    for (int off = 32; off >= 1; off >>= 1) {
      m0 = fmaxf(m0, __shfl_xor(m0, off));
      m1 = fmaxf(m1, __shfl_xor(m1, off));
    }
    for (int i = start + lane; i < end; i += 64) {
      int s = sorted_src[i];
      float4 a = al4[s];
      float l0 = a.x + ad0; l0 = l0 > 0.f ? l0 : 0.2f * l0;
      float l1 = a.y + ad1; l1 = l1 > 0.f ? l1 : 0.2f * l1;
      d0 += __expf(l0 - m0); d1 += __expf(l1 - m1);
    }
    for (int off = 32; off >= 1; off >>= 1) {
      d0 += __shfl_xor(d0, off);
      d1 += __shfl_xor(d1, off);
    }
    const float inv0 = 1.f / d0, inv1 = 1.f / d1;
    if (HC == 128) {
      const float invh = head128 ? inv1 : inv0;
      const float mh = head128 ? m1 : m0;
      const float adh = head128 ? ad1 : ad0;
      for (int i = start; i < end; ++i) {
        int s = sorted_src[i];
        float lv = al[s * 4 + head128] + adh;
        lv = lv > 0.f ? lv : 0.2f * lv;
        float a0 = __expf(lv - mh) * invh;
        uint32 v0 = xb32[(size_t)s * 64 + lane];
        acc0 = fmaf(a0, blo(v0), acc0);
        acc1 = fmaf(a0, bhi(v0), acc1);
      }
    } else {
      const float invh = head64 ? inv1 : inv0;
      const float mh = head64 ? m1 : m0;
      const float adh = head64 ? ad1 : ad0;
      for (int j = 0; j < deg; j += 2) {
        int jj = j + hh;
        float a0 = 0.f; uint32 v0 = 0;
        if (jj < deg) {
          int s = sorted_src[start + jj];
          float lv = al[s * 4 + head64] + adh;
          lv = lv > 0.f ? lv : 0.2f * lv;
          a0 = __expf(lv - mh) * invh;
          v0 = xb32[(size_t)s * 32 + c];
        }
        acc0 = fmaf(a0, blo(v0), acc0);
        acc1 = fmaf(a0, bhi(v0), acc1);
      }
    }
  }

  // ---- epilogue: bias + ELU + store ----
  if (HC == 128) {
    float o0 = acc0 + bias[lane * 2];
    float o1 = acc1 + bias[lane * 2 + 1];
    o0 = o0 > 0.f ? o0 : __expf(o0) - 1.f;
    o1 = o1 > 0.f ? o1 : __expf(o1) - 1.f;
    if (OUTBF) {
      ((uint32*)outp)[(size_t)wid * 64 + lane] = pack2bf(o0, o1);
    } else {
      *reinterpret_cast<float2*>((float*)outp + (size_t)wid * 128 + lane * 2) = make_float2(o0, o1);
    }
  } else {
    acc0 += __shfl_xor(acc0, 32);
    acc1 += __shfl_xor(acc1, 32);
    if (hh == 0) {
      float o0 = acc0 + bias[c * 2];
      float o1 = acc1 + bias[c * 2 + 1];
      o0 = o0 > 0.f ? o0 : __expf(o0) - 1.f;
      o1 = o1 > 0.f ? o1 : __expf(o1) - 1.f;
      *reinterpret_cast<float2*>((float*)outp + (size_t)wid * 64 + c * 2) = make_float2(o0, o1);
    }
  }
}

__global__ void copy4_kernel(const float4* __restrict__ in, float4* __restrict__ out, int n4) {
  int i = blockIdx.x * blockDim.x + threadIdx.x;
  if (i < n4) out[i] = in[i];
}

extern "C" void kernel_launch(void* const* d_in, const int* in_sizes, int n_in,
                              void* d_out, int out_size, void* d_ws, size_t ws_size,
                              hipStream_t stream) {
  const float* x      = (const float*)d_in[0];
  const int*   ei     = (const int*)d_in[1];
  const float* W1     = (const float*)d_in[2];
  const float* a_src1 = (const float*)d_in[3];
  const float* a_dst1 = (const float*)d_in[4];
  const float* b1     = (const float*)d_in[5];
  const float* W2     = (const float*)d_in[6];
  const float* a_src2 = (const float*)d_in[7];
  const float* a_dst2 = (const float*)d_in[8];
  const float* b2     = (const float*)d_in[9];
  float* out = (float*)d_out;

  char* ws = (char*)d_ws;
  size_t off = 0;
  auto alloc = [&](size_t bytes) {
    void* p = ws + off;
    off = (off + bytes + 255) & ~(size_t)255;
    return p;
  };
  ushort* xb1       = (ushort*)alloc((size_t)N_NODES * 128 * 2);
  ushort* h1b       = (ushort*)alloc((size_t)N_NODES * 128 * 2);  // layer-1 output, bf16
  ushort* xb2       = (ushort*)alloc((size_t)N_NODES * 64 * 2);
  float*  al1       = (float*)alloc((size_t)N_NODES * 4 * 4);
  float*  al2       = (float*)alloc((size_t)N_NODES * 4 * 4);
  int*    counts    = (int*)alloc((size_t)N_NODES * 4);
  int*    row_start = (int*)alloc((size_t)(N_NODES + 1) * 4);
  int*    bsum      = (int*)alloc(256 * 4);
  int*    boff      = (int*)alloc(256 * 4);
  int*    bcur      = (int*)alloc(NBUCK * 4);
  int*    sorted_src= (int*)alloc((size_t)EA * 4);
  uint32* ebuf      = (uint32*)h1b;   // alias: h1b not live until agg1

  const int* src = ei;
  const int* dst = ei + N_EDGES;

  const int nodeBlocks = (N_NODES + 255) / 256;   // 196
  const int waveBlocks = (N_NODES * 64) / 256;
  const int partBlocks = (N_EDGES + EPB - 1) / EPB;
  const int gemmBlocks = (N_NODES + 63) / 64;     // 782

  // ---- CSR by destination (two-level scatter) ----
  init_counts_kernel<<<nodeBlocks, 256, 0, stream>>>(counts);
  hist_kernel<<<(N_EDGES / 4 + 255) / 256, 256, 0, stream>>>(dst, counts);
  scanA_kernel<<<nodeBlocks, 256, 0, stream>>>(counts, row_start, bsum, N_NODES);
  scanB_kernel<<<1, 256, 0, stream>>>(bsum, boff, nodeBlocks, &row_start[N_NODES]);
  scanC_kernel<<<nodeBlocks, 256, 0, stream>>>(row_start, boff, N_NODES);
  bucket_base_kernel<<<1, 256, 0, stream>>>(row_start, bcur);
  partA_kernel<<<partBlocks, 256, 0, stream>>>(src, dst, bcur, ebuf);
  partB_kernel<<<NBUCK, 256, 0, stream>>>(row_start, ebuf, sorted_src);

  // ---- layer 1 ----
  gemm_mfma_kernel<128, false><<<gemmBlocks, 256, 0, stream>>>(x, W1, a_src1, a_dst1, xb1, al1, N_NODES);
  agg_kernel<128, true><<<waveBlocks, 256, 0, stream>>>(xb1, al1, row_start, sorted_src, b1, h1b);

  // ---- layer 2 ----
  gemm_mfma_kernel<64, true><<<gemmBlocks, 256, 0, stream>>>(h1b, W2, a_src2, a_dst2, xb2, al2, N_NODES);
  agg_kernel<64, false><<<waveBlocks, 256, 0, stream>>>(xb2, al2, row_start, sorted_src, b2, out);

  // ---- encoded passthrough ----
  copy4_kernel<<<((N_NODES * 128 / 4) + 255) / 256, 256, 0, stream>>>(
      (const float4*)x, (float4*)(out + (size_t)N_NODES * 64), N_NODES * 128 / 4);
}

// Round 5
// 205.372 us; speedup vs baseline: 3.3987x; 1.3148x over previous
//
#include <hip/hip_runtime.h>
#include <math.h>

#define N_NODES 50000
#define N_EDGES 1600000
#define EA (N_EDGES + N_NODES)
#define MAXD 128
#define NBUCK 196         // ceil(N_NODES / 256)
#define EPB 4096          // edges per workgroup in partition pass
#define BCAP 16000        // ebuf words per bucket (mean fill 8192; 196*BCAP fits h1b alias)

typedef unsigned int uint32;
typedef float f32x4 __attribute__((ext_vector_type(4)));
typedef short s16x8 __attribute__((ext_vector_type(8)));

__device__ inline ushort f2bf(float f) {
  uint32 u = __float_as_uint(f);
  u += 0x7fffu + ((u >> 16) & 1u);
  return (ushort)(u >> 16);
}
__device__ inline float blo(uint32 v) { return __uint_as_float(v << 16); }
__device__ inline float bhi(uint32 v) { return __uint_as_float(v & 0xffff0000u); }
__device__ inline uint32 pack2bf(float a, float b) {
  return (uint32)f2bf(a) | ((uint32)f2bf(b) << 16);
}

// ---------------- MFMA GEMM + fused attention-logit epilogue ----------------
// C(bf16)[M][N] = A[M][128] * B[128][N];  al[n] = {src_h0,src_h1,dst_h0,dst_h1}
template<int N, bool ABF>
__global__ __launch_bounds__(256) void gemm_mfma_kernel(
    const void* __restrict__ Ap, const float* __restrict__ B,
    const float* __restrict__ asrc, const float* __restrict__ adst,
    ushort* __restrict__ Cb, float* __restrict__ al, int M) {
  constexpr int KK = 4;              // 128 / 32
  constexpr int NC = N / 16;         // 8 or 4 column fragments
  __shared__ uint32 Bl[KK * NC * 64 * 4];   // 16B chunk per (kk,c,lane)
  const int t = threadIdx.x;

  for (int id = t; id < KK * NC * 64; id += 256) {
    int lane = id & 63;
    int cf = (id >> 6) % NC;
    int kk = (id >> 6) / NC;
    int col = cf * 16 + (lane & 15);
    int k0 = kk * 32 + (lane >> 4) * 8;
    uint32 w0 = pack2bf(B[(k0 + 0) * N + col], B[(k0 + 1) * N + col]);
    uint32 w1 = pack2bf(B[(k0 + 2) * N + col], B[(k0 + 3) * N + col]);
    uint32 w2 = pack2bf(B[(k0 + 4) * N + col], B[(k0 + 5) * N + col]);
    uint32 w3 = pack2bf(B[(k0 + 6) * N + col], B[(k0 + 7) * N + col]);
    *reinterpret_cast<uint4*>(&Bl[id * 4]) = make_uint4(w0, w1, w2, w3);
  }
  __syncthreads();

  const int w = t >> 6, lane = t & 63;
  const int l15 = lane & 15, g4 = lane >> 4;
  const int row0 = blockIdx.x * 64 + w * 16;
  int arow = row0 + l15; if (arow > M - 1) arow = M - 1;
  const int k0 = g4 * 8;

  f32x4 acc[NC];
#pragma unroll
  for (int c = 0; c < NC; ++c) acc[c] = f32x4{0.f, 0.f, 0.f, 0.f};

#pragma unroll
  for (int kk = 0; kk < KK; ++kk) {
    s16x8 af;
    if (ABF) {
      af = *reinterpret_cast<const s16x8*>((const ushort*)Ap + (size_t)arow * 128 + kk * 32 + k0);
    } else {
      const float* A = (const float*)Ap;
      float4 a0 = *reinterpret_cast<const float4*>(A + (size_t)arow * 128 + kk * 32 + k0);
      float4 a1 = *reinterpret_cast<const float4*>(A + (size_t)arow * 128 + kk * 32 + k0 + 4);
      union { uint32 u[4]; s16x8 v; } p;
      p.u[0] = pack2bf(a0.x, a0.y);
      p.u[1] = pack2bf(a0.z, a0.w);
      p.u[2] = pack2bf(a1.x, a1.y);
      p.u[3] = pack2bf(a1.z, a1.w);
      af = p.v;
    }
#pragma unroll
    for (int c = 0; c < NC; ++c) {
      s16x8 bf = *reinterpret_cast<const s16x8*>(&Bl[((kk * NC + c) * 64 + lane) * 4]);
      acc[c] = __builtin_amdgcn_mfma_f32_16x16x32_bf16(af, bf, acc[c], 0, 0, 0);
    }
  }

  float as_c[NC], ad_c[NC];
#pragma unroll
  for (int c = 0; c < NC; ++c) { as_c[c] = asrc[c * 16 + l15]; ad_c[c] = adst[c * 16 + l15]; }
#pragma unroll
  for (int reg = 0; reg < 4; ++reg) {
    int row = row0 + g4 * 4 + reg;
    bool ok = row < M;
    float ps0 = 0.f, ps1 = 0.f, pd0 = 0.f, pd1 = 0.f;
#pragma unroll
    for (int c = 0; c < NC; ++c) {
      float v = acc[c][reg];
      if (ok) Cb[(size_t)row * N + c * 16 + l15] = f2bf(v);
      if (c < NC / 2) { ps0 += v * as_c[c]; pd0 += v * ad_c[c]; }
      else            { ps1 += v * as_c[c]; pd1 += v * ad_c[c]; }
    }
#pragma unroll
    for (int off = 8; off >= 1; off >>= 1) {
      ps0 += __shfl_xor(ps0, off); ps1 += __shfl_xor(ps1, off);
      pd0 += __shfl_xor(pd0, off); pd1 += __shfl_xor(pd1, off);
    }
    if (ok && l15 == 0)
      *reinterpret_cast<float4*>(&al[row * 4]) = make_float4(ps0, ps1, pd0, pd1);
  }
}

// ---------------- CSR build (no global-atomic histogram) ----------------
__global__ void init_bcur_kernel(int* __restrict__ bcur) {
  int b = blockIdx.x * blockDim.x + threadIdx.x;
  if (b < NBUCK) bcur[b] = b * BCAP;
}

// ---- Pass A: partition edges into 196 coarse buckets (fixed-capacity slices) ----
__global__ void partA_kernel(const int* __restrict__ src, const int* __restrict__ dst,
                             int* __restrict__ bcur, uint32* __restrict__ ebuf) {
  __shared__ int h[NBUCK];
  __shared__ int lo[NBUCK + 1];
  __shared__ int rank_[NBUCK];
  __shared__ int gbase[NBUCK];
  __shared__ uint32 staged[EPB];
  const int t = threadIdx.x;
  const int e0 = blockIdx.x * EPB;
  const int ne = min(EPB, N_EDGES - e0);

  for (int i = t; i < NBUCK; i += 256) h[i] = 0;
  __syncthreads();
  for (int i = t; i < ne; i += 256) {
    int d = dst[e0 + i];
    atomicAdd(&h[d >> 8], 1);
  }
  __syncthreads();
  if (t == 0) {
    int a = 0;
    for (int b = 0; b < NBUCK; ++b) { lo[b] = a; a += h[b]; }
    lo[NBUCK] = a;
  }
  __syncthreads();
  for (int i = t; i < NBUCK; i += 256) rank_[i] = lo[i];
  __syncthreads();
  for (int i = t; i < ne; i += 256) {
    int d = dst[e0 + i];
    int s = src[e0 + i];
    int b = d >> 8;
    int r = atomicAdd(&rank_[b], 1);
    staged[r] = ((uint32)s << 8) | (uint32)(d & 255);
  }
  __syncthreads();
  if (t < NBUCK) gbase[t] = atomicAdd(&bcur[t], h[t]);
  __syncthreads();
  for (int i = t; i < ne; i += 256) {
    int a = 0, b = NBUCK;
    while (b - a > 1) { int mid = (a + b) >> 1; if (lo[mid] <= i) a = mid; else b = mid; }
    ebuf[gbase[a] + (i - lo[a])] = staged[i];
  }
}

// ---- per-bucket LDS histogram -> counts (self loop folded in) ----
__global__ void bucket_hist_kernel(const uint32* __restrict__ ebuf, const int* __restrict__ bcur,
                                   int* __restrict__ counts) {
  __shared__ int h[256];
  const int b = blockIdx.x;
  const int t = threadIdx.x;
  h[t] = 0;
  __syncthreads();
  const int base = b * BCAP;
  const int ee = bcur[b];
  for (int i = base + t; i < ee; i += 256) {
    uint32 w = ebuf[i];
    atomicAdd(&h[w & 255], 1);
  }
  __syncthreads();
  int n = b * 256 + t;
  if (n < N_NODES) counts[n] = h[t] + 1;   // +1 self loop
}

__global__ void scanA_kernel(const int* __restrict__ counts, int* __restrict__ row_start,
                             int* __restrict__ bsum, int n) {
  __shared__ int wsh[4];
  const int t = threadIdx.x, lane = t & 63, wv = t >> 6;
  int i = blockIdx.x * 256 + t;
  int v = (i < n) ? counts[i] : 0;
  int x = v;
  for (int off = 1; off < 64; off <<= 1) {
    int y = __shfl_up(x, off);
    if (lane >= off) x += y;
  }
  if (lane == 63) wsh[wv] = x;
  __syncthreads();
  int wo = 0;
  for (int w = 0; w < wv; ++w) wo += wsh[w];
  if (i < n) row_start[i] = wo + x - v;
  if (t == 255) bsum[blockIdx.x] = wo + x;
}

__global__ void scanB_kernel(const int* __restrict__ bsum, int* __restrict__ boff,
                             int nb, int* __restrict__ total_out) {
  __shared__ int wsh[4];
  const int t = threadIdx.x, lane = t & 63, wv = t >> 6;
  int v = (t < nb) ? bsum[t] : 0;
  int x = v;
  for (int off = 1; off < 64; off <<= 1) {
    int y = __shfl_up(x, off);
    if (lane >= off) x += y;
  }
  if (lane == 63) wsh[wv] = x;
  __syncthreads();
  int wo = 0;
  for (int w = 0; w < wv; ++w) wo += wsh[w];
  if (t < nb) boff[t] = wo + x - v;
  if (t == 255) total_out[0] = wo + x;
}

__global__ void scanC_kernel(int* __restrict__ row_start, const int* __restrict__ boff, int n) {
  int i = blockIdx.x * 256 + threadIdx.x;
  if (i < n) row_start[i] += boff[blockIdx.x];
}

// ---- Pass B: per-bucket local scatter, LDS cursors ----
__global__ void partB_kernel(const int* __restrict__ row_start, const uint32* __restrict__ ebuf,
                             const int* __restrict__ bcur, int* __restrict__ sorted_src) {
  __shared__ int cur[256];
  const int b = blockIdx.x;
  const int t = threadIdx.x;
  const int nb = b * 256;
  const int nn = min(256, N_NODES - nb);
  if (t < nn) {
    int n = nb + t;
    int rs = row_start[n];
    sorted_src[rs] = n;       // self loop first
    cur[t] = rs + 1;
  }
  __syncthreads();
  const int base = b * BCAP;
  const int ee = bcur[b];
  for (int i = base + t; i < ee; i += 256) {
    uint32 w = ebuf[i];
    int pos = atomicAdd(&cur[w & 255], 1);
    sorted_src[pos] = (int)(w >> 8);
  }
}

// ---------------- segment softmax + aggregate, one wave per dst node ----------------
template<int HC, bool OUTBF>
__global__ void agg_kernel(const ushort* __restrict__ xb, const float* __restrict__ al,
                           const int* __restrict__ row_start, const int* __restrict__ sorted_src,
                           const float* __restrict__ bias, void* __restrict__ outp) {
  __shared__ float2 eL[4][MAXD];
  __shared__ int    sL[4][MAXD];
  const int wid = (blockIdx.x * blockDim.x + threadIdx.x) >> 6;
  const int lane = threadIdx.x & 63;
  const int wv = (threadIdx.x >> 6) & 3;
  if (wid >= N_NODES) return;
  const float4* al4 = (const float4*)al;
  const uint32* xb32 = (const uint32*)xb;
  const int start = row_start[wid], end = row_start[wid + 1], deg = end - start;
  float4 mya = al4[wid];
  const float ad0 = mya.z, ad1 = mya.w;

  float m0 = -1e30f, m1 = -1e30f;
  float d0 = 0.f, d1 = 0.f;
  float acc0 = 0.f, acc1 = 0.f;
  const int c = lane & 31, hh = lane >> 5;
  const int head64 = c >> 4;
  const int head128 = lane >> 5;

  if (deg <= MAXD) {
    for (int i = start + lane; i < end; i += 64) {
      int s = sorted_src[i];
      float4 a = al4[s];
      float l0 = a.x + ad0; l0 = l0 > 0.f ? l0 : 0.2f * l0;
      float l1 = a.y + ad1; l1 = l1 > 0.f ? l1 : 0.2f * l1;
      int j = i - start;
      sL[wv][j] = s;
      eL[wv][j] = make_float2(l0, l1);
      m0 = fmaxf(m0, l0); m1 = fmaxf(m1, l1);
    }
    for (int off = 32; off >= 1; off >>= 1) {
      m0 = fmaxf(m0, __shfl_xor(m0, off));
      m1 = fmaxf(m1, __shfl_xor(m1, off));
    }
    for (int i = start + lane; i < end; i += 64) {
      int j = i - start;
      float2 l = eL[wv][j];
      float e0 = __expf(l.x - m0), e1 = __expf(l.y - m1);
      eL[wv][j] = make_float2(e0, e1);
      d0 += e0; d1 += e1;
    }
    for (int off = 32; off >= 1; off >>= 1) {
      d0 += __shfl_xor(d0, off);
      d1 += __shfl_xor(d1, off);
    }
    const float inv0 = 1.f / d0, inv1 = 1.f / d1;
    for (int j = lane; j < deg; j += 64) {
      float2 e = eL[wv][j];
      eL[wv][j] = make_float2(e.x * inv0, e.y * inv1);
    }
    if (HC == 128) {
      float a0x = 0.f, a1x = 0.f;
      int j = 0;
      for (; j + 4 <= deg; j += 4) {
        int s0 = sL[wv][j],     s1 = sL[wv][j + 1];
        int s2 = sL[wv][j + 2], s3 = sL[wv][j + 3];
        uint32 v0 = xb32[(size_t)s0 * 64 + lane];
        uint32 v1 = xb32[(size_t)s1 * 64 + lane];
        uint32 v2 = xb32[(size_t)s2 * 64 + lane];
        uint32 v3 = xb32[(size_t)s3 * 64 + lane];
        float2 e0 = eL[wv][j],     e1 = eL[wv][j + 1];
        float2 e2 = eL[wv][j + 2], e3 = eL[wv][j + 3];
        float w0 = head128 ? e0.y : e0.x, w1 = head128 ? e1.y : e1.x;
        float w2 = head128 ? e2.y : e2.x, w3 = head128 ? e3.y : e3.x;
        acc0 = fmaf(w0, blo(v0), fmaf(w1, blo(v1), acc0));
        acc1 = fmaf(w0, bhi(v0), fmaf(w1, bhi(v1), acc1));
        a0x  = fmaf(w2, blo(v2), fmaf(w3, blo(v3), a0x));
        a1x  = fmaf(w2, bhi(v2), fmaf(w3, bhi(v3), a1x));
      }
      for (; j < deg; ++j) {
        int s0 = sL[wv][j];
        uint32 v0 = xb32[(size_t)s0 * 64 + lane];
        float2 e0 = eL[wv][j];
        float w0 = head128 ? e0.y : e0.x;
        acc0 = fmaf(w0, blo(v0), acc0);
        acc1 = fmaf(w0, bhi(v0), acc1);
      }
      acc0 += a0x; acc1 += a1x;
    } else {
      float a0x = 0.f, a1x = 0.f;
      int j = 0;
      for (; j + 4 <= deg; j += 4) {
        int jj0 = j + hh, jj1 = j + 2 + hh;
        int s0 = sL[wv][jj0], s1 = sL[wv][jj1];
        uint32 v0 = xb32[(size_t)s0 * 32 + c];
        uint32 v1 = xb32[(size_t)s1 * 32 + c];
        float2 e0 = eL[wv][jj0], e1 = eL[wv][jj1];
        float w0 = head64 ? e0.y : e0.x, w1 = head64 ? e1.y : e1.x;
        acc0 = fmaf(w0, blo(v0), acc0);
        acc1 = fmaf(w0, bhi(v0), acc1);
        a0x  = fmaf(w1, blo(v1), a0x);
        a1x  = fmaf(w1, bhi(v1), a1x);
      }
      for (; j < deg; j += 2) {
        int jj = j + hh;
        float w0 = 0.f; uint32 v0 = 0;
        if (jj < deg) {
          int s = sL[wv][jj];
          v0 = xb32[(size_t)s * 32 + c];
          float2 e = eL[wv][jj];
          w0 = head64 ? e.y : e.x;
        }
        acc0 = fmaf(w0, blo(v0), acc0);
        acc1 = fmaf(w0, bhi(v0), acc1);
      }
      acc0 += a0x; acc1 += a1x;
    }
  } else {
    // fallback: deg > MAXD
    for (int i = start + lane; i < end; i += 64) {
      int s = sorted_src[i];
      float4 a = al4[s];
      float l0 = a.x + ad0; l0 = l0 > 0.f ? l0 : 0.2f * l0;
      float l1 = a.y + ad1; l1 = l1 > 0.f ? l1 : 0.2f * l1;
      m0 = fmaxf(m0, l0); m1 = fmaxf(m1, l1);
    }
    for (int off = 32; off >= 1; off >>= 1) {
      m0 = fmaxf(m0, __shfl_xor(m0, off));
      m1 = fmaxf(m1, __shfl_xor(m1, off));
    }
    for (int i = start + lane; i < end; i += 64) {
      int s = sorted_src[i];
      float4 a = al4[s];
      float l0 = a.x + ad0; l0 = l0 > 0.f ? l0 : 0.2f * l0;
      float l1 = a.y + ad1; l1 = l1 > 0.f ? l1 : 0.2f * l1;
      d0 += __expf(l0 - m0); d1 += __expf(l1 - m1);
    }
    for (int off = 32; off >= 1; off >>= 1) {
      d0 += __shfl_xor(d0, off);
      d1 += __shfl_xor(d1, off);
    }
    const float inv0 = 1.f / d0, inv1 = 1.f / d1;
    if (HC == 128) {
      const float invh = head128 ? inv1 : inv0;
      const float mh = head128 ? m1 : m0;
      const float adh = head128 ? ad1 : ad0;
      for (int i = start; i < end; ++i) {
        int s = sorted_src[i];
        float lv = al[s * 4 + head128] + adh;
        lv = lv > 0.f ? lv : 0.2f * lv;
        float a0 = __expf(lv - mh) * invh;
        uint32 v0 = xb32[(size_t)s * 64 + lane];
        acc0 = fmaf(a0, blo(v0), acc0);
        acc1 = fmaf(a0, bhi(v0), acc1);
      }
    } else {
      const float invh = head64 ? inv1 : inv0;
      const float mh = head64 ? m1 : m0;
      const float adh = head64 ? ad1 : ad0;
      for (int j = 0; j < deg; j += 2) {
        int jj = j + hh;
        float a0 = 0.f; uint32 v0 = 0;
        if (jj < deg) {
          int s = sorted_src[start + jj];
          float lv = al[s * 4 + head64] + adh;
          lv = lv > 0.f ? lv : 0.2f * lv;
          a0 = __expf(lv - mh) * invh;
          v0 = xb32[(size_t)s * 32 + c];
        }
        acc0 = fmaf(a0, blo(v0), acc0);
        acc1 = fmaf(a0, bhi(v0), acc1);
      }
    }
  }

  if (HC == 128) {
    float o0 = acc0 + bias[lane * 2];
    float o1 = acc1 + bias[lane * 2 + 1];
    o0 = o0 > 0.f ? o0 : __expf(o0) - 1.f;
    o1 = o1 > 0.f ? o1 : __expf(o1) - 1.f;
    if (OUTBF) {
      ((uint32*)outp)[(size_t)wid * 64 + lane] = pack2bf(o0, o1);
    } else {
      *reinterpret_cast<float2*>((float*)outp + (size_t)wid * 128 + lane * 2) = make_float2(o0, o1);
    }
  } else {
    acc0 += __shfl_xor(acc0, 32);
    acc1 += __shfl_xor(acc1, 32);
    if (hh == 0) {
      float o0 = acc0 + bias[c * 2];
      float o1 = acc1 + bias[c * 2 + 1];
      o0 = o0 > 0.f ? o0 : __expf(o0) - 1.f;
      o1 = o1 > 0.f ? o1 : __expf(o1) - 1.f;
      *reinterpret_cast<float2*>((float*)outp + (size_t)wid * 64 + c * 2) = make_float2(o0, o1);
    }
  }
}

__global__ void copy4_kernel(const float4* __restrict__ in, float4* __restrict__ out, int n4) {
  int i = blockIdx.x * blockDim.x + threadIdx.x;
  if (i < n4) out[i] = in[i];
}

extern "C" void kernel_launch(void* const* d_in, const int* in_sizes, int n_in,
                              void* d_out, int out_size, void* d_ws, size_t ws_size,
                              hipStream_t stream) {
  const float* x      = (const float*)d_in[0];
  const int*   ei     = (const int*)d_in[1];
  const float* W1     = (const float*)d_in[2];
  const float* a_src1 = (const float*)d_in[3];
  const float* a_dst1 = (const float*)d_in[4];
  const float* b1     = (const float*)d_in[5];
  const float* W2     = (const float*)d_in[6];
  const float* a_src2 = (const float*)d_in[7];
  const float* a_dst2 = (const float*)d_in[8];
  const float* b2     = (const float*)d_in[9];
  float* out = (float*)d_out;

  char* ws = (char*)d_ws;
  size_t off = 0;
  auto alloc = [&](size_t bytes) {
    void* p = ws + off;
    off = (off + bytes + 255) & ~(size_t)255;
    return p;
  };
  ushort* xb1       = (ushort*)alloc((size_t)N_NODES * 128 * 2);
  ushort* h1b       = (ushort*)alloc((size_t)N_NODES * 128 * 2);  // layer-1 output, bf16
  ushort* xb2       = (ushort*)alloc((size_t)N_NODES * 64 * 2);
  float*  al1       = (float*)alloc((size_t)N_NODES * 4 * 4);
  float*  al2       = (float*)alloc((size_t)N_NODES * 4 * 4);
  int*    counts    = (int*)alloc((size_t)N_NODES * 4);
  int*    row_start = (int*)alloc((size_t)(N_NODES + 1) * 4);
  int*    bsum      = (int*)alloc(256 * 4);
  int*    boff      = (int*)alloc(256 * 4);
  int*    bcur      = (int*)alloc(NBUCK * 4);
  int*    sorted_src= (int*)alloc((size_t)EA * 4);
  uint32* ebuf      = (uint32*)h1b;   // alias: h1b not live until agg1; 196*BCAP*4 <= h1b size

  const int* src = ei;
  const int* dst = ei + N_EDGES;

  const int nodeBlocks = (N_NODES + 255) / 256;   // 196
  const int waveBlocks = (N_NODES * 64) / 256;
  const int partBlocks = (N_EDGES + EPB - 1) / EPB;
  const int gemmBlocks = (N_NODES + 63) / 64;     // 782

  // ---- CSR by destination (two-level scatter, LDS-only histograms) ----
  init_bcur_kernel<<<1, 256, 0, stream>>>(bcur);
  partA_kernel<<<partBlocks, 256, 0, stream>>>(src, dst, bcur, ebuf);
  bucket_hist_kernel<<<NBUCK, 256, 0, stream>>>(ebuf, bcur, counts);
  scanA_kernel<<<nodeBlocks, 256, 0, stream>>>(counts, row_start, bsum, N_NODES);
  scanB_kernel<<<1, 256, 0, stream>>>(bsum, boff, nodeBlocks, &row_start[N_NODES]);
  scanC_kernel<<<nodeBlocks, 256, 0, stream>>>(row_start, boff, N_NODES);
  partB_kernel<<<NBUCK, 256, 0, stream>>>(row_start, ebuf, bcur, sorted_src);

  // ---- layer 1 ----
  gemm_mfma_kernel<128, false><<<gemmBlocks, 256, 0, stream>>>(x, W1, a_src1, a_dst1, xb1, al1, N_NODES);
  agg_kernel<128, true><<<waveBlocks, 256, 0, stream>>>(xb1, al1, row_start, sorted_src, b1, h1b);

  // ---- layer 2 ----
  gemm_mfma_kernel<64, true><<<gemmBlocks, 256, 0, stream>>>(h1b, W2, a_src2, a_dst2, xb2, al2, N_NODES);
  agg_kernel<64, false><<<waveBlocks, 256, 0, stream>>>(xb2, al2, row_start, sorted_src, b2, out);

  // ---- encoded passthrough ----
  copy4_kernel<<<((N_NODES * 128 / 4) + 255) / 256, 256, 0, stream>>>(
      (const float4*)x, (float4*)(out + (size_t)N_NODES * 64), N_NODES * 128 / 4);
}

// Round 6
// 196.253 us; speedup vs baseline: 3.5566x; 1.0465x over previous
//
#include <hip/hip_runtime.h>
#include <math.h>

#define N_NODES 50000
#define N_EDGES 1600000
#define EA (N_EDGES + N_NODES)
#define MAXD 128
#define NBUCK 196         // ceil(N_NODES / 256)
#define EPB 4096          // edges per workgroup in partition pass
#define BCAP 16000        // ebuf words per bucket (196*BCAP*4B fits h1b alias)

typedef unsigned int uint32;
typedef float f32x4 __attribute__((ext_vector_type(4)));
typedef short s16x8 __attribute__((ext_vector_type(8)));

__device__ inline ushort f2bf(float f) {
  uint32 u = __float_as_uint(f);
  u += 0x7fffu + ((u >> 16) & 1u);
  return (ushort)(u >> 16);
}
__device__ inline float blo(uint32 v) { return __uint_as_float(v << 16); }
__device__ inline float bhi(uint32 v) { return __uint_as_float(v & 0xffff0000u); }
__device__ inline uint32 pack2bf(float a, float b) {
  return (uint32)f2bf(a) | ((uint32)f2bf(b) << 16);
}

// ---------------- MFMA GEMM + fused attention-logit epilogue ----------------
// C(bf16)[M][N] = A[M][128] * B[128][N];  al[n] = {src_h0,src_h1,dst_h0,dst_h1}
template<int N, bool ABF>
__global__ __launch_bounds__(256) void gemm_mfma_kernel(
    const void* __restrict__ Ap, const float* __restrict__ B,
    const float* __restrict__ asrc, const float* __restrict__ adst,
    ushort* __restrict__ Cb, float* __restrict__ al, int M) {
  constexpr int KK = 4;              // 128 / 32
  constexpr int NC = N / 16;         // 8 or 4 column fragments
  __shared__ uint32 Bl[KK * NC * 64 * 4];   // 16B chunk per (kk,c,lane)
  const int t = threadIdx.x;

  for (int id = t; id < KK * NC * 64; id += 256) {
    int lane = id & 63;
    int cf = (id >> 6) % NC;
    int kk = (id >> 6) / NC;
    int col = cf * 16 + (lane & 15);
    int k0 = kk * 32 + (lane >> 4) * 8;
    uint32 w0 = pack2bf(B[(k0 + 0) * N + col], B[(k0 + 1) * N + col]);
    uint32 w1 = pack2bf(B[(k0 + 2) * N + col], B[(k0 + 3) * N + col]);
    uint32 w2 = pack2bf(B[(k0 + 4) * N + col], B[(k0 + 5) * N + col]);
    uint32 w3 = pack2bf(B[(k0 + 6) * N + col], B[(k0 + 7) * N + col]);
    *reinterpret_cast<uint4*>(&Bl[id * 4]) = make_uint4(w0, w1, w2, w3);
  }
  __syncthreads();

  const int w = t >> 6, lane = t & 63;
  const int l15 = lane & 15, g4 = lane >> 4;
  const int row0 = blockIdx.x * 64 + w * 16;
  int arow = row0 + l15; if (arow > M - 1) arow = M - 1;
  const int k0 = g4 * 8;

  f32x4 acc[NC];
#pragma unroll
  for (int c = 0; c < NC; ++c) acc[c] = f32x4{0.f, 0.f, 0.f, 0.f};

#pragma unroll
  for (int kk = 0; kk < KK; ++kk) {
    s16x8 af;
    if (ABF) {
      af = *reinterpret_cast<const s16x8*>((const ushort*)Ap + (size_t)arow * 128 + kk * 32 + k0);
    } else {
      const float* A = (const float*)Ap;
      float4 a0 = *reinterpret_cast<const float4*>(A + (size_t)arow * 128 + kk * 32 + k0);
      float4 a1 = *reinterpret_cast<const float4*>(A + (size_t)arow * 128 + kk * 32 + k0 + 4);
      union { uint32 u[4]; s16x8 v; } p;
      p.u[0] = pack2bf(a0.x, a0.y);
      p.u[1] = pack2bf(a0.z, a0.w);
      p.u[2] = pack2bf(a1.x, a1.y);
      p.u[3] = pack2bf(a1.z, a1.w);
      af = p.v;
    }
#pragma unroll
    for (int c = 0; c < NC; ++c) {
      s16x8 bf = *reinterpret_cast<const s16x8*>(&Bl[((kk * NC + c) * 64 + lane) * 4]);
      acc[c] = __builtin_amdgcn_mfma_f32_16x16x32_bf16(af, bf, acc[c], 0, 0, 0);
    }
  }

  float as_c[NC], ad_c[NC];
#pragma unroll
  for (int c = 0; c < NC; ++c) { as_c[c] = asrc[c * 16 + l15]; ad_c[c] = adst[c * 16 + l15]; }
#pragma unroll
  for (int reg = 0; reg < 4; ++reg) {
    int row = row0 + g4 * 4 + reg;
    bool ok = row < M;
    float ps0 = 0.f, ps1 = 0.f, pd0 = 0.f, pd1 = 0.f;
#pragma unroll
    for (int c = 0; c < NC; ++c) {
      float v = acc[c][reg];
      if (ok) Cb[(size_t)row * N + c * 16 + l15] = f2bf(v);
      if (c < NC / 2) { ps0 += v * as_c[c]; pd0 += v * ad_c[c]; }
      else            { ps1 += v * as_c[c]; pd1 += v * ad_c[c]; }
    }
#pragma unroll
    for (int off = 8; off >= 1; off >>= 1) {
      ps0 += __shfl_xor(ps0, off); ps1 += __shfl_xor(ps1, off);
      pd0 += __shfl_xor(pd0, off); pd1 += __shfl_xor(pd1, off);
    }
    if (ok && l15 == 0)
      *reinterpret_cast<float4*>(&al[row * 4]) = make_float4(ps0, ps1, pd0, pd1);
  }
}

// ---------------- CSR build (no global-atomic histogram) ----------------
__global__ void init_bcur_kernel(int* __restrict__ bcur) {
  int b = blockIdx.x * blockDim.x + threadIdx.x;
  if (b < NBUCK) bcur[b] = b * BCAP;
}

// ---- Pass A: partition edges into 196 coarse buckets (fixed-capacity slices) ----
__global__ void partA_kernel(const int* __restrict__ src, const int* __restrict__ dst,
                             int* __restrict__ bcur, uint32* __restrict__ ebuf) {
  __shared__ int h[NBUCK];
  __shared__ int lo[NBUCK + 1];
  __shared__ int rank_[NBUCK];
  __shared__ int gbase[NBUCK];
  __shared__ uint32 staged[EPB];
  const int t = threadIdx.x;
  const int e0 = blockIdx.x * EPB;
  const int ne = min(EPB, N_EDGES - e0);

  for (int i = t; i < NBUCK; i += 256) h[i] = 0;
  __syncthreads();
  for (int i = t; i < ne; i += 256) {
    int d = dst[e0 + i];
    atomicAdd(&h[d >> 8], 1);
  }
  __syncthreads();
  if (t == 0) {
    int a = 0;
    for (int b = 0; b < NBUCK; ++b) { lo[b] = a; a += h[b]; }
    lo[NBUCK] = a;
  }
  __syncthreads();
  for (int i = t; i < NBUCK; i += 256) rank_[i] = lo[i];
  __syncthreads();
  for (int i = t; i < ne; i += 256) {
    int d = dst[e0 + i];
    int s = src[e0 + i];
    int b = d >> 8;
    int r = atomicAdd(&rank_[b], 1);
    staged[r] = ((uint32)s << 8) | (uint32)(d & 255);
  }
  __syncthreads();
  if (t < NBUCK) gbase[t] = atomicAdd(&bcur[t], h[t]);
  __syncthreads();
  for (int i = t; i < ne; i += 256) {
    int a = 0, b = NBUCK;
    while (b - a > 1) { int mid = (a + b) >> 1; if (lo[mid] <= i) a = mid; else b = mid; }
    ebuf[gbase[a] + (i - lo[a])] = staged[i];
  }
}

// ---- per-bucket LDS histogram -> counts (self loop folded in) ----
__global__ void bucket_hist_kernel(const uint32* __restrict__ ebuf, const int* __restrict__ bcur,
                                   int* __restrict__ counts) {
  __shared__ int h[256];
  const int b = blockIdx.x;
  const int t = threadIdx.x;
  h[t] = 0;
  __syncthreads();
  const int base = b * BCAP;
  const int ee = bcur[b];
  for (int i = base + t; i < ee; i += 256) {
    uint32 w = ebuf[i];
    atomicAdd(&h[w & 255], 1);
  }
  __syncthreads();
  int n = b * 256 + t;
  if (n < N_NODES) counts[n] = h[t] + 1;   // +1 self loop
}

__global__ void scanA_kernel(const int* __restrict__ counts, int* __restrict__ row_start,
                             int* __restrict__ bsum, int n) {
  __shared__ int wsh[4];
  const int t = threadIdx.x, lane = t & 63, wv = t >> 6;
  int i = blockIdx.x * 256 + t;
  int v = (i < n) ? counts[i] : 0;
  int x = v;
  for (int off = 1; off < 64; off <<= 1) {
    int y = __shfl_up(x, off);
    if (lane >= off) x += y;
  }
  if (lane == 63) wsh[wv] = x;
  __syncthreads();
  int wo = 0;
  for (int w = 0; w < wv; ++w) wo += wsh[w];
  if (i < n) row_start[i] = wo + x - v;
  if (t == 255) bsum[blockIdx.x] = wo + x;
}

__global__ void scanB_kernel(const int* __restrict__ bsum, int* __restrict__ boff,
                             int nb, int* __restrict__ total_out) {
  __shared__ int wsh[4];
  const int t = threadIdx.x, lane = t & 63, wv = t >> 6;
  int v = (t < nb) ? bsum[t] : 0;
  int x = v;
  for (int off = 1; off < 64; off <<= 1) {
    int y = __shfl_up(x, off);
    if (lane >= off) x += y;
  }
  if (lane == 63) wsh[wv] = x;
  __syncthreads();
  int wo = 0;
  for (int w = 0; w < wv; ++w) wo += wsh[w];
  if (t < nb) boff[t] = wo + x - v;
  if (t == 255) total_out[0] = wo + x;
}

__global__ void scanC_kernel(int* __restrict__ row_start, const int* __restrict__ boff, int n) {
  int i = blockIdx.x * 256 + threadIdx.x;
  if (i < n) row_start[i] += boff[blockIdx.x];
}

// ---- Pass B: per-bucket local scatter, LDS cursors ----
__global__ void partB_kernel(const int* __restrict__ row_start, const uint32* __restrict__ ebuf,
                             const int* __restrict__ bcur, int* __restrict__ sorted_src) {
  __shared__ int cur[256];
  const int b = blockIdx.x;
  const int t = threadIdx.x;
  const int nb = b * 256;
  const int nn = min(256, N_NODES - nb);
  if (t < nn) {
    int n = nb + t;
    int rs = row_start[n];
    sorted_src[rs] = n;       // self loop first
    cur[t] = rs + 1;
  }
  __syncthreads();
  const int base = b * BCAP;
  const int ee = bcur[b];
  for (int i = base + t; i < ee; i += 256) {
    uint32 w = ebuf[i];
    int pos = atomicAdd(&cur[w & 255], 1);
    sorted_src[pos] = (int)(w >> 8);
  }
}

// ---------------- segment softmax + aggregate, one wave per dst node ----------------
// Main path: (src,weight) pairs pre-normalized & head-duplicated in LDS; gather via
// dwordx4 with 64/LPR edges per wave-iteration.
template<int HC, bool OUTBF>
__global__ __launch_bounds__(256) void agg_kernel(
    const ushort* __restrict__ xb, const float* __restrict__ al,
    const int* __restrict__ row_start, const int* __restrict__ sorted_src,
    const float* __restrict__ bias, void* __restrict__ outp) {
  __shared__ uint2 pL[4][2][MAXD];
  const int wid = (blockIdx.x * blockDim.x + threadIdx.x) >> 6;
  const int lane = threadIdx.x & 63;
  const int wv = (threadIdx.x >> 6) & 3;
  if (wid >= N_NODES) return;
  const float4* al4 = (const float4*)al;
  const uint32* xb32 = (const uint32*)xb;
  const int start = row_start[wid], end = row_start[wid + 1], deg = end - start;
  float4 mya = al4[wid];
  const float ad0 = mya.z, ad1 = mya.w;

  float m0 = -1e30f, m1 = -1e30f, d0 = 0.f, d1 = 0.f;

  if (deg > MAXD) {
    // ---- fallback: recompute per edge (not expected for this graph) ----
    const int c = lane & 31, hh = lane >> 5;
    const int head64 = c >> 4;
    const int head128 = lane >> 5;
    float acc0 = 0.f, acc1 = 0.f;
    for (int i = start + lane; i < end; i += 64) {
      int s = sorted_src[i];
      float4 a = al4[s];
      float l0 = a.x + ad0; l0 = l0 > 0.f ? l0 : 0.2f * l0;
      float l1 = a.y + ad1; l1 = l1 > 0.f ? l1 : 0.2f * l1;
      m0 = fmaxf(m0, l0); m1 = fmaxf(m1, l1);
    }
    for (int off = 32; off >= 1; off >>= 1) {
      m0 = fmaxf(m0, __shfl_xor(m0, off));
      m1 = fmaxf(m1, __shfl_xor(m1, off));
    }
    for (int i = start + lane; i < end; i += 64) {
      int s = sorted_src[i];
      float4 a = al4[s];
      float l0 = a.x + ad0; l0 = l0 > 0.f ? l0 : 0.2f * l0;
      float l1 = a.y + ad1; l1 = l1 > 0.f ? l1 : 0.2f * l1;
      d0 += __expf(l0 - m0); d1 += __expf(l1 - m1);
    }
    for (int off = 32; off >= 1; off >>= 1) {
      d0 += __shfl_xor(d0, off);
      d1 += __shfl_xor(d1, off);
    }
    const float inv0 = 1.f / d0, inv1 = 1.f / d1;
    if (HC == 128) {
      const float invh = head128 ? inv1 : inv0;
      const float mh = head128 ? m1 : m0;
      const float adh = head128 ? ad1 : ad0;
      for (int i = start; i < end; ++i) {
        int s = sorted_src[i];
        float lv = al[s * 4 + head128] + adh;
        lv = lv > 0.f ? lv : 0.2f * lv;
        float a0 = __expf(lv - mh) * invh;
        uint32 v0 = xb32[(size_t)s * 64 + lane];
        acc0 = fmaf(a0, blo(v0), acc0);
        acc1 = fmaf(a0, bhi(v0), acc1);
      }
      float o0 = acc0 + bias[lane * 2];
      float o1 = acc1 + bias[lane * 2 + 1];
      o0 = o0 > 0.f ? o0 : __expf(o0) - 1.f;
      o1 = o1 > 0.f ? o1 : __expf(o1) - 1.f;
      if (OUTBF) ((uint32*)outp)[(size_t)wid * 64 + lane] = pack2bf(o0, o1);
      else *reinterpret_cast<float2*>((float*)outp + (size_t)wid * 128 + lane * 2) = make_float2(o0, o1);
    } else {
      const float invh = head64 ? inv1 : inv0;
      const float mh = head64 ? m1 : m0;
      const float adh = head64 ? ad1 : ad0;
      for (int j = 0; j < deg; j += 2) {
        int jj = j + hh;
        float a0 = 0.f; uint32 v0 = 0;
        if (jj < deg) {
          int s = sorted_src[start + jj];
          float lv = al[s * 4 + head64] + adh;
          lv = lv > 0.f ? lv : 0.2f * lv;
          a0 = __expf(lv - mh) * invh;
          v0 = xb32[(size_t)s * 32 + c];
        }
        acc0 = fmaf(a0, blo(v0), acc0);
        acc1 = fmaf(a0, bhi(v0), acc1);
      }
      acc0 += __shfl_xor(acc0, 32);
      acc1 += __shfl_xor(acc1, 32);
      if (hh == 0) {
        float o0 = acc0 + bias[c * 2];
        float o1 = acc1 + bias[c * 2 + 1];
        o0 = o0 > 0.f ? o0 : __expf(o0) - 1.f;
        o1 = o1 > 0.f ? o1 : __expf(o1) - 1.f;
        if (OUTBF) ((uint32*)outp)[(size_t)wid * 32 + c] = pack2bf(o0, o1);
        else *reinterpret_cast<float2*>((float*)outp + (size_t)wid * 64 + c * 2) = make_float2(o0, o1);
      }
    }
    return;
  }

  // ---- pass 1: leaky logits -> LDS pairs (s, logit), head-duplicated; segment max ----
  for (int i = start + lane; i < end; i += 64) {
    int s = sorted_src[i];
    float4 a = al4[s];
    float l0 = a.x + ad0; l0 = l0 > 0.f ? l0 : 0.2f * l0;
    float l1 = a.y + ad1; l1 = l1 > 0.f ? l1 : 0.2f * l1;
    int j = i - start;
    pL[wv][0][j] = make_uint2((uint32)s, __float_as_uint(l0));
    pL[wv][1][j] = make_uint2((uint32)s, __float_as_uint(l1));
    m0 = fmaxf(m0, l0); m1 = fmaxf(m1, l1);
  }
  for (int off = 32; off >= 1; off >>= 1) {
    m0 = fmaxf(m0, __shfl_xor(m0, off));
    m1 = fmaxf(m1, __shfl_xor(m1, off));
  }
  // ---- pass 2: exp + denom ----
  for (int j = lane; j < deg; j += 64) {
    float e0 = __expf(__uint_as_float(pL[wv][0][j].y) - m0);
    float e1 = __expf(__uint_as_float(pL[wv][1][j].y) - m1);
    pL[wv][0][j].y = __float_as_uint(e0);
    pL[wv][1][j].y = __float_as_uint(e1);
    d0 += e0; d1 += e1;
  }
  for (int off = 32; off >= 1; off >>= 1) {
    d0 += __shfl_xor(d0, off);
    d1 += __shfl_xor(d1, off);
  }
  const float inv0 = 1.f / d0, inv1 = 1.f / d1;
  // ---- pass 2.5: normalize weights in place ----
  for (int j = lane; j < deg; j += 64) {
    pL[wv][0][j].y = __float_as_uint(__uint_as_float(pL[wv][0][j].y) * inv0);
    pL[wv][1][j].y = __float_as_uint(__uint_as_float(pL[wv][1][j].y) * inv1);
  }

  // ---- pass 3: dwordx4 gather, 64/LPR edges per iteration ----
  constexpr int LPR = HC / 8;          // lanes per row: 16 (HC=128) / 8 (HC=64)
  constexpr int EPI = 64 / LPR;        // edges per iteration: 4 / 8
  constexpr int RS  = HC / 2;          // row stride in uint32
  const int q  = lane / LPR;           // edge slot within iteration
  const int cc = lane % LPR;           // 16B chunk within row
  const int hd = cc / (LPR / 2);       // head for cols [8cc, 8cc+8)
  const uint2* myP = &pL[wv][hd][0];
  const uint32* myx = xb32 + cc * 4;

  float acc[8];
#pragma unroll
  for (int k = 0; k < 8; ++k) acc[k] = 0.f;

  int j = 0;
  for (; j + 2 * EPI <= deg; j += 2 * EPI) {
    uint2 pa = myP[j + q];
    uint2 pb = myP[j + EPI + q];
    const uint4 va = *reinterpret_cast<const uint4*>(myx + (size_t)pa.x * RS);
    const uint4 vb = *reinterpret_cast<const uint4*>(myx + (size_t)pb.x * RS);
    float wa = __uint_as_float(pa.y), wb = __uint_as_float(pb.y);
    acc[0] = fmaf(wa, blo(va.x), acc[0]); acc[1] = fmaf(wa, bhi(va.x), acc[1]);
    acc[2] = fmaf(wa, blo(va.y), acc[2]); acc[3] = fmaf(wa, bhi(va.y), acc[3]);
    acc[4] = fmaf(wa, blo(va.z), acc[4]); acc[5] = fmaf(wa, bhi(va.z), acc[5]);
    acc[6] = fmaf(wa, blo(va.w), acc[6]); acc[7] = fmaf(wa, bhi(va.w), acc[7]);
    acc[0] = fmaf(wb, blo(vb.x), acc[0]); acc[1] = fmaf(wb, bhi(vb.x), acc[1]);
    acc[2] = fmaf(wb, blo(vb.y), acc[2]); acc[3] = fmaf(wb, bhi(vb.y), acc[3]);
    acc[4] = fmaf(wb, blo(vb.z), acc[4]); acc[5] = fmaf(wb, bhi(vb.z), acc[5]);
    acc[6] = fmaf(wb, blo(vb.w), acc[6]); acc[7] = fmaf(wb, bhi(vb.w), acc[7]);
  }
  for (; j < deg; j += EPI) {
    int jj = j + q;
    int jc = jj < deg ? jj : 0;
    uint2 p = myP[jc];
    float w = jj < deg ? __uint_as_float(p.y) : 0.f;
    const uint4 v = *reinterpret_cast<const uint4*>(myx + (size_t)p.x * RS);
    acc[0] = fmaf(w, blo(v.x), acc[0]); acc[1] = fmaf(w, bhi(v.x), acc[1]);
    acc[2] = fmaf(w, blo(v.y), acc[2]); acc[3] = fmaf(w, bhi(v.y), acc[3]);
    acc[4] = fmaf(w, blo(v.z), acc[4]); acc[5] = fmaf(w, bhi(v.z), acc[5]);
    acc[6] = fmaf(w, blo(v.w), acc[6]); acc[7] = fmaf(w, bhi(v.w), acc[7]);
  }

  // ---- reduce across edge slots ----
#pragma unroll
  for (int k = 0; k < 8; ++k) {
    if (LPR == 8) acc[k] += __shfl_xor(acc[k], 8);
    acc[k] += __shfl_xor(acc[k], 16);
    acc[k] += __shfl_xor(acc[k], 32);
  }

  // ---- epilogue: bias + ELU + store (first lane group) ----
  if (q == 0) {
    float o[8];
#pragma unroll
    for (int k = 0; k < 8; ++k) {
      float v = acc[k] + bias[cc * 8 + k];
      o[k] = v > 0.f ? v : __expf(v) - 1.f;
    }
    if (OUTBF) {
      uint4 u;
      u.x = pack2bf(o[0], o[1]); u.y = pack2bf(o[2], o[3]);
      u.z = pack2bf(o[4], o[5]); u.w = pack2bf(o[6], o[7]);
      *reinterpret_cast<uint4*>((uint32*)outp + (size_t)wid * RS + cc * 4) = u;
    } else {
      float* op = (float*)outp + (size_t)wid * HC + cc * 8;
      *reinterpret_cast<float4*>(op)     = make_float4(o[0], o[1], o[2], o[3]);
      *reinterpret_cast<float4*>(op + 4) = make_float4(o[4], o[5], o[6], o[7]);
    }
  }
}

__global__ void copy4_kernel(const float4* __restrict__ in, float4* __restrict__ out, int n4) {
  int i = blockIdx.x * blockDim.x + threadIdx.x;
  if (i < n4) out[i] = in[i];
}

extern "C" void kernel_launch(void* const* d_in, const int* in_sizes, int n_in,
                              void* d_out, int out_size, void* d_ws, size_t ws_size,
                              hipStream_t stream) {
  const float* x      = (const float*)d_in[0];
  const int*   ei     = (const int*)d_in[1];
  const float* W1     = (const float*)d_in[2];
  const float* a_src1 = (const float*)d_in[3];
  const float* a_dst1 = (const float*)d_in[4];
  const float* b1     = (const float*)d_in[5];
  const float* W2     = (const float*)d_in[6];
  const float* a_src2 = (const float*)d_in[7];
  const float* a_dst2 = (const float*)d_in[8];
  const float* b2     = (const float*)d_in[9];
  float* out = (float*)d_out;

  char* ws = (char*)d_ws;
  size_t off = 0;
  auto alloc = [&](size_t bytes) {
    void* p = ws + off;
    off = (off + bytes + 255) & ~(size_t)255;
    return p;
  };
  ushort* xb1       = (ushort*)alloc((size_t)N_NODES * 128 * 2);
  ushort* h1b       = (ushort*)alloc((size_t)N_NODES * 128 * 2);  // layer-1 output, bf16
  ushort* xb2       = (ushort*)alloc((size_t)N_NODES * 64 * 2);
  float*  al1       = (float*)alloc((size_t)N_NODES * 4 * 4);
  float*  al2       = (float*)alloc((size_t)N_NODES * 4 * 4);
  int*    counts    = (int*)alloc((size_t)N_NODES * 4);
  int*    row_start = (int*)alloc((size_t)(N_NODES + 1) * 4);
  int*    bsum      = (int*)alloc(256 * 4);
  int*    boff      = (int*)alloc(256 * 4);
  int*    bcur      = (int*)alloc(NBUCK * 4);
  int*    sorted_src= (int*)alloc((size_t)EA * 4);
  uint32* ebuf      = (uint32*)h1b;   // alias: h1b not live until agg1; 196*BCAP*4 <= h1b size

  const int* src = ei;
  const int* dst = ei + N_EDGES;

  const int nodeBlocks = (N_NODES + 255) / 256;   // 196
  const int waveBlocks = (N_NODES * 64) / 256;
  const int partBlocks = (N_EDGES + EPB - 1) / EPB;
  const int gemmBlocks = (N_NODES + 63) / 64;     // 782

  // ---- CSR by destination (two-level scatter, LDS-only histograms) ----
  init_bcur_kernel<<<1, 256, 0, stream>>>(bcur);
  partA_kernel<<<partBlocks, 256, 0, stream>>>(src, dst, bcur, ebuf);
  bucket_hist_kernel<<<NBUCK, 256, 0, stream>>>(ebuf, bcur, counts);
  scanA_kernel<<<nodeBlocks, 256, 0, stream>>>(counts, row_start, bsum, N_NODES);
  scanB_kernel<<<1, 256, 0, stream>>>(bsum, boff, nodeBlocks, &row_start[N_NODES]);
  scanC_kernel<<<nodeBlocks, 256, 0, stream>>>(row_start, boff, N_NODES);
  partB_kernel<<<NBUCK, 256, 0, stream>>>(row_start, ebuf, bcur, sorted_src);

  // ---- layer 1 ----
  gemm_mfma_kernel<128, false><<<gemmBlocks, 256, 0, stream>>>(x, W1, a_src1, a_dst1, xb1, al1, N_NODES);
  agg_kernel<128, true><<<waveBlocks, 256, 0, stream>>>(xb1, al1, row_start, sorted_src, b1, h1b);

  // ---- layer 2 ----
  gemm_mfma_kernel<64, true><<<gemmBlocks, 256, 0, stream>>>(h1b, W2, a_src2, a_dst2, xb2, al2, N_NODES);
  agg_kernel<64, false><<<waveBlocks, 256, 0, stream>>>(xb2, al2, row_start, sorted_src, b2, out);

  // ---- encoded passthrough ----
  copy4_kernel<<<((N_NODES * 128 / 4) + 255) / 256, 256, 0, stream>>>(
      (const float4*)x, (float4*)(out + (size_t)N_NODES * 64), N_NODES * 128 / 4);
}

// Round 8
// 186.820 us; speedup vs baseline: 3.7362x; 1.0505x over previous
//
#include <hip/hip_runtime.h>
#include <math.h>

#define N_NODES 50000
#define N_EDGES 1600000
#define EA (N_EDGES + N_NODES)
#define MAXD 128
#define NBUCK 196         // ceil(N_NODES / 256)
#define EPB 4096          // edges per workgroup in partition pass
#define BCAP 16000        // ebuf words per bucket (mean fill ~8163)

typedef unsigned int uint32;
typedef float f32x4 __attribute__((ext_vector_type(4)));
typedef short s16x8 __attribute__((ext_vector_type(8)));

__device__ inline ushort f2bf(float f) {
  uint32 u = __float_as_uint(f);
  u += 0x7fffu + ((u >> 16) & 1u);
  return (ushort)(u >> 16);
}
__device__ inline float blo(uint32 v) { return __uint_as_float(v << 16); }
__device__ inline float bhi(uint32 v) { return __uint_as_float(v & 0xffff0000u); }
__device__ inline uint32 pack2bf(float a, float b) {
  return (uint32)f2bf(a) | ((uint32)f2bf(b) << 16);
}
__device__ inline int clampi(int v, int lo, int hi) {
  return v < lo ? lo : (v > hi ? hi : v);
}

// ---------------- MFMA GEMM + fused attention-logit epilogue ----------------
template<int N, bool ABF>
__global__ __launch_bounds__(256) void gemm_mfma_kernel(
    const void* __restrict__ Ap, const float* __restrict__ B,
    const float* __restrict__ asrc, const float* __restrict__ adst,
    ushort* __restrict__ Cb, float* __restrict__ al, int M) {
  constexpr int KK = 4;
  constexpr int NC = N / 16;
  __shared__ uint32 Bl[KK * NC * 64 * 4];
  const int t = threadIdx.x;

  for (int id = t; id < KK * NC * 64; id += 256) {
    int lane = id & 63;
    int cf = (id >> 6) % NC;
    int kk = (id >> 6) / NC;
    int col = cf * 16 + (lane & 15);
    int k0 = kk * 32 + (lane >> 4) * 8;
    uint32 w0 = pack2bf(B[(k0 + 0) * N + col], B[(k0 + 1) * N + col]);
    uint32 w1 = pack2bf(B[(k0 + 2) * N + col], B[(k0 + 3) * N + col]);
    uint32 w2 = pack2bf(B[(k0 + 4) * N + col], B[(k0 + 5) * N + col]);
    uint32 w3 = pack2bf(B[(k0 + 6) * N + col], B[(k0 + 7) * N + col]);
    *reinterpret_cast<uint4*>(&Bl[id * 4]) = make_uint4(w0, w1, w2, w3);
  }
  __syncthreads();

  const int w = t >> 6, lane = t & 63;
  const int l15 = lane & 15, g4 = lane >> 4;
  const int row0 = blockIdx.x * 64 + w * 16;
  int arow = row0 + l15; if (arow > M - 1) arow = M - 1;
  const int k0 = g4 * 8;

  f32x4 acc[NC];
#pragma unroll
  for (int c = 0; c < NC; ++c) acc[c] = f32x4{0.f, 0.f, 0.f, 0.f};

#pragma unroll
  for (int kk = 0; kk < KK; ++kk) {
    s16x8 af;
    if (ABF) {
      af = *reinterpret_cast<const s16x8*>((const ushort*)Ap + (size_t)arow * 128 + kk * 32 + k0);
    } else {
      const float* A = (const float*)Ap;
      float4 a0 = *reinterpret_cast<const float4*>(A + (size_t)arow * 128 + kk * 32 + k0);
      float4 a1 = *reinterpret_cast<const float4*>(A + (size_t)arow * 128 + kk * 32 + k0 + 4);
      union { uint32 u[4]; s16x8 v; } p;
      p.u[0] = pack2bf(a0.x, a0.y);
      p.u[1] = pack2bf(a0.z, a0.w);
      p.u[2] = pack2bf(a1.x, a1.y);
      p.u[3] = pack2bf(a1.z, a1.w);
      af = p.v;
    }
#pragma unroll
    for (int c = 0; c < NC; ++c) {
      s16x8 bf = *reinterpret_cast<const s16x8*>(&Bl[((kk * NC + c) * 64 + lane) * 4]);
      acc[c] = __builtin_amdgcn_mfma_f32_16x16x32_bf16(af, bf, acc[c], 0, 0, 0);
    }
  }

  float as_c[NC], ad_c[NC];
#pragma unroll
  for (int c = 0; c < NC; ++c) { as_c[c] = asrc[c * 16 + l15]; ad_c[c] = adst[c * 16 + l15]; }
#pragma unroll
  for (int reg = 0; reg < 4; ++reg) {
    int row = row0 + g4 * 4 + reg;
    bool ok = row < M;
    float ps0 = 0.f, ps1 = 0.f, pd0 = 0.f, pd1 = 0.f;
#pragma unroll
    for (int c = 0; c < NC; ++c) {
      float v = acc[c][reg];
      if (ok) Cb[(size_t)row * N + c * 16 + l15] = f2bf(v);
      if (c < NC / 2) { ps0 += v * as_c[c]; pd0 += v * ad_c[c]; }
      else            { ps1 += v * as_c[c]; pd1 += v * ad_c[c]; }
    }
#pragma unroll
    for (int off = 8; off >= 1; off >>= 1) {
      ps0 += __shfl_xor(ps0, off); ps1 += __shfl_xor(ps1, off);
      pd0 += __shfl_xor(pd0, off); pd1 += __shfl_xor(pd1, off);
    }
    if (ok && l15 == 0)
      *reinterpret_cast<float4*>(&al[row * 4]) = make_float4(ps0, ps1, pd0, pd1);
  }
}

// ---------------- CSR build ----------------
__global__ void init_bcur_kernel(int* __restrict__ bcur) {
  int b = blockIdx.x * blockDim.x + threadIdx.x;
  if (b < NBUCK) bcur[b] = b * BCAP;
}

// ---- Pass A: partition edges into 196 coarse buckets (fixed-capacity slices) ----
__global__ void partA_kernel(const int* __restrict__ src, const int* __restrict__ dst,
                             int* __restrict__ bcur, uint32* __restrict__ ebuf) {
  __shared__ int h[NBUCK];
  __shared__ int lo[NBUCK + 1];
  __shared__ int rank_[NBUCK];
  __shared__ int gbase[NBUCK];
  __shared__ uint32 staged[EPB];
  const int t = threadIdx.x;
  const int e0 = blockIdx.x * EPB;
  const int ne = min(EPB, N_EDGES - e0);

  for (int i = t; i < NBUCK; i += 256) h[i] = 0;
  __syncthreads();
  for (int i = t; i < ne; i += 256) {
    int d = dst[e0 + i];
    atomicAdd(&h[d >> 8], 1);
  }
  __syncthreads();
  if (t == 0) {
    int a = 0;
    for (int b = 0; b < NBUCK; ++b) { lo[b] = a; a += h[b]; }
    lo[NBUCK] = a;
  }
  __syncthreads();
  for (int i = t; i < NBUCK; i += 256) rank_[i] = lo[i];
  __syncthreads();
  for (int i = t; i < ne; i += 256) {
    int d = dst[e0 + i];
    int s = src[e0 + i];
    int b = d >> 8;
    int r = atomicAdd(&rank_[b], 1);
    staged[r] = ((uint32)s << 8) | (uint32)(d & 255);
  }
  __syncthreads();
  if (t < NBUCK) gbase[t] = atomicAdd(&bcur[t], h[t]);
  __syncthreads();
  for (int i = t; i < ne; i += 256) {
    int a = 0, b = NBUCK;
    while (b - a > 1) { int mid = (a + b) >> 1; if (lo[mid] <= i) a = mid; else b = mid; }
    ebuf[gbase[a] + (i - lo[a])] = staged[i];
  }
}

// ---- scan over 196 bucket totals (edges + resident self-loops) ----
__global__ void scan196_kernel(const int* __restrict__ bcur, int* __restrict__ bbase,
                               int* __restrict__ row_start) {
  __shared__ int wsh[4];
  const int t = threadIdx.x, lane = t & 63, wv = t >> 6;
  int v = 0;
  if (t < NBUCK) {
    int nn = min(256, N_NODES - t * 256);
    v = (bcur[t] - t * BCAP) + nn;
  }
  int x = v;
  for (int off = 1; off < 64; off <<= 1) {
    int y = __shfl_up(x, off);
    if (lane >= off) x += y;
  }
  if (lane == 63) wsh[wv] = x;
  __syncthreads();
  int wo = 0;
  for (int w = 0; w < wv; ++w) wo += wsh[w];
  if (t < NBUCK) bbase[t] = wo + x - v;
  if (t == 0) row_start[N_NODES] = EA;
}

// ---- Pass B2: per-bucket LDS hist + scan + row_start + scatter (ebuf read once) ----
__global__ __launch_bounds__(256) void partB2_kernel(
    const int* __restrict__ bcur, const int* __restrict__ bbase,
    const uint32* __restrict__ ebuf, int* __restrict__ row_start,
    int* __restrict__ sorted_src) {
  __shared__ uint32 sl[BCAP];
  __shared__ int h[256];
  __shared__ int cur[256];
  __shared__ int wsh[4];
  const int b = blockIdx.x;
  const int t = threadIdx.x, lane = t & 63, wv = t >> 6;
  h[t] = 0;
  __syncthreads();
  const int base = b * BCAP;
  const int len = min(bcur[b] - base, BCAP);
  for (int i = t; i < len; i += 256) {
    uint32 w = ebuf[base + i];
    sl[i] = w;
    atomicAdd(&h[w & 255], 1);
  }
  __syncthreads();
  const int n = b * 256 + t;
  const bool valid = n < N_NODES;
  int v = valid ? h[t] + 1 : 0;       // +1 self loop
  int x = v;
  for (int off = 1; off < 64; off <<= 1) {
    int y = __shfl_up(x, off);
    if (lane >= off) x += y;
  }
  if (lane == 63) wsh[wv] = x;
  __syncthreads();
  int wo = 0;
  for (int w = 0; w < wv; ++w) wo += wsh[w];
  int rs = bbase[b] + wo + x - v;
  if (valid) {
    row_start[n] = rs;
    sorted_src[rs] = n;               // self loop first
    cur[t] = rs + 1;
  }
  __syncthreads();
  for (int i = t; i < len; i += 256) {
    uint32 w = sl[i];
    int pos = atomicAdd(&cur[w & 255], 1);
    sorted_src[pos] = (int)(w >> 8);
  }
}

// ---------------- segment softmax + aggregate, one wave per dst node ----------------
template<int HC, bool OUTBF>
__global__ __launch_bounds__(256) void agg_kernel(
    const ushort* __restrict__ xb, const float* __restrict__ al,
    const int* __restrict__ row_start, const int* __restrict__ sorted_src,
    const float* __restrict__ bias, void* __restrict__ outp) {
  __shared__ uint2 pL[4][2][MAXD];
  const int wid = (blockIdx.x * blockDim.x + threadIdx.x) >> 6;
  const int lane = threadIdx.x & 63;
  const int wv = (threadIdx.x >> 6) & 3;
  if (wid >= N_NODES) return;
  const float4* al4 = (const float4*)al;
  const uint32* xb32 = (const uint32*)xb;
  int start = row_start[wid], end = row_start[wid + 1];
  start = clampi(start, 0, EA);                 // fault-proofing (no-op when CSR correct)
  end   = clampi(end, start, EA);
  const int deg = end - start;
  float4 mya = al4[wid];
  const float ad0 = mya.z, ad1 = mya.w;

  float m0 = -1e30f, m1 = -1e30f, d0 = 0.f, d1 = 0.f;

  if (deg > MAXD) {
    // ---- fallback (cold): recompute per edge ----
    const int c = lane & 31, hh = lane >> 5;
    const int head64 = c >> 4;
    const int head128 = lane >> 5;
    float acc0 = 0.f, acc1 = 0.f;
    for (int i = start + lane; i < end; i += 64) {
      int s = clampi(sorted_src[i], 0, N_NODES - 1);
      float4 a = al4[s];
      float l0 = a.x + ad0; l0 = l0 > 0.f ? l0 : 0.2f * l0;
      float l1 = a.y + ad1; l1 = l1 > 0.f ? l1 : 0.2f * l1;
      m0 = fmaxf(m0, l0); m1 = fmaxf(m1, l1);
    }
    for (int off = 32; off >= 1; off >>= 1) {
      m0 = fmaxf(m0, __shfl_xor(m0, off));
      m1 = fmaxf(m1, __shfl_xor(m1, off));
    }
    for (int i = start + lane; i < end; i += 64) {
      int s = clampi(sorted_src[i], 0, N_NODES - 1);
      float4 a = al4[s];
      float l0 = a.x + ad0; l0 = l0 > 0.f ? l0 : 0.2f * l0;
      float l1 = a.y + ad1; l1 = l1 > 0.f ? l1 : 0.2f * l1;
      d0 += __expf(l0 - m0); d1 += __expf(l1 - m1);
    }
    for (int off = 32; off >= 1; off >>= 1) {
      d0 += __shfl_xor(d0, off);
      d1 += __shfl_xor(d1, off);
    }
    const float inv0 = 1.f / d0, inv1 = 1.f / d1;
    if (HC == 128) {
      const float invh = head128 ? inv1 : inv0;
      const float mh = head128 ? m1 : m0;
      const float adh = head128 ? ad1 : ad0;
      for (int i = start; i < end; ++i) {
        int s = clampi(sorted_src[i], 0, N_NODES - 1);
        float lv = al[s * 4 + head128] + adh;
        lv = lv > 0.f ? lv : 0.2f * lv;
        float a0 = __expf(lv - mh) * invh;
        uint32 v0 = xb32[(size_t)s * 64 + lane];
        acc0 = fmaf(a0, blo(v0), acc0);
        acc1 = fmaf(a0, bhi(v0), acc1);
      }
      float o0 = acc0 + bias[lane * 2];
      float o1 = acc1 + bias[lane * 2 + 1];
      o0 = o0 > 0.f ? o0 : __expf(o0) - 1.f;
      o1 = o1 > 0.f ? o1 : __expf(o1) - 1.f;
      if (OUTBF) ((uint32*)outp)[(size_t)wid * 64 + lane] = pack2bf(o0, o1);
      else *reinterpret_cast<float2*>((float*)outp + (size_t)wid * 128 + lane * 2) = make_float2(o0, o1);
    } else {
      const float invh = head64 ? inv1 : inv0;
      const float mh = head64 ? m1 : m0;
      const float adh = head64 ? ad1 : ad0;
      for (int j = 0; j < deg; j += 2) {
        int jj = j + hh;
        float a0 = 0.f; uint32 v0 = 0;
        if (jj < deg) {
          int s = clampi(sorted_src[start + jj], 0, N_NODES - 1);
          float lv = al[s * 4 + head64] + adh;
          lv = lv > 0.f ? lv : 0.2f * lv;
          a0 = __expf(lv - mh) * invh;
          v0 = xb32[(size_t)s * 32 + c];
        }
        acc0 = fmaf(a0, blo(v0), acc0);
        acc1 = fmaf(a0, bhi(v0), acc1);
      }
      acc0 += __shfl_xor(acc0, 32);
      acc1 += __shfl_xor(acc1, 32);
      if (hh == 0) {
        float o0 = acc0 + bias[c * 2];
        float o1 = acc1 + bias[c * 2 + 1];
        o0 = o0 > 0.f ? o0 : __expf(o0) - 1.f;
        o1 = o1 > 0.f ? o1 : __expf(o1) - 1.f;
        if (OUTBF) ((uint32*)outp)[(size_t)wid * 32 + c] = pack2bf(o0, o1);
        else *reinterpret_cast<float2*>((float*)outp + (size_t)wid * 64 + c * 2) = make_float2(o0, o1);
      }
    }
    return;
  }

  // ---- pass 1: leaky logits -> LDS pairs (s, logit), head-duplicated; segment max ----
  for (int i = start + lane; i < end; i += 64) {
    int s = clampi(sorted_src[i], 0, N_NODES - 1);
    float4 a = al4[s];
    float l0 = a.x + ad0; l0 = l0 > 0.f ? l0 : 0.2f * l0;
    float l1 = a.y + ad1; l1 = l1 > 0.f ? l1 : 0.2f * l1;
    int j = i - start;
    pL[wv][0][j] = make_uint2((uint32)s, __float_as_uint(l0));
    pL[wv][1][j] = make_uint2((uint32)s, __float_as_uint(l1));
    m0 = fmaxf(m0, l0); m1 = fmaxf(m1, l1);
  }
  for (int off = 32; off >= 1; off >>= 1) {
    m0 = fmaxf(m0, __shfl_xor(m0, off));
    m1 = fmaxf(m1, __shfl_xor(m1, off));
  }
  // ---- pass 2: exp + denom ----
  for (int j = lane; j < deg; j += 64) {
    float e0 = __expf(__uint_as_float(pL[wv][0][j].y) - m0);
    float e1 = __expf(__uint_as_float(pL[wv][1][j].y) - m1);
    pL[wv][0][j].y = __float_as_uint(e0);
    pL[wv][1][j].y = __float_as_uint(e1);
    d0 += e0; d1 += e1;
  }
  for (int off = 32; off >= 1; off >>= 1) {
    d0 += __shfl_xor(d0, off);
    d1 += __shfl_xor(d1, off);
  }
  const float inv0 = 1.f / d0, inv1 = 1.f / d1;
  // ---- pass 2.5: normalize in place ----
  for (int j = lane; j < deg; j += 64) {
    pL[wv][0][j].y = __float_as_uint(__uint_as_float(pL[wv][0][j].y) * inv0);
    pL[wv][1][j].y = __float_as_uint(__uint_as_float(pL[wv][1][j].y) * inv1);
  }

  // ---- pass 3: dwordx4 gather, 64/LPR edges per iteration ----
  constexpr int LPR = HC / 8;          // lanes per row: 16 (HC=128) / 8 (HC=64)
  constexpr int EPI = 64 / LPR;
  constexpr int RS  = HC / 2;          // row stride in dwords
  const int q  = lane / LPR;
  const int cc = lane % LPR;
  const int hd = cc / (LPR / 2);
  const uint2* myP = &pL[wv][hd][0];
  const uint32* myx = xb32 + cc * 4;

  float acc[8];
#pragma unroll
  for (int k = 0; k < 8; ++k) acc[k] = 0.f;

  int j = 0;
  for (; j + 2 * EPI <= deg; j += 2 * EPI) {
    uint2 pa = myP[j + q];
    uint2 pb = myP[j + EPI + q];
    const uint4 va = *reinterpret_cast<const uint4*>(myx + (size_t)pa.x * RS);
    const uint4 vb = *reinterpret_cast<const uint4*>(myx + (size_t)pb.x * RS);
    float wa = __uint_as_float(pa.y), wb = __uint_as_float(pb.y);
    acc[0] = fmaf(wa, blo(va.x), acc[0]); acc[1] = fmaf(wa, bhi(va.x), acc[1]);
    acc[2] = fmaf(wa, blo(va.y), acc[2]); acc[3] = fmaf(wa, bhi(va.y), acc[3]);
    acc[4] = fmaf(wa, blo(va.z), acc[4]); acc[5] = fmaf(wa, bhi(va.z), acc[5]);
    acc[6] = fmaf(wa, blo(va.w), acc[6]); acc[7] = fmaf(wa, bhi(va.w), acc[7]);
    acc[0] = fmaf(wb, blo(vb.x), acc[0]); acc[1] = fmaf(wb, bhi(vb.x), acc[1]);
    acc[2] = fmaf(wb, blo(vb.y), acc[2]); acc[3] = fmaf(wb, bhi(vb.y), acc[3]);
    acc[4] = fmaf(wb, blo(vb.z), acc[4]); acc[5] = fmaf(wb, bhi(vb.z), acc[5]);
    acc[6] = fmaf(wb, blo(vb.w), acc[6]); acc[7] = fmaf(wb, bhi(vb.w), acc[7]);
  }
  for (; j < deg; j += EPI) {
    int jj = j + q;
    int jc = jj < deg ? jj : 0;
    uint2 p = myP[jc];
    float w = jj < deg ? __uint_as_float(p.y) : 0.f;
    const uint4 v = *reinterpret_cast<const uint4*>(myx + (size_t)p.x * RS);
    acc[0] = fmaf(w, blo(v.x), acc[0]); acc[1] = fmaf(w, bhi(v.x), acc[1]);
    acc[2] = fmaf(w, blo(v.y), acc[2]); acc[3] = fmaf(w, bhi(v.y), acc[3]);
    acc[4] = fmaf(w, blo(v.z), acc[4]); acc[5] = fmaf(w, bhi(v.z), acc[5]);
    acc[6] = fmaf(w, blo(v.w), acc[6]); acc[7] = fmaf(w, bhi(v.w), acc[7]);
  }

  // ---- reduce across edge slots ----
#pragma unroll
  for (int k = 0; k < 8; ++k) {
    if (LPR == 8) acc[k] += __shfl_xor(acc[k], 8);
    acc[k] += __shfl_xor(acc[k], 16);
    acc[k] += __shfl_xor(acc[k], 32);
  }

  // ---- epilogue: bias + ELU + store (first lane group) ----
  if (q == 0) {
    float o[8];
#pragma unroll
    for (int k = 0; k < 8; ++k) {
      float v = acc[k] + bias[cc * 8 + k];
      o[k] = v > 0.f ? v : __expf(v) - 1.f;
    }
    if (OUTBF) {
      uint4 u;
      u.x = pack2bf(o[0], o[1]); u.y = pack2bf(o[2], o[3]);
      u.z = pack2bf(o[4], o[5]); u.w = pack2bf(o[6], o[7]);
      *reinterpret_cast<uint4*>((uint32*)outp + (size_t)wid * RS + cc * 4) = u;
    } else {
      float* op = (float*)outp + (size_t)wid * HC + cc * 8;
      *reinterpret_cast<float4*>(op)     = make_float4(o[0], o[1], o[2], o[3]);
      *reinterpret_cast<float4*>(op + 4) = make_float4(o[4], o[5], o[6], o[7]);
    }
  }
}

__global__ void copy4_kernel(const float4* __restrict__ in, float4* __restrict__ out, int n4) {
  int i = blockIdx.x * blockDim.x + threadIdx.x;
  if (i < n4) out[i] = in[i];
}

extern "C" void kernel_launch(void* const* d_in, const int* in_sizes, int n_in,
                              void* d_out, int out_size, void* d_ws, size_t ws_size,
                              hipStream_t stream) {
  const float* x      = (const float*)d_in[0];
  const int*   ei     = (const int*)d_in[1];
  const float* W1     = (const float*)d_in[2];
  const float* a_src1 = (const float*)d_in[3];
  const float* a_dst1 = (const float*)d_in[4];
  const float* b1     = (const float*)d_in[5];
  const float* W2     = (const float*)d_in[6];
  const float* a_src2 = (const float*)d_in[7];
  const float* a_dst2 = (const float*)d_in[8];
  const float* b2     = (const float*)d_in[9];
  float* out = (float*)d_out;

  char* ws = (char*)d_ws;
  size_t off = 0;
  auto alloc = [&](size_t bytes) {
    void* p = ws + off;
    off = (off + bytes + 255) & ~(size_t)255;
    return p;
  };
  ushort* xb1       = (ushort*)alloc((size_t)N_NODES * 128 * 2);
  ushort* h1b       = (ushort*)alloc((size_t)N_NODES * 128 * 2);  // layer-1 output, bf16
  ushort* xb2       = (ushort*)alloc((size_t)N_NODES * 64 * 2);
  float*  al1       = (float*)alloc((size_t)N_NODES * 4 * 4);
  float*  al2       = (float*)alloc((size_t)N_NODES * 4 * 4);
  int*    row_start = (int*)alloc((size_t)(N_NODES + 1) * 4);
  int*    bbase     = (int*)alloc(256 * 4);
  int*    bcur      = (int*)alloc(NBUCK * 4);
  int*    sorted_src= (int*)alloc((size_t)EA * 4);
  uint32* ebuf      = (uint32*)h1b;   // alias: h1b not live until agg1; 196*BCAP*4 <= h1b size

  const int* src = ei;
  const int* dst = ei + N_EDGES;

  const int waveBlocks = (N_NODES * 64) / 256;
  const int partBlocks = (N_EDGES + EPB - 1) / EPB;
  const int gemmBlocks = (N_NODES + 63) / 64;

  // ---- CSR by destination (two-level scatter, single-read partB) ----
  init_bcur_kernel<<<1, 256, 0, stream>>>(bcur);
  partA_kernel<<<partBlocks, 256, 0, stream>>>(src, dst, bcur, ebuf);
  scan196_kernel<<<1, 256, 0, stream>>>(bcur, bbase, row_start);
  partB2_kernel<<<NBUCK, 256, 0, stream>>>(bcur, bbase, ebuf, row_start, sorted_src);

  // ---- layer 1 ----
  gemm_mfma_kernel<128, false><<<gemmBlocks, 256, 0, stream>>>(x, W1, a_src1, a_dst1, xb1, al1, N_NODES);
  agg_kernel<128, true><<<waveBlocks, 256, 0, stream>>>(xb1, al1, row_start, sorted_src, b1, h1b);

  // ---- layer 2 ----
  gemm_mfma_kernel<64, true><<<gemmBlocks, 256, 0, stream>>>(h1b, W2, a_src2, a_dst2, xb2, al2, N_NODES);
  agg_kernel<64, false><<<waveBlocks, 256, 0, stream>>>(xb2, al2, row_start, sorted_src, b2, out);

  // ---- encoded passthrough ----
  copy4_kernel<<<((N_NODES * 128 / 4) + 255) / 256, 256, 0, stream>>>(
      (const float4*)x, (float4*)(out + (size_t)N_NODES * 64), N_NODES * 128 / 4);
}

// Round 11
// 173.687 us; speedup vs baseline: 4.0187x; 1.0756x over previous
//
#include <hip/hip_runtime.h>
#include <math.h>

#define N_NODES 50000
#define N_EDGES 1600000
#define EA (N_EDGES + N_NODES)
#define MAXD 128
#define NBUCK 196         // ceil(N_NODES / 256)
#define EPB 4096          // edges per workgroup in partition pass
#define BCAP 16000        // ebuf words per bucket (mean fill ~8163)

typedef unsigned int uint32;
typedef float f32x4 __attribute__((ext_vector_type(4)));
typedef _Float16 h16x2 __attribute__((ext_vector_type(2)));
typedef _Float16 f16x8 __attribute__((ext_vector_type(8)));

__device__ inline h16x2 u2h(uint32 u) { return __builtin_bit_cast(h16x2, u); }
__device__ inline uint32 h2u(h16x2 h) { return __builtin_bit_cast(uint32, h); }
__device__ inline uint32 pkh(float a, float b) {      // pack 2 floats -> half2 (RTZ, 1 instr)
  return __builtin_bit_cast(uint32, __builtin_amdgcn_cvt_pkrtz(a, b));
}
__device__ inline ushort f2h(float f) {                // single f32 -> fp16 bits (RTE)
  _Float16 h = (_Float16)f;
  return __builtin_bit_cast(ushort, h);
}
__device__ inline int clampi(int v, int lo, int hi) {
  return v < lo ? lo : (v > hi ? hi : v);
}

// ---------------- MFMA(f16) GEMM + fused attention-logit epilogue ----------------
// C(fp16)[M][N] = A[M][128] * B[128][N];  al[n] = {src_h0,src_h1,dst_h0,dst_h1} (fp32)
template<int N, bool AF16>
__global__ __launch_bounds__(256) void gemm_mfma_kernel(
    const void* __restrict__ Ap, const float* __restrict__ B,
    const float* __restrict__ asrc, const float* __restrict__ adst,
    ushort* __restrict__ Cb, float* __restrict__ al, int M) {
  constexpr int KK = 4;
  constexpr int NC = N / 16;
  __shared__ uint32 Bl[KK * NC * 64 * 4];
  const int t = threadIdx.x;

  for (int id = t; id < KK * NC * 64; id += 256) {
    int lane = id & 63;
    int cf = (id >> 6) % NC;
    int kk = (id >> 6) / NC;
    int col = cf * 16 + (lane & 15);
    int k0 = kk * 32 + (lane >> 4) * 8;
    uint32 w0 = pkh(B[(k0 + 0) * N + col], B[(k0 + 1) * N + col]);
    uint32 w1 = pkh(B[(k0 + 2) * N + col], B[(k0 + 3) * N + col]);
    uint32 w2 = pkh(B[(k0 + 4) * N + col], B[(k0 + 5) * N + col]);
    uint32 w3 = pkh(B[(k0 + 6) * N + col], B[(k0 + 7) * N + col]);
    *reinterpret_cast<uint4*>(&Bl[id * 4]) = make_uint4(w0, w1, w2, w3);
  }
  __syncthreads();

  const int w = t >> 6, lane = t & 63;
  const int l15 = lane & 15, g4 = lane >> 4;
  const int row0 = blockIdx.x * 64 + w * 16;
  int arow = row0 + l15; if (arow > M - 1) arow = M - 1;
  const int k0 = g4 * 8;

  f32x4 acc[NC];
#pragma unroll
  for (int c = 0; c < NC; ++c) acc[c] = f32x4{0.f, 0.f, 0.f, 0.f};

#pragma unroll
  for (int kk = 0; kk < KK; ++kk) {
    f16x8 af;
    if (AF16) {
      af = *reinterpret_cast<const f16x8*>((const ushort*)Ap + (size_t)arow * 128 + kk * 32 + k0);
    } else {
      const float* A = (const float*)Ap;
      float4 a0 = *reinterpret_cast<const float4*>(A + (size_t)arow * 128 + kk * 32 + k0);
      float4 a1 = *reinterpret_cast<const float4*>(A + (size_t)arow * 128 + kk * 32 + k0 + 4);
      union { uint32 u[4]; f16x8 v; } p;
      p.u[0] = pkh(a0.x, a0.y);
      p.u[1] = pkh(a0.z, a0.w);
      p.u[2] = pkh(a1.x, a1.y);
      p.u[3] = pkh(a1.z, a1.w);
      af = p.v;
    }
#pragma unroll
    for (int c = 0; c < NC; ++c) {
      f16x8 bf = *reinterpret_cast<const f16x8*>(&Bl[((kk * NC + c) * 64 + lane) * 4]);
      acc[c] = __builtin_amdgcn_mfma_f32_16x16x32_f16(af, bf, acc[c], 0, 0, 0);
    }
  }

  float as_c[NC], ad_c[NC];
#pragma unroll
  for (int c = 0; c < NC; ++c) { as_c[c] = asrc[c * 16 + l15]; ad_c[c] = adst[c * 16 + l15]; }
#pragma unroll
  for (int reg = 0; reg < 4; ++reg) {
    int row = row0 + g4 * 4 + reg;
    bool ok = row < M;
    float ps0 = 0.f, ps1 = 0.f, pd0 = 0.f, pd1 = 0.f;
#pragma unroll
    for (int c = 0; c < NC; ++c) {
      float v = acc[c][reg];
      if (ok) Cb[(size_t)row * N + c * 16 + l15] = f2h(v);
      if (c < NC / 2) { ps0 += v * as_c[c]; pd0 += v * ad_c[c]; }
      else            { ps1 += v * as_c[c]; pd1 += v * ad_c[c]; }
    }
#pragma unroll
    for (int off = 8; off >= 1; off >>= 1) {
      ps0 += __shfl_xor(ps0, off); ps1 += __shfl_xor(ps1, off);
      pd0 += __shfl_xor(pd0, off); pd1 += __shfl_xor(pd1, off);
    }
    if (ok && l15 == 0)
      *reinterpret_cast<float4*>(&al[row * 4]) = make_float4(ps0, ps1, pd0, pd1);
  }
}

// ---------------- CSR build ----------------
__global__ void init_bcur_kernel(int* __restrict__ bcur) {
  int b = blockIdx.x * blockDim.x + threadIdx.x;
  if (b < NBUCK) bcur[b] = b * BCAP;
}

// ---- Pass A: partition edges into 196 coarse buckets (fixed-capacity slices) ----
// staged word layout: [31:24]=bucket, [23:8]=src (<65536), [7:0]=dst&255
__global__ void partA_kernel(const int* __restrict__ src, const int* __restrict__ dst,
                             int* __restrict__ bcur, uint32* __restrict__ ebuf) {
  __shared__ int h[NBUCK];
  __shared__ int lo[NBUCK];
  __shared__ int rank_[NBUCK];     // reused as gb2 after reservation
  __shared__ int gbase[NBUCK];
  __shared__ uint32 staged[EPB];
  const int t = threadIdx.x;
  const int e0 = blockIdx.x * EPB;
  const int ne = min(EPB, N_EDGES - e0);

  for (int i = t; i < NBUCK; i += 256) h[i] = 0;
  __syncthreads();
  for (int i = t; i < ne; i += 256) {
    int d = dst[e0 + i];
    atomicAdd(&h[d >> 8], 1);
  }
  __syncthreads();
  if (t == 0) {
    int a = 0;
    for (int b = 0; b < NBUCK; ++b) { lo[b] = a; a += h[b]; }
  }
  __syncthreads();
  for (int i = t; i < NBUCK; i += 256) rank_[i] = lo[i];
  __syncthreads();
  for (int i = t; i < ne; i += 256) {
    int d = dst[e0 + i];
    int s = src[e0 + i];
    int b = d >> 8;
    int r = atomicAdd(&rank_[b], 1);
    staged[r] = ((uint32)b << 24) | ((uint32)s << 8) | (uint32)(d & 255);
  }
  __syncthreads();
  if (t < NBUCK) gbase[t] = atomicAdd(&bcur[t], h[t]);
  __syncthreads();
  if (t < NBUCK) rank_[t] = gbase[t] - lo[t];   // gb2[b]
  __syncthreads();
  // coalesced copy-out; position = gb2[bucket] + i  (staged sorted by bucket)
  for (int i = t; i < ne; i += 256) {
    uint32 wd = staged[i];
    ebuf[rank_[wd >> 24] + i] = wd;
  }
}

// ---- scan over 196 bucket totals (edges + resident self-loops) ----
__global__ void scan196_kernel(const int* __restrict__ bcur, int* __restrict__ bbase,
                               int* __restrict__ row_start) {
  __shared__ int wsh[4];
  const int t = threadIdx.x, lane = t & 63, wv = t >> 6;
  int v = 0;
  if (t < NBUCK) {
    int nn = min(256, N_NODES - t * 256);
    v = (bcur[t] - t * BCAP) + nn;
  }
  int x = v;
  for (int off = 1; off < 64; off <<= 1) {
    int y = __shfl_up(x, off);
    if (lane >= off) x += y;
  }
  if (lane == 63) wsh[wv] = x;
  __syncthreads();
  int wo = 0;
  for (int w = 0; w < wv; ++w) wo += wsh[w];
  if (t < NBUCK) bbase[t] = wo + x - v;
  if (t == 0) row_start[N_NODES] = EA;
}

// ---- Pass B2: per-bucket LDS hist + scan + row_start + scatter (ebuf read once) ----
__global__ __launch_bounds__(256) void partB2_kernel(
    const int* __restrict__ bcur, const int* __restrict__ bbase,
    const uint32* __restrict__ ebuf, int* __restrict__ row_start,
    int* __restrict__ sorted_src) {
  __shared__ uint32 sl[BCAP];
  __shared__ int h[256];
  __shared__ int cur[256];
  __shared__ int wsh[4];
  const int b = blockIdx.x;
  const int t = threadIdx.x, lane = t & 63, wv = t >> 6;
  h[t] = 0;
  __syncthreads();
  const int base = b * BCAP;
  const int len = min(bcur[b] - base, BCAP);
  for (int i = t; i < len; i += 256) {
    uint32 w = ebuf[base + i];
    sl[i] = w;
    atomicAdd(&h[w & 255], 1);
  }
  __syncthreads();
  const int n = b * 256 + t;
  const bool valid = n < N_NODES;
  int v = valid ? h[t] + 1 : 0;       // +1 self loop
  int x = v;
  for (int off = 1; off < 64; off <<= 1) {
    int y = __shfl_up(x, off);
    if (lane >= off) x += y;
  }
  if (lane == 63) wsh[wv] = x;
  __syncthreads();
  int wo = 0;
  for (int w = 0; w < wv; ++w) wo += wsh[w];
  int rs = bbase[b] + wo + x - v;
  if (valid) {
    row_start[n] = rs;
    sorted_src[rs] = n;               // self loop first
    cur[t] = rs + 1;
  }
  __syncthreads();
  for (int i = t; i < len; i += 256) {
    uint32 w = sl[i];
    int pos = atomicAdd(&cur[w & 255], 1);
    sorted_src[pos] = (int)((w >> 8) & 0xffffu);
  }
}

// ---------------- segment softmax + aggregate, one wave per dst node ----------------
// fp16 features; packed-half2 weights; v_pk_fma_f16 inner loop.
template<int HC, bool OUTF16>
__global__ __launch_bounds__(256) void agg_kernel(
    const ushort* __restrict__ xh, const float* __restrict__ al,
    const int* __restrict__ row_start, const int* __restrict__ sorted_src,
    const float* __restrict__ bias, void* __restrict__ outp) {
  __shared__ uint2 pL[4][2][MAXD];
  const int wid = (blockIdx.x * blockDim.x + threadIdx.x) >> 6;
  const int lane = threadIdx.x & 63;
  const int wv = (threadIdx.x >> 6) & 3;
  if (wid >= N_NODES) return;
  const float4* al4 = (const float4*)al;
  const uint32* xb32 = (const uint32*)xh;
  int start = row_start[wid], end = row_start[wid + 1];
  start = clampi(start, 0, EA);
  end   = clampi(end, start, EA);
  const int deg = end - start;
  float4 mya = al4[wid];
  const float ad0 = mya.z, ad1 = mya.w;

  float m0 = -1e30f, m1 = -1e30f, d0 = 0.f, d1 = 0.f;

  if (deg > MAXD) {
    // ---- fallback (cold): recompute per edge, fp32 math, fp16 decode ----
    for (int i = start + lane; i < end; i += 64) {
      int s = clampi(sorted_src[i], 0, N_NODES - 1);
      float4 a = al4[s];
      float l0 = a.x + ad0; l0 = l0 > 0.f ? l0 : 0.2f * l0;
      float l1 = a.y + ad1; l1 = l1 > 0.f ? l1 : 0.2f * l1;
      m0 = fmaxf(m0, l0); m1 = fmaxf(m1, l1);
    }
    for (int off = 32; off >= 1; off >>= 1) {
      m0 = fmaxf(m0, __shfl_xor(m0, off));
      m1 = fmaxf(m1, __shfl_xor(m1, off));
    }
    for (int i = start + lane; i < end; i += 64) {
      int s = clampi(sorted_src[i], 0, N_NODES - 1);
      float4 a = al4[s];
      float l0 = a.x + ad0; l0 = l0 > 0.f ? l0 : 0.2f * l0;
      float l1 = a.y + ad1; l1 = l1 > 0.f ? l1 : 0.2f * l1;
      d0 += __expf(l0 - m0); d1 += __expf(l1 - m1);
    }
    for (int off = 32; off >= 1; off >>= 1) {
      d0 += __shfl_xor(d0, off);
      d1 += __shfl_xor(d1, off);
    }
    const float inv0 = 1.f / d0, inv1 = 1.f / d1;
    constexpr int AL = HC / 2;          // dwords per row
    const int cols0 = lane * 2;
    const int head = cols0 >= HC / 2;
    const float invh = head ? inv1 : inv0;
    const float mh = head ? m1 : m0;
    const float adh = head ? ad1 : ad0;
    float a0 = 0.f, a1 = 0.f;
    if (lane < AL) {
      for (int i = start; i < end; ++i) {
        int s = clampi(sorted_src[i], 0, N_NODES - 1);
        float lv = al[s * 4 + head] + adh;
        lv = lv > 0.f ? lv : 0.2f * lv;
        float wgt = __expf(lv - mh) * invh;
        h16x2 hx = u2h(xb32[(size_t)s * AL + lane]);
        a0 = fmaf(wgt, (float)hx[0], a0);
        a1 = fmaf(wgt, (float)hx[1], a1);
      }
      float o0 = a0 + bias[cols0];
      float o1 = a1 + bias[cols0 + 1];
      o0 = o0 > 0.f ? o0 : __expf(o0) - 1.f;
      o1 = o1 > 0.f ? o1 : __expf(o1) - 1.f;
      if (OUTF16) ((uint32*)outp)[(size_t)wid * AL + lane] = pkh(o0, o1);
      else *reinterpret_cast<float2*>((float*)outp + (size_t)wid * HC + cols0) = make_float2(o0, o1);
    }
    return;
  }

  // ---- pass 1: leaky logits -> LDS pairs (s, logit), head-duplicated; segment max ----
  for (int i = start + lane; i < end; i += 64) {
    int s = clampi(sorted_src[i], 0, N_NODES - 1);
    float4 a = al4[s];
    float l0 = a.x + ad0; l0 = l0 > 0.f ? l0 : 0.2f * l0;
    float l1 = a.y + ad1; l1 = l1 > 0.f ? l1 : 0.2f * l1;
    int j = i - start;
    pL[wv][0][j] = make_uint2((uint32)s, __float_as_uint(l0));
    pL[wv][1][j] = make_uint2((uint32)s, __float_as_uint(l1));
    m0 = fmaxf(m0, l0); m1 = fmaxf(m1, l1);
  }
  for (int off = 32; off >= 1; off >>= 1) {
    m0 = fmaxf(m0, __shfl_xor(m0, off));
    m1 = fmaxf(m1, __shfl_xor(m1, off));
  }
  // ---- pass 2: exp + denom ----
  for (int j = lane; j < deg; j += 64) {
    float e0 = __expf(__uint_as_float(pL[wv][0][j].y) - m0);
    float e1 = __expf(__uint_as_float(pL[wv][1][j].y) - m1);
    pL[wv][0][j].y = __float_as_uint(e0);
    pL[wv][1][j].y = __float_as_uint(e1);
    d0 += e0; d1 += e1;
  }
  for (int off = 32; off >= 1; off >>= 1) {
    d0 += __shfl_xor(d0, off);
    d1 += __shfl_xor(d1, off);
  }
  const float inv0 = 1.f / d0, inv1 = 1.f / d1;
  // ---- pass 2.5: normalize and pack weight as half2(w,w) ----
  for (int j = lane; j < deg; j += 64) {
    float w0 = __uint_as_float(pL[wv][0][j].y) * inv0;
    float w1 = __uint_as_float(pL[wv][1][j].y) * inv1;
    pL[wv][0][j].y = pkh(w0, w0);
    pL[wv][1][j].y = pkh(w1, w1);
  }

  // ---- pass 3: dwordx4 gather + packed fp16 FMA, 64/LPR edges per iteration ----
  constexpr int LPR = HC / 8;          // lanes per row: 16 (HC=128) / 8 (HC=64)
  constexpr int EPI = 64 / LPR;
  constexpr int RS  = HC / 2;          // row stride in dwords
  const int q  = lane / LPR;
  const int cc = lane % LPR;
  const int hd = cc / (LPR / 2);
  const uint2* myP = &pL[wv][hd][0];
  const uint32* myx = xb32 + cc * 4;

  h16x2 acc2[4];
#pragma unroll
  for (int k = 0; k < 4; ++k) acc2[k] = u2h(0u);

  int j = 0;
  for (; j + 2 * EPI <= deg; j += 2 * EPI) {
    uint2 pa = myP[j + q];
    uint2 pb = myP[j + EPI + q];
    const uint4 va = *reinterpret_cast<const uint4*>(myx + (size_t)pa.x * RS);
    const uint4 vb = *reinterpret_cast<const uint4*>(myx + (size_t)pb.x * RS);
    h16x2 wa = u2h(pa.y), wb = u2h(pb.y);
    acc2[0] += wa * u2h(va.x); acc2[1] += wa * u2h(va.y);
    acc2[2] += wa * u2h(va.z); acc2[3] += wa * u2h(va.w);
    acc2[0] += wb * u2h(vb.x); acc2[1] += wb * u2h(vb.y);
    acc2[2] += wb * u2h(vb.z); acc2[3] += wb * u2h(vb.w);
  }
  for (; j < deg; j += EPI) {
    int jj = j + q;
    int jc = jj < deg ? jj : 0;
    uint2 p = myP[jc];
    h16x2 w2 = u2h(jj < deg ? p.y : 0u);
    const uint4 v = *reinterpret_cast<const uint4*>(myx + (size_t)p.x * RS);
    acc2[0] += w2 * u2h(v.x); acc2[1] += w2 * u2h(v.y);
    acc2[2] += w2 * u2h(v.z); acc2[3] += w2 * u2h(v.w);
  }

  // ---- reduce across edge slots (packed) ----
#pragma unroll
  for (int k = 0; k < 4; ++k) {
    if (LPR == 8) acc2[k] = u2h((uint32)__shfl_xor((int)h2u(acc2[k]), 8)) + acc2[k];
    acc2[k] = u2h((uint32)__shfl_xor((int)h2u(acc2[k]), 16)) + acc2[k];
    acc2[k] = u2h((uint32)__shfl_xor((int)h2u(acc2[k]), 32)) + acc2[k];
  }

  // ---- epilogue: bias + ELU + store (first lane group) ----
  if (q == 0) {
    float o[8];
#pragma unroll
    for (int k = 0; k < 4; ++k) {
      o[2 * k]     = (float)acc2[k][0] + bias[cc * 8 + 2 * k];
      o[2 * k + 1] = (float)acc2[k][1] + bias[cc * 8 + 2 * k + 1];
    }
#pragma unroll
    for (int k = 0; k < 8; ++k) o[k] = o[k] > 0.f ? o[k] : __expf(o[k]) - 1.f;
    if (OUTF16) {
      uint4 u;
      u.x = pkh(o[0], o[1]); u.y = pkh(o[2], o[3]);
      u.z = pkh(o[4], o[5]); u.w = pkh(o[6], o[7]);
      *reinterpret_cast<uint4*>((uint32*)outp + (size_t)wid * RS + cc * 4) = u;
    } else {
      float* op = (float*)outp + (size_t)wid * HC + cc * 8;
      *reinterpret_cast<float4*>(op)     = make_float4(o[0], o[1], o[2], o[3]);
      *reinterpret_cast<float4*>(op + 4) = make_float4(o[4], o[5], o[6], o[7]);
    }
  }
}

__global__ void copy4_kernel(const float4* __restrict__ in, float4* __restrict__ out, int n4) {
  int i = blockIdx.x * blockDim.x + threadIdx.x;
  if (i < n4) out[i] = in[i];
}

extern "C" void kernel_launch(void* const* d_in, const int* in_sizes, int n_in,
                              void* d_out, int out_size, void* d_ws, size_t ws_size,
                              hipStream_t stream) {
  const float* x      = (const float*)d_in[0];
  const int*   ei     = (const int*)d_in[1];
  const float* W1     = (const float*)d_in[2];
  const float* a_src1 = (const float*)d_in[3];
  const float* a_dst1 = (const float*)d_in[4];
  const float* b1     = (const float*)d_in[5];
  const float* W2     = (const float*)d_in[6];
  const float* a_src2 = (const float*)d_in[7];
  const float* a_dst2 = (const float*)d_in[8];
  const float* b2     = (const float*)d_in[9];
  float* out = (float*)d_out;

  char* ws = (char*)d_ws;
  size_t off = 0;
  auto alloc = [&](size_t bytes) {
    void* p = ws + off;
    off = (off + bytes + 255) & ~(size_t)255;
    return p;
  };
  ushort* xh1       = (ushort*)alloc((size_t)N_NODES * 128 * 2);  // fp16 xp1
  ushort* h1h       = (ushort*)alloc((size_t)N_NODES * 128 * 2);  // fp16 layer-1 output
  ushort* xh2       = (ushort*)alloc((size_t)N_NODES * 64 * 2);   // fp16 xp2
  float*  al1       = (float*)alloc((size_t)N_NODES * 4 * 4);
  float*  al2       = (float*)alloc((size_t)N_NODES * 4 * 4);
  int*    row_start = (int*)alloc((size_t)(N_NODES + 1) * 4);
  int*    bbase     = (int*)alloc(256 * 4);
  int*    bcur      = (int*)alloc(NBUCK * 4);
  int*    sorted_src= (int*)alloc((size_t)EA * 4);
  uint32* ebuf      = (uint32*)h1h;   // alias: h1h not live until agg1; 196*BCAP*4 <= 12.8MB

  const int* src = ei;
  const int* dst = ei + N_EDGES;

  const int waveBlocks = (N_NODES * 64) / 256;
  const int partBlocks = (N_EDGES + EPB - 1) / EPB;
  const int gemmBlocks = (N_NODES + 63) / 64;

  // ---- CSR by destination (two-level scatter, single-read partB) ----
  init_bcur_kernel<<<1, 256, 0, stream>>>(bcur);
  partA_kernel<<<partBlocks, 256, 0, stream>>>(src, dst, bcur, ebuf);
  scan196_kernel<<<1, 256, 0, stream>>>(bcur, bbase, row_start);
  partB2_kernel<<<NBUCK, 256, 0, stream>>>(bcur, bbase, ebuf, row_start, sorted_src);

  // ---- layer 1 ----
  gemm_mfma_kernel<128, false><<<gemmBlocks, 256, 0, stream>>>(x, W1, a_src1, a_dst1, xh1, al1, N_NODES);
  agg_kernel<128, true><<<waveBlocks, 256, 0, stream>>>(xh1, al1, row_start, sorted_src, b1, h1h);

  // ---- layer 2 ----
  gemm_mfma_kernel<64, true><<<gemmBlocks, 256, 0, stream>>>(h1h, W2, a_src2, a_dst2, xh2, al2, N_NODES);
  agg_kernel<64, false><<<waveBlocks, 256, 0, stream>>>(xh2, al2, row_start, sorted_src, b2, out);

  // ---- encoded passthrough ----
  copy4_kernel<<<((N_NODES * 128 / 4) + 255) / 256, 256, 0, stream>>>(
      (const float4*)x, (float4*)(out + (size_t)N_NODES * 64), N_NODES * 128 / 4);
}

// Round 12
// 167.601 us; speedup vs baseline: 4.1646x; 1.0363x over previous
//
#include <hip/hip_runtime.h>
#include <math.h>

#define N_NODES 50000
#define N_EDGES 1600000
#define EA (N_EDGES + N_NODES)
#define MAXD 128
#define NBUCK 196         // ceil(N_NODES / 256)
#define EPB 4096          // edges per workgroup in partition pass
#define BCAP 16000        // ebuf words per bucket (mean fill ~8163)

typedef unsigned int uint32;
typedef float f32x4 __attribute__((ext_vector_type(4)));
typedef _Float16 h16x2 __attribute__((ext_vector_type(2)));
typedef _Float16 f16x8 __attribute__((ext_vector_type(8)));

__device__ inline h16x2 u2h(uint32 u) { return __builtin_bit_cast(h16x2, u); }
__device__ inline uint32 h2u(h16x2 h) { return __builtin_bit_cast(uint32, h); }
__device__ inline uint32 pkh(float a, float b) {      // pack 2 floats -> half2 (RTZ, 1 instr)
  return __builtin_bit_cast(uint32, __builtin_amdgcn_cvt_pkrtz(a, b));
}
__device__ inline ushort f2h(float f) {                // single f32 -> fp16 bits (RTE)
  _Float16 h = (_Float16)f;
  return __builtin_bit_cast(ushort, h);
}
__device__ inline int clampi(int v, int lo, int hi) {
  return v < lo ? lo : (v > hi ? hi : v);
}

// ---------------- MFMA(f16) GEMM + fused attention-logit epilogue ----------------
// C(fp16)[M][N] = A[M][128] * B[128][N];  al[n] = {src_h0,src_h1,dst_h0,dst_h1} (fp32)
// COPYX: also stream the f32 A rows to encout (fuses the encoded passthrough).
template<int N, bool AF16, bool COPYX>
__global__ __launch_bounds__(256) void gemm_mfma_kernel(
    const void* __restrict__ Ap, const float* __restrict__ B,
    const float* __restrict__ asrc, const float* __restrict__ adst,
    ushort* __restrict__ Cb, float* __restrict__ al, float* __restrict__ encout, int M) {
  constexpr int KK = 4;
  constexpr int NC = N / 16;
  __shared__ uint32 Bl[KK * NC * 64 * 4];
  const int t = threadIdx.x;

  for (int id = t; id < KK * NC * 64; id += 256) {
    int lane = id & 63;
    int cf = (id >> 6) % NC;
    int kk = (id >> 6) / NC;
    int col = cf * 16 + (lane & 15);
    int k0 = kk * 32 + (lane >> 4) * 8;
    uint32 w0 = pkh(B[(k0 + 0) * N + col], B[(k0 + 1) * N + col]);
    uint32 w1 = pkh(B[(k0 + 2) * N + col], B[(k0 + 3) * N + col]);
    uint32 w2 = pkh(B[(k0 + 4) * N + col], B[(k0 + 5) * N + col]);
    uint32 w3 = pkh(B[(k0 + 6) * N + col], B[(k0 + 7) * N + col]);
    *reinterpret_cast<uint4*>(&Bl[id * 4]) = make_uint4(w0, w1, w2, w3);
  }
  __syncthreads();

  const int w = t >> 6, lane = t & 63;
  const int l15 = lane & 15, g4 = lane >> 4;
  const int row0 = blockIdx.x * 64 + w * 16;
  int arow = row0 + l15; if (arow > M - 1) arow = M - 1;
  const int k0 = g4 * 8;

  f32x4 acc[NC];
#pragma unroll
  for (int c = 0; c < NC; ++c) acc[c] = f32x4{0.f, 0.f, 0.f, 0.f};

#pragma unroll
  for (int kk = 0; kk < KK; ++kk) {
    f16x8 af;
    if (AF16) {
      af = *reinterpret_cast<const f16x8*>((const ushort*)Ap + (size_t)arow * 128 + kk * 32 + k0);
    } else {
      const float* A = (const float*)Ap;
      float4 a0 = *reinterpret_cast<const float4*>(A + (size_t)arow * 128 + kk * 32 + k0);
      float4 a1 = *reinterpret_cast<const float4*>(A + (size_t)arow * 128 + kk * 32 + k0 + 4);
      if (COPYX) {   // fused encoded passthrough (clamped rows duplicate-store same data)
        *reinterpret_cast<float4*>(encout + (size_t)arow * 128 + kk * 32 + k0)     = a0;
        *reinterpret_cast<float4*>(encout + (size_t)arow * 128 + kk * 32 + k0 + 4) = a1;
      }
      union { uint32 u[4]; f16x8 v; } p;
      p.u[0] = pkh(a0.x, a0.y);
      p.u[1] = pkh(a0.z, a0.w);
      p.u[2] = pkh(a1.x, a1.y);
      p.u[3] = pkh(a1.z, a1.w);
      af = p.v;
    }
#pragma unroll
    for (int c = 0; c < NC; ++c) {
      f16x8 bf = *reinterpret_cast<const f16x8*>(&Bl[((kk * NC + c) * 64 + lane) * 4]);
      acc[c] = __builtin_amdgcn_mfma_f32_16x16x32_f16(af, bf, acc[c], 0, 0, 0);
    }
  }

  float as_c[NC], ad_c[NC];
#pragma unroll
  for (int c = 0; c < NC; ++c) { as_c[c] = asrc[c * 16 + l15]; ad_c[c] = adst[c * 16 + l15]; }
#pragma unroll
  for (int reg = 0; reg < 4; ++reg) {
    int row = row0 + g4 * 4 + reg;
    bool ok = row < M;
    float ps0 = 0.f, ps1 = 0.f, pd0 = 0.f, pd1 = 0.f;
#pragma unroll
    for (int c = 0; c < NC; ++c) {
      float v = acc[c][reg];
      if (ok) Cb[(size_t)row * N + c * 16 + l15] = f2h(v);
      if (c < NC / 2) { ps0 += v * as_c[c]; pd0 += v * ad_c[c]; }
      else            { ps1 += v * as_c[c]; pd1 += v * ad_c[c]; }
    }
#pragma unroll
    for (int off = 8; off >= 1; off >>= 1) {
      ps0 += __shfl_xor(ps0, off); ps1 += __shfl_xor(ps1, off);
      pd0 += __shfl_xor(pd0, off); pd1 += __shfl_xor(pd1, off);
    }
    if (ok && l15 == 0)
      *reinterpret_cast<float4*>(&al[row * 4]) = make_float4(ps0, ps1, pd0, pd1);
  }
}

// ---------------- CSR build ----------------
__global__ void init_bcur_kernel(int* __restrict__ bcur) {
  int b = blockIdx.x * blockDim.x + threadIdx.x;
  if (b < NBUCK) bcur[b] = b * BCAP;
}

// ---- Pass A: partition edges into 196 coarse buckets (fixed-capacity slices) ----
// staged word layout: [31:24]=bucket, [23:8]=src (<65536), [7:0]=dst&255
__global__ void partA_kernel(const int* __restrict__ src, const int* __restrict__ dst,
                             int* __restrict__ bcur, uint32* __restrict__ ebuf) {
  __shared__ int h[NBUCK];
  __shared__ int lo[NBUCK];
  __shared__ int rank_[NBUCK];     // reused as gb2 after reservation
  __shared__ int gbase[NBUCK];
  __shared__ uint32 staged[EPB];
  const int t = threadIdx.x;
  const int e0 = blockIdx.x * EPB;
  const int ne = min(EPB, N_EDGES - e0);

  for (int i = t; i < NBUCK; i += 256) h[i] = 0;
  __syncthreads();
  for (int i = t; i < ne; i += 256) {
    int d = dst[e0 + i];
    atomicAdd(&h[d >> 8], 1);
  }
  __syncthreads();
  if (t == 0) {
    int a = 0;
    for (int b = 0; b < NBUCK; ++b) { lo[b] = a; a += h[b]; }
  }
  __syncthreads();
  for (int i = t; i < NBUCK; i += 256) rank_[i] = lo[i];
  __syncthreads();
  for (int i = t; i < ne; i += 256) {
    int d = dst[e0 + i];
    int s = src[e0 + i];
    int b = d >> 8;
    int r = atomicAdd(&rank_[b], 1);
    staged[r] = ((uint32)b << 24) | ((uint32)s << 8) | (uint32)(d & 255);
  }
  __syncthreads();
  if (t < NBUCK) gbase[t] = atomicAdd(&bcur[t], h[t]);
  __syncthreads();
  if (t < NBUCK) rank_[t] = gbase[t] - lo[t];   // gb2[b]
  __syncthreads();
  // coalesced copy-out; position = gb2[bucket] + i  (staged sorted by bucket)
  for (int i = t; i < ne; i += 256) {
    uint32 wd = staged[i];
    ebuf[rank_[wd >> 24] + i] = wd;
  }
}

// ---- scan over 196 bucket totals (edges + resident self-loops) ----
__global__ void scan196_kernel(const int* __restrict__ bcur, int* __restrict__ bbase,
                               int* __restrict__ row_start) {
  __shared__ int wsh[4];
  const int t = threadIdx.x, lane = t & 63, wv = t >> 6;
  int v = 0;
  if (t < NBUCK) {
    int nn = min(256, N_NODES - t * 256);
    v = (bcur[t] - t * BCAP) + nn;
  }
  int x = v;
  for (int off = 1; off < 64; off <<= 1) {
    int y = __shfl_up(x, off);
    if (lane >= off) x += y;
  }
  if (lane == 63) wsh[wv] = x;
  __syncthreads();
  int wo = 0;
  for (int w = 0; w < wv; ++w) wo += wsh[w];
  if (t < NBUCK) bbase[t] = wo + x - v;
  if (t == 0) row_start[N_NODES] = EA;
}

// ---- Pass B2: per-bucket LDS hist + scan + row_start + scatter (ebuf read once) ----
__global__ __launch_bounds__(256) void partB2_kernel(
    const int* __restrict__ bcur, const int* __restrict__ bbase,
    const uint32* __restrict__ ebuf, int* __restrict__ row_start,
    int* __restrict__ sorted_src) {
  __shared__ uint32 sl[BCAP];
  __shared__ int h[256];
  __shared__ int cur[256];
  __shared__ int wsh[4];
  const int b = blockIdx.x;
  const int t = threadIdx.x, lane = t & 63, wv = t >> 6;
  h[t] = 0;
  __syncthreads();
  const int base = b * BCAP;
  const int len = min(bcur[b] - base, BCAP);
  for (int i = t; i < len; i += 256) {
    uint32 w = ebuf[base + i];
    sl[i] = w;
    atomicAdd(&h[w & 255], 1);
  }
  __syncthreads();
  const int n = b * 256 + t;
  const bool valid = n < N_NODES;
  int v = valid ? h[t] + 1 : 0;       // +1 self loop
  int x = v;
  for (int off = 1; off < 64; off <<= 1) {
    int y = __shfl_up(x, off);
    if (lane >= off) x += y;
  }
  if (lane == 63) wsh[wv] = x;
  __syncthreads();
  int wo = 0;
  for (int w = 0; w < wv; ++w) wo += wsh[w];
  int rs = bbase[b] + wo + x - v;
  if (valid) {
    row_start[n] = rs;
    sorted_src[rs] = n;               // self loop first
    cur[t] = rs + 1;
  }
  __syncthreads();
  for (int i = t; i < len; i += 256) {
    uint32 w = sl[i];
    int pos = atomicAdd(&cur[w & 255], 1);
    sorted_src[pos] = (int)((w >> 8) & 0xffffu);
  }
}

// ---------------- segment softmax + aggregate, one wave per dst node ----------------
// fp16 features; packed-half2 weights; v_pk_fma_f16 inner loop; 4-deep gather pipeline.
template<int HC, bool OUTF16>
__global__ __launch_bounds__(256) void agg_kernel(
    const ushort* __restrict__ xh, const float* __restrict__ al,
    const int* __restrict__ row_start, const int* __restrict__ sorted_src,
    const float* __restrict__ bias, void* __restrict__ outp) {
  __shared__ uint2 pL[4][2][MAXD];
  const int wid = (blockIdx.x * blockDim.x + threadIdx.x) >> 6;
  const int lane = threadIdx.x & 63;
  const int wv = (threadIdx.x >> 6) & 3;
  if (wid >= N_NODES) return;
  const float4* al4 = (const float4*)al;
  const uint32* xb32 = (const uint32*)xh;
  int start = row_start[wid], end = row_start[wid + 1];
  start = clampi(start, 0, EA);
  end   = clampi(end, start, EA);
  const int deg = end - start;
  float4 mya = al4[wid];
  const float ad0 = mya.z, ad1 = mya.w;

  float m0 = -1e30f, m1 = -1e30f, d0 = 0.f, d1 = 0.f;

  if (deg > MAXD) {
    // ---- fallback (cold): recompute per edge, fp32 math, fp16 decode ----
    for (int i = start + lane; i < end; i += 64) {
      int s = clampi(sorted_src[i], 0, N_NODES - 1);
      float4 a = al4[s];
      float l0 = a.x + ad0; l0 = l0 > 0.f ? l0 : 0.2f * l0;
      float l1 = a.y + ad1; l1 = l1 > 0.f ? l1 : 0.2f * l1;
      m0 = fmaxf(m0, l0); m1 = fmaxf(m1, l1);
    }
    for (int off = 32; off >= 1; off >>= 1) {
      m0 = fmaxf(m0, __shfl_xor(m0, off));
      m1 = fmaxf(m1, __shfl_xor(m1, off));
    }
    for (int i = start + lane; i < end; i += 64) {
      int s = clampi(sorted_src[i], 0, N_NODES - 1);
      float4 a = al4[s];
      float l0 = a.x + ad0; l0 = l0 > 0.f ? l0 : 0.2f * l0;
      float l1 = a.y + ad1; l1 = l1 > 0.f ? l1 : 0.2f * l1;
      d0 += __expf(l0 - m0); d1 += __expf(l1 - m1);
    }
    for (int off = 32; off >= 1; off >>= 1) {
      d0 += __shfl_xor(d0, off);
      d1 += __shfl_xor(d1, off);
    }
    const float inv0 = 1.f / d0, inv1 = 1.f / d1;
    constexpr int AL = HC / 2;          // dwords per row
    const int cols0 = lane * 2;
    const int head = cols0 >= HC / 2;
    const float invh = head ? inv1 : inv0;
    const float mh = head ? m1 : m0;
    const float adh = head ? ad1 : ad0;
    float a0 = 0.f, a1 = 0.f;
    if (lane < AL) {
      for (int i = start; i < end; ++i) {
        int s = clampi(sorted_src[i], 0, N_NODES - 1);
        float lv = al[s * 4 + head] + adh;
        lv = lv > 0.f ? lv : 0.2f * lv;
        float wgt = __expf(lv - mh) * invh;
        h16x2 hx = u2h(xb32[(size_t)s * AL + lane]);
        a0 = fmaf(wgt, (float)hx[0], a0);
        a1 = fmaf(wgt, (float)hx[1], a1);
      }
      float o0 = a0 + bias[cols0];
      float o1 = a1 + bias[cols0 + 1];
      o0 = o0 > 0.f ? o0 : __expf(o0) - 1.f;
      o1 = o1 > 0.f ? o1 : __expf(o1) - 1.f;
      if (OUTF16) ((uint32*)outp)[(size_t)wid * AL + lane] = pkh(o0, o1);
      else *reinterpret_cast<float2*>((float*)outp + (size_t)wid * HC + cols0) = make_float2(o0, o1);
    }
    return;
  }

  // ---- pass 1: leaky logits -> LDS pairs (s, logit), head-duplicated; segment max ----
  for (int i = start + lane; i < end; i += 64) {
    int s = clampi(sorted_src[i], 0, N_NODES - 1);
    float4 a = al4[s];
    float l0 = a.x + ad0; l0 = l0 > 0.f ? l0 : 0.2f * l0;
    float l1 = a.y + ad1; l1 = l1 > 0.f ? l1 : 0.2f * l1;
    int j = i - start;
    pL[wv][0][j] = make_uint2((uint32)s, __float_as_uint(l0));
    pL[wv][1][j] = make_uint2((uint32)s, __float_as_uint(l1));
    m0 = fmaxf(m0, l0); m1 = fmaxf(m1, l1);
  }
  for (int off = 32; off >= 1; off >>= 1) {
    m0 = fmaxf(m0, __shfl_xor(m0, off));
    m1 = fmaxf(m1, __shfl_xor(m1, off));
  }
  // ---- pass 2: exp + denom ----
  for (int j = lane; j < deg; j += 64) {
    float e0 = __expf(__uint_as_float(pL[wv][0][j].y) - m0);
    float e1 = __expf(__uint_as_float(pL[wv][1][j].y) - m1);
    pL[wv][0][j].y = __float_as_uint(e0);
    pL[wv][1][j].y = __float_as_uint(e1);
    d0 += e0; d1 += e1;
  }
  for (int off = 32; off >= 1; off >>= 1) {
    d0 += __shfl_xor(d0, off);
    d1 += __shfl_xor(d1, off);
  }
  const float inv0 = 1.f / d0, inv1 = 1.f / d1;
  // ---- pass 2.5: normalize and pack weight as half2(w,w) ----
  for (int j = lane; j < deg; j += 64) {
    float w0 = __uint_as_float(pL[wv][0][j].y) * inv0;
    float w1 = __uint_as_float(pL[wv][1][j].y) * inv1;
    pL[wv][0][j].y = pkh(w0, w0);
    pL[wv][1][j].y = pkh(w1, w1);
  }

  // ---- pass 3: 4-deep dwordx4 gather pipeline + packed fp16 FMA ----
  constexpr int LPR = HC / 8;          // lanes per row: 16 (HC=128) / 8 (HC=64)
  constexpr int EPI = 64 / LPR;        // edges per step: 4 / 8
  constexpr int RS  = HC / 2;          // row stride in dwords
  const int q  = lane / LPR;
  const int cc = lane % LPR;
  const int hd = cc / (LPR / 2);
  const uint2* myP = &pL[wv][hd][0];
  const uint32* myx = xb32 + cc * 4;

  h16x2 acc2[4];
#pragma unroll
  for (int k = 0; k < 4; ++k) acc2[k] = u2h(0u);

  int j = 0;
  // main: 4 loads in flight (4*EPI edges)
  for (; j + 4 * EPI <= deg; j += 4 * EPI) {
    uint2 p0 = myP[j + q];
    uint2 p1 = myP[j + EPI + q];
    uint2 p2 = myP[j + 2 * EPI + q];
    uint2 p3 = myP[j + 3 * EPI + q];
    const uint4 v0 = *reinterpret_cast<const uint4*>(myx + (size_t)p0.x * RS);
    const uint4 v1 = *reinterpret_cast<const uint4*>(myx + (size_t)p1.x * RS);
    const uint4 v2 = *reinterpret_cast<const uint4*>(myx + (size_t)p2.x * RS);
    const uint4 v3 = *reinterpret_cast<const uint4*>(myx + (size_t)p3.x * RS);
    h16x2 w0 = u2h(p0.y), w1 = u2h(p1.y), w2 = u2h(p2.y), w3 = u2h(p3.y);
    acc2[0] += w0 * u2h(v0.x); acc2[1] += w0 * u2h(v0.y);
    acc2[2] += w0 * u2h(v0.z); acc2[3] += w0 * u2h(v0.w);
    acc2[0] += w1 * u2h(v1.x); acc2[1] += w1 * u2h(v1.y);
    acc2[2] += w1 * u2h(v1.z); acc2[3] += w1 * u2h(v1.w);
    acc2[0] += w2 * u2h(v2.x); acc2[1] += w2 * u2h(v2.y);
    acc2[2] += w2 * u2h(v2.z); acc2[3] += w2 * u2h(v2.w);
    acc2[0] += w3 * u2h(v3.x); acc2[1] += w3 * u2h(v3.y);
    acc2[2] += w3 * u2h(v3.z); acc2[3] += w3 * u2h(v3.w);
  }
  // full-EPI steps
  for (; j + EPI <= deg; j += EPI) {
    uint2 p = myP[j + q];
    h16x2 w2 = u2h(p.y);
    const uint4 v = *reinterpret_cast<const uint4*>(myx + (size_t)p.x * RS);
    acc2[0] += w2 * u2h(v.x); acc2[1] += w2 * u2h(v.y);
    acc2[2] += w2 * u2h(v.z); acc2[3] += w2 * u2h(v.w);
  }
  // predicated tail
  if (j < deg) {
    int jj = j + q;
    int jc = jj < deg ? jj : 0;
    uint2 p = myP[jc];
    h16x2 w2 = u2h(jj < deg ? p.y : 0u);
    const uint4 v = *reinterpret_cast<const uint4*>(myx + (size_t)p.x * RS);
    acc2[0] += w2 * u2h(v.x); acc2[1] += w2 * u2h(v.y);
    acc2[2] += w2 * u2h(v.z); acc2[3] += w2 * u2h(v.w);
  }

  // ---- reduce across edge slots (packed) ----
#pragma unroll
  for (int k = 0; k < 4; ++k) {
    if (LPR == 8) acc2[k] = u2h((uint32)__shfl_xor((int)h2u(acc2[k]), 8)) + acc2[k];
    acc2[k] = u2h((uint32)__shfl_xor((int)h2u(acc2[k]), 16)) + acc2[k];
    acc2[k] = u2h((uint32)__shfl_xor((int)h2u(acc2[k]), 32)) + acc2[k];
  }

  // ---- epilogue: bias + ELU + store (first lane group) ----
  if (q == 0) {
    float o[8];
#pragma unroll
    for (int k = 0; k < 4; ++k) {
      o[2 * k]     = (float)acc2[k][0] + bias[cc * 8 + 2 * k];
      o[2 * k + 1] = (float)acc2[k][1] + bias[cc * 8 + 2 * k + 1];
    }
#pragma unroll
    for (int k = 0; k < 8; ++k) o[k] = o[k] > 0.f ? o[k] : __expf(o[k]) - 1.f;
    if (OUTF16) {
      uint4 u;
      u.x = pkh(o[0], o[1]); u.y = pkh(o[2], o[3]);
      u.z = pkh(o[4], o[5]); u.w = pkh(o[6], o[7]);
      *reinterpret_cast<uint4*>((uint32*)outp + (size_t)wid * RS + cc * 4) = u;
    } else {
      float* op = (float*)outp + (size_t)wid * HC + cc * 8;
      *reinterpret_cast<float4*>(op)     = make_float4(o[0], o[1], o[2], o[3]);
      *reinterpret_cast<float4*>(op + 4) = make_float4(o[4], o[5], o[6], o[7]);
    }
  }
}

extern "C" void kernel_launch(void* const* d_in, const int* in_sizes, int n_in,
                              void* d_out, int out_size, void* d_ws, size_t ws_size,
                              hipStream_t stream) {
  const float* x      = (const float*)d_in[0];
  const int*   ei     = (const int*)d_in[1];
  const float* W1     = (const float*)d_in[2];
  const float* a_src1 = (const float*)d_in[3];
  const float* a_dst1 = (const float*)d_in[4];
  const float* b1     = (const float*)d_in[5];
  const float* W2     = (const float*)d_in[6];
  const float* a_src2 = (const float*)d_in[7];
  const float* a_dst2 = (const float*)d_in[8];
  const float* b2     = (const float*)d_in[9];
  float* out = (float*)d_out;

  char* ws = (char*)d_ws;
  size_t off = 0;
  auto alloc = [&](size_t bytes) {
    void* p = ws + off;
    off = (off + bytes + 255) & ~(size_t)255;
    return p;
  };
  ushort* xh1       = (ushort*)alloc((size_t)N_NODES * 128 * 2);  // fp16 xp1
  ushort* h1h       = (ushort*)alloc((size_t)N_NODES * 128 * 2);  // fp16 layer-1 output
  ushort* xh2       = (ushort*)alloc((size_t)N_NODES * 64 * 2);   // fp16 xp2
  float*  al1       = (float*)alloc((size_t)N_NODES * 4 * 4);
  float*  al2       = (float*)alloc((size_t)N_NODES * 4 * 4);
  int*    row_start = (int*)alloc((size_t)(N_NODES + 1) * 4);
  int*    bbase     = (int*)alloc(256 * 4);
  int*    bcur      = (int*)alloc(NBUCK * 4);
  int*    sorted_src= (int*)alloc((size_t)EA * 4);
  uint32* ebuf      = (uint32*)h1h;   // alias: h1h not live until agg1; 196*BCAP*4 <= 12.8MB

  const int* src = ei;
  const int* dst = ei + N_EDGES;

  const int waveBlocks = (N_NODES * 64) / 256;
  const int partBlocks = (N_EDGES + EPB - 1) / EPB;
  const int gemmBlocks = (N_NODES + 63) / 64;

  // ---- CSR by destination (two-level scatter, single-read partB) ----
  init_bcur_kernel<<<1, 256, 0, stream>>>(bcur);
  partA_kernel<<<partBlocks, 256, 0, stream>>>(src, dst, bcur, ebuf);
  scan196_kernel<<<1, 256, 0, stream>>>(bcur, bbase, row_start);
  partB2_kernel<<<NBUCK, 256, 0, stream>>>(bcur, bbase, ebuf, row_start, sorted_src);

  // ---- layer 1 (gemm fuses the encoded passthrough copy) ----
  gemm_mfma_kernel<128, false, true><<<gemmBlocks, 256, 0, stream>>>(
      x, W1, a_src1, a_dst1, xh1, al1, out + (size_t)N_NODES * 64, N_NODES);
  agg_kernel<128, true><<<waveBlocks, 256, 0, stream>>>(xh1, al1, row_start, sorted_src, b1, h1h);

  // ---- layer 2 ----
  gemm_mfma_kernel<64, true, false><<<gemmBlocks, 256, 0, stream>>>(
      h1h, W2, a_src2, a_dst2, xh2, al2, nullptr, N_NODES);
  agg_kernel<64, false><<<waveBlocks, 256, 0, stream>>>(xh2, al2, row_start, sorted_src, b2, out);
}

// Round 13
// 160.317 us; speedup vs baseline: 4.3538x; 1.0454x over previous
//
#include <hip/hip_runtime.h>
#include <math.h>

#define N_NODES 50000
#define N_EDGES 1600000
#define EA (N_EDGES + N_NODES)
#define MAXD 128
#define NBUCK 196         // ceil(N_NODES / 256)
#define EPB 4096          // edges per workgroup in partition pass
#define BCAP 16000        // ebuf words per bucket (mean fill ~8163)

typedef unsigned int uint32;
typedef float f32x4 __attribute__((ext_vector_type(4)));
typedef _Float16 h16x2 __attribute__((ext_vector_type(2)));
typedef _Float16 f16x8 __attribute__((ext_vector_type(8)));

__device__ inline h16x2 u2h(uint32 u) { return __builtin_bit_cast(h16x2, u); }
__device__ inline uint32 h2u(h16x2 h) { return __builtin_bit_cast(uint32, h); }
__device__ inline uint32 pkh(float a, float b) {      // pack 2 floats -> half2 (RTZ, 1 instr)
  return __builtin_bit_cast(uint32, __builtin_amdgcn_cvt_pkrtz(a, b));
}
__device__ inline ushort f2h(float f) {                // single f32 -> fp16 bits (RTE)
  _Float16 h = (_Float16)f;
  return __builtin_bit_cast(ushort, h);
}
__device__ inline int clampi(int v, int lo, int hi) {
  return v < lo ? lo : (v > hi ? hi : v);
}

// ---------------- MFMA(f16) GEMM + fused attention-logit epilogue ----------------
// C(fp16)[M][N] = A[M][128] * B[128][N];  al[n] = {src_h0,src_h1,dst_h0,dst_h1} (fp32)
// COPYX: also stream the f32 A rows to encout (fuses the encoded passthrough).
template<int N, bool AF16, bool COPYX>
__global__ __launch_bounds__(256) void gemm_mfma_kernel(
    const void* __restrict__ Ap, const float* __restrict__ B,
    const float* __restrict__ asrc, const float* __restrict__ adst,
    ushort* __restrict__ Cb, float* __restrict__ al, float* __restrict__ encout, int M) {
  constexpr int KK = 4;
  constexpr int NC = N / 16;
  __shared__ uint32 Bl[KK * NC * 64 * 4];
  const int t = threadIdx.x;

  for (int id = t; id < KK * NC * 64; id += 256) {
    int lane = id & 63;
    int cf = (id >> 6) % NC;
    int kk = (id >> 6) / NC;
    int col = cf * 16 + (lane & 15);
    int k0 = kk * 32 + (lane >> 4) * 8;
    uint32 w0 = pkh(B[(k0 + 0) * N + col], B[(k0 + 1) * N + col]);
    uint32 w1 = pkh(B[(k0 + 2) * N + col], B[(k0 + 3) * N + col]);
    uint32 w2 = pkh(B[(k0 + 4) * N + col], B[(k0 + 5) * N + col]);
    uint32 w3 = pkh(B[(k0 + 6) * N + col], B[(k0 + 7) * N + col]);
    *reinterpret_cast<uint4*>(&Bl[id * 4]) = make_uint4(w0, w1, w2, w3);
  }
  __syncthreads();

  const int w = t >> 6, lane = t & 63;
  const int l15 = lane & 15, g4 = lane >> 4;
  const int row0 = blockIdx.x * 64 + w * 16;
  int arow = row0 + l15; if (arow > M - 1) arow = M - 1;
  const int k0 = g4 * 8;

  f32x4 acc[NC];
#pragma unroll
  for (int c = 0; c < NC; ++c) acc[c] = f32x4{0.f, 0.f, 0.f, 0.f};

#pragma unroll
  for (int kk = 0; kk < KK; ++kk) {
    f16x8 af;
    if (AF16) {
      af = *reinterpret_cast<const f16x8*>((const ushort*)Ap + (size_t)arow * 128 + kk * 32 + k0);
    } else {
      const float* A = (const float*)Ap;
      float4 a0 = *reinterpret_cast<const float4*>(A + (size_t)arow * 128 + kk * 32 + k0);
      float4 a1 = *reinterpret_cast<const float4*>(A + (size_t)arow * 128 + kk * 32 + k0 + 4);
      if (COPYX) {   // fused encoded passthrough (clamped rows duplicate-store same data)
        *reinterpret_cast<float4*>(encout + (size_t)arow * 128 + kk * 32 + k0)     = a0;
        *reinterpret_cast<float4*>(encout + (size_t)arow * 128 + kk * 32 + k0 + 4) = a1;
      }
      union { uint32 u[4]; f16x8 v; } p;
      p.u[0] = pkh(a0.x, a0.y);
      p.u[1] = pkh(a0.z, a0.w);
      p.u[2] = pkh(a1.x, a1.y);
      p.u[3] = pkh(a1.z, a1.w);
      af = p.v;
    }
#pragma unroll
    for (int c = 0; c < NC; ++c) {
      f16x8 bf = *reinterpret_cast<const f16x8*>(&Bl[((kk * NC + c) * 64 + lane) * 4]);
      acc[c] = __builtin_amdgcn_mfma_f32_16x16x32_f16(af, bf, acc[c], 0, 0, 0);
    }
  }

  float as_c[NC], ad_c[NC];
#pragma unroll
  for (int c = 0; c < NC; ++c) { as_c[c] = asrc[c * 16 + l15]; ad_c[c] = adst[c * 16 + l15]; }
#pragma unroll
  for (int reg = 0; reg < 4; ++reg) {
    int row = row0 + g4 * 4 + reg;
    bool ok = row < M;
    float ps0 = 0.f, ps1 = 0.f, pd0 = 0.f, pd1 = 0.f;
#pragma unroll
    for (int c = 0; c < NC; ++c) {
      float v = acc[c][reg];
      if (ok) Cb[(size_t)row * N + c * 16 + l15] = f2h(v);
      if (c < NC / 2) { ps0 += v * as_c[c]; pd0 += v * ad_c[c]; }
      else            { ps1 += v * as_c[c]; pd1 += v * ad_c[c]; }
    }
#pragma unroll
    for (int off = 8; off >= 1; off >>= 1) {
      ps0 += __shfl_xor(ps0, off); ps1 += __shfl_xor(ps1, off);
      pd0 += __shfl_xor(pd0, off); pd1 += __shfl_xor(pd1, off);
    }
    if (ok && l15 == 0)
      *reinterpret_cast<float4*>(&al[row * 4]) = make_float4(ps0, ps1, pd0, pd1);
  }
}

// ---------------- CSR build ----------------
__global__ void init_bcur_kernel(int* __restrict__ bcur) {
  int b = blockIdx.x * blockDim.x + threadIdx.x;
  if (b < NBUCK) bcur[b] = b * BCAP;
}

// ---- Pass A: partition edges into 196 coarse buckets (fixed-capacity slices) ----
// staged word layout: [31:24]=bucket, [23:8]=src (<65536), [7:0]=dst&255
__global__ void partA_kernel(const int* __restrict__ src, const int* __restrict__ dst,
                             int* __restrict__ bcur, uint32* __restrict__ ebuf) {
  __shared__ int h[NBUCK];
  __shared__ int lo[NBUCK];
  __shared__ int rank_[NBUCK];     // reused as gb2 after reservation
  __shared__ int gbase[NBUCK];
  __shared__ uint32 staged[EPB];
  const int t = threadIdx.x;
  const int e0 = blockIdx.x * EPB;
  const int ne = min(EPB, N_EDGES - e0);

  for (int i = t; i < NBUCK; i += 256) h[i] = 0;
  __syncthreads();
  for (int i = t; i < ne; i += 256) {
    int d = dst[e0 + i];
    atomicAdd(&h[d >> 8], 1);
  }
  __syncthreads();
  if (t == 0) {
    int a = 0;
    for (int b = 0; b < NBUCK; ++b) { lo[b] = a; a += h[b]; }
  }
  __syncthreads();
  for (int i = t; i < NBUCK; i += 256) rank_[i] = lo[i];
  __syncthreads();
  for (int i = t; i < ne; i += 256) {
    int d = dst[e0 + i];
    int s = src[e0 + i];
    int b = d >> 8;
    int r = atomicAdd(&rank_[b], 1);
    staged[r] = ((uint32)b << 24) | ((uint32)s << 8) | (uint32)(d & 255);
  }
  __syncthreads();
  if (t < NBUCK) gbase[t] = atomicAdd(&bcur[t], h[t]);
  __syncthreads();
  if (t < NBUCK) rank_[t] = gbase[t] - lo[t];   // gb2[b]
  __syncthreads();
  // coalesced copy-out; position = gb2[bucket] + i  (staged sorted by bucket)
  for (int i = t; i < ne; i += 256) {
    uint32 wd = staged[i];
    ebuf[rank_[wd >> 24] + i] = wd;
  }
}

// ---- scan over 196 bucket totals (edges + resident self-loops) ----
__global__ void scan196_kernel(const int* __restrict__ bcur, int* __restrict__ bbase,
                               int* __restrict__ row_start) {
  __shared__ int wsh[4];
  const int t = threadIdx.x, lane = t & 63, wv = t >> 6;
  int v = 0;
  if (t < NBUCK) {
    int nn = min(256, N_NODES - t * 256);
    v = (bcur[t] - t * BCAP) + nn;
  }
  int x = v;
  for (int off = 1; off < 64; off <<= 1) {
    int y = __shfl_up(x, off);
    if (lane >= off) x += y;
  }
  if (lane == 63) wsh[wv] = x;
  __syncthreads();
  int wo = 0;
  for (int w = 0; w < wv; ++w) wo += wsh[w];
  if (t < NBUCK) bbase[t] = wo + x - v;
  if (t == 0) row_start[N_NODES] = EA;
}

// ---- Pass B2: per-bucket LDS hist + scan + row_start + scatter (ebuf read once) ----
__global__ __launch_bounds__(256) void partB2_kernel(
    const int* __restrict__ bcur, const int* __restrict__ bbase,
    const uint32* __restrict__ ebuf, int* __restrict__ row_start,
    int* __restrict__ sorted_src) {
  __shared__ uint32 sl[BCAP];
  __shared__ int h[256];
  __shared__ int cur[256];
  __shared__ int wsh[4];
  const int b = blockIdx.x;
  const int t = threadIdx.x, lane = t & 63, wv = t >> 6;
  h[t] = 0;
  __syncthreads();
  const int base = b * BCAP;
  const int len = min(bcur[b] - base, BCAP);
  for (int i = t; i < len; i += 256) {
    uint32 w = ebuf[base + i];
    sl[i] = w;
    atomicAdd(&h[w & 255], 1);
  }
  __syncthreads();
  const int n = b * 256 + t;
  const bool valid = n < N_NODES;
  int v = valid ? h[t] + 1 : 0;       // +1 self loop
  int x = v;
  for (int off = 1; off < 64; off <<= 1) {
    int y = __shfl_up(x, off);
    if (lane >= off) x += y;
  }
  if (lane == 63) wsh[wv] = x;
  __syncthreads();
  int wo = 0;
  for (int w = 0; w < wv; ++w) wo += wsh[w];
  int rs = bbase[b] + wo + x - v;
  if (valid) {
    row_start[n] = rs;
    sorted_src[rs] = n;               // self loop first
    cur[t] = rs + 1;
  }
  __syncthreads();
  for (int i = t; i < len; i += 256) {
    uint32 w = sl[i];
    int pos = atomicAdd(&cur[w & 255], 1);
    sorted_src[pos] = (int)((w >> 8) & 0xffffu);
  }
}

// ---------------- segment softmax + aggregate, one wave per dst node ----------------
// fp16 features; no-max softmax (exp(l - 4ln2), exact-α); denom folded post-reduce;
// first gather batch prefetched under the denom reduce; 4-deep pipeline after.
template<int HC, bool OUTF16>
__global__ __launch_bounds__(256) void agg_kernel(
    const ushort* __restrict__ xh, const float* __restrict__ al,
    const int* __restrict__ row_start, const int* __restrict__ sorted_src,
    const float* __restrict__ bias, void* __restrict__ outp) {
  __shared__ uint2 pL[4][2][MAXD];
  const int wid = (blockIdx.x * blockDim.x + threadIdx.x) >> 6;
  const int lane = threadIdx.x & 63;
  const int wv = (threadIdx.x >> 6) & 3;
  if (wid >= N_NODES) return;
  const float4* al4 = (const float4*)al;
  const uint32* xb32 = (const uint32*)xh;
  int start = row_start[wid], end = row_start[wid + 1];
  start = clampi(start, 0, EA);
  end   = clampi(end, start, EA);
  const int deg = end - start;
  float4 mya = al4[wid];
  const float ad0 = mya.z, ad1 = mya.w;
  const float ESH = 2.7725887f;   // 4*ln2: exp(l-ESH) = 2^-4 * exp(l); exact-alpha shift

  float m0 = -1e30f, m1 = -1e30f, d0 = 0.f, d1 = 0.f;

  if (deg > MAXD) {
    // ---- fallback (cold): recompute per edge, fp32 math with max ----
    for (int i = start + lane; i < end; i += 64) {
      int s = clampi(sorted_src[i], 0, N_NODES - 1);
      float4 a = al4[s];
      float l0 = a.x + ad0; l0 = l0 > 0.f ? l0 : 0.2f * l0;
      float l1 = a.y + ad1; l1 = l1 > 0.f ? l1 : 0.2f * l1;
      m0 = fmaxf(m0, l0); m1 = fmaxf(m1, l1);
    }
    for (int off = 32; off >= 1; off >>= 1) {
      m0 = fmaxf(m0, __shfl_xor(m0, off));
      m1 = fmaxf(m1, __shfl_xor(m1, off));
    }
    for (int i = start + lane; i < end; i += 64) {
      int s = clampi(sorted_src[i], 0, N_NODES - 1);
      float4 a = al4[s];
      float l0 = a.x + ad0; l0 = l0 > 0.f ? l0 : 0.2f * l0;
      float l1 = a.y + ad1; l1 = l1 > 0.f ? l1 : 0.2f * l1;
      d0 += __expf(l0 - m0); d1 += __expf(l1 - m1);
    }
    for (int off = 32; off >= 1; off >>= 1) {
      d0 += __shfl_xor(d0, off);
      d1 += __shfl_xor(d1, off);
    }
    const float inv0 = 1.f / d0, inv1 = 1.f / d1;
    constexpr int AL = HC / 2;          // dwords per row
    const int cols0 = lane * 2;
    const int head = cols0 >= HC / 2;
    const float invh = head ? inv1 : inv0;
    const float mh = head ? m1 : m0;
    const float adh = head ? ad1 : ad0;
    float a0 = 0.f, a1 = 0.f;
    if (lane < AL) {
      for (int i = start; i < end; ++i) {
        int s = clampi(sorted_src[i], 0, N_NODES - 1);
        float lv = al[s * 4 + head] + adh;
        lv = lv > 0.f ? lv : 0.2f * lv;
        float wgt = __expf(lv - mh) * invh;
        h16x2 hx = u2h(xb32[(size_t)s * AL + lane]);
        a0 = fmaf(wgt, (float)hx[0], a0);
        a1 = fmaf(wgt, (float)hx[1], a1);
      }
      float o0 = a0 + bias[cols0];
      float o1 = a1 + bias[cols0 + 1];
      o0 = o0 > 0.f ? o0 : __expf(o0) - 1.f;
      o1 = o1 > 0.f ? o1 : __expf(o1) - 1.f;
      if (OUTF16) ((uint32*)outp)[(size_t)wid * AL + lane] = pkh(o0, o1);
      else *reinterpret_cast<float2*>((float*)outp + (size_t)wid * HC + cols0) = make_float2(o0, o1);
    }
    return;
  }

  constexpr int LPR = HC / 8;          // lanes per row: 16 (HC=128) / 8 (HC=64)
  constexpr int EPI = 64 / LPR;        // edges per step: 4 / 8
  constexpr int RS  = HC / 2;          // row stride in dwords
  constexpr int PF  = 4;               // prefetched steps
  const int q  = lane / LPR;
  const int cc = lane % LPR;
  const int hd = cc / (LPR / 2);
  const uint2* myP = &pL[wv][hd][0];
  const uint32* myx = xb32 + cc * 4;

  // ---- pass 1 (fused): stage (s, pkh(e,e)) head-duplicated; accumulate denoms ----
  for (int i = start + lane; i < end; i += 64) {
    int s = clampi(sorted_src[i], 0, N_NODES - 1);
    float4 a = al4[s];
    float l0 = a.x + ad0; l0 = l0 > 0.f ? l0 : 0.2f * l0;
    float l1 = a.y + ad1; l1 = l1 > 0.f ? l1 : 0.2f * l1;
    float e0 = __expf(l0 - ESH);
    float e1 = __expf(l1 - ESH);
    int j = i - start;
    pL[wv][0][j] = make_uint2((uint32)s, pkh(e0, e0));
    pL[wv][1][j] = make_uint2((uint32)s, pkh(e1, e1));
    d0 += e0; d1 += e1;
  }

  // ---- prefetch first PF gather steps (loads fly under the denom reduce) ----
  uint4 pv[PF];
  h16x2 pw[PF];
#pragma unroll
  for (int st = 0; st < PF; ++st) {
    int jj = st * EPI + q;
    int jc = jj < deg ? jj : 0;
    uint2 p = myP[jc];
    pw[st] = u2h(jj < deg ? p.y : 0u);
    pv[st] = *reinterpret_cast<const uint4*>(myx + (size_t)p.x * RS);
  }

  // ---- denom reduce ----
  for (int off = 32; off >= 1; off >>= 1) {
    d0 += __shfl_xor(d0, off);
    d1 += __shfl_xor(d1, off);
  }
  const float inv0 = 1.f / d0, inv1 = 1.f / d1;

  // ---- pass 3: consume prefetched, then 4-deep pipeline ----
  h16x2 acc2[4];
#pragma unroll
  for (int k = 0; k < 4; ++k) acc2[k] = u2h(0u);

#pragma unroll
  for (int st = 0; st < PF; ++st) {
    acc2[0] += pw[st] * u2h(pv[st].x); acc2[1] += pw[st] * u2h(pv[st].y);
    acc2[2] += pw[st] * u2h(pv[st].z); acc2[3] += pw[st] * u2h(pv[st].w);
  }

  int j = PF * EPI;
  for (; j + 4 * EPI <= deg; j += 4 * EPI) {
    uint2 p0 = myP[j + q];
    uint2 p1 = myP[j + EPI + q];
    uint2 p2 = myP[j + 2 * EPI + q];
    uint2 p3 = myP[j + 3 * EPI + q];
    const uint4 v0 = *reinterpret_cast<const uint4*>(myx + (size_t)p0.x * RS);
    const uint4 v1 = *reinterpret_cast<const uint4*>(myx + (size_t)p1.x * RS);
    const uint4 v2 = *reinterpret_cast<const uint4*>(myx + (size_t)p2.x * RS);
    const uint4 v3 = *reinterpret_cast<const uint4*>(myx + (size_t)p3.x * RS);
    h16x2 w0 = u2h(p0.y), w1 = u2h(p1.y), w2 = u2h(p2.y), w3 = u2h(p3.y);
    acc2[0] += w0 * u2h(v0.x); acc2[1] += w0 * u2h(v0.y);
    acc2[2] += w0 * u2h(v0.z); acc2[3] += w0 * u2h(v0.w);
    acc2[0] += w1 * u2h(v1.x); acc2[1] += w1 * u2h(v1.y);
    acc2[2] += w1 * u2h(v1.z); acc2[3] += w1 * u2h(v1.w);
    acc2[0] += w2 * u2h(v2.x); acc2[1] += w2 * u2h(v2.y);
    acc2[2] += w2 * u2h(v2.z); acc2[3] += w2 * u2h(v2.w);
    acc2[0] += w3 * u2h(v3.x); acc2[1] += w3 * u2h(v3.y);
    acc2[2] += w3 * u2h(v3.z); acc2[3] += w3 * u2h(v3.w);
  }
  for (; j + EPI <= deg; j += EPI) {
    uint2 p = myP[j + q];
    h16x2 w2 = u2h(p.y);
    const uint4 v = *reinterpret_cast<const uint4*>(myx + (size_t)p.x * RS);
    acc2[0] += w2 * u2h(v.x); acc2[1] += w2 * u2h(v.y);
    acc2[2] += w2 * u2h(v.z); acc2[3] += w2 * u2h(v.w);
  }
  if (j < deg) {
    int jj = j + q;
    int jc = jj < deg ? jj : 0;
    uint2 p = myP[jc];
    h16x2 w2 = u2h(jj < deg ? p.y : 0u);
    const uint4 v = *reinterpret_cast<const uint4*>(myx + (size_t)p.x * RS);
    acc2[0] += w2 * u2h(v.x); acc2[1] += w2 * u2h(v.y);
    acc2[2] += w2 * u2h(v.z); acc2[3] += w2 * u2h(v.w);
  }

  // ---- reduce across edge slots (packed) ----
#pragma unroll
  for (int k = 0; k < 4; ++k) {
    if (LPR == 8) acc2[k] = u2h((uint32)__shfl_xor((int)h2u(acc2[k]), 8)) + acc2[k];
    acc2[k] = u2h((uint32)__shfl_xor((int)h2u(acc2[k]), 16)) + acc2[k];
    acc2[k] = u2h((uint32)__shfl_xor((int)h2u(acc2[k]), 32)) + acc2[k];
  }

  // ---- epilogue: fold 1/denom, bias + ELU + store (first lane group) ----
  if (q == 0) {
    const float invh = hd ? inv1 : inv0;
    float o[8];
#pragma unroll
    for (int k = 0; k < 4; ++k) {
      o[2 * k]     = (float)acc2[k][0] * invh + bias[cc * 8 + 2 * k];
      o[2 * k + 1] = (float)acc2[k][1] * invh + bias[cc * 8 + 2 * k + 1];
    }
#pragma unroll
    for (int k = 0; k < 8; ++k) o[k] = o[k] > 0.f ? o[k] : __expf(o[k]) - 1.f;
    if (OUTF16) {
      uint4 u;
      u.x = pkh(o[0], o[1]); u.y = pkh(o[2], o[3]);
      u.z = pkh(o[4], o[5]); u.w = pkh(o[6], o[7]);
      *reinterpret_cast<uint4*>((uint32*)outp + (size_t)wid * RS + cc * 4) = u;
    } else {
      float* op = (float*)outp + (size_t)wid * HC + cc * 8;
      *reinterpret_cast<float4*>(op)     = make_float4(o[0], o[1], o[2], o[3]);
      *reinterpret_cast<float4*>(op + 4) = make_float4(o[4], o[5], o[6], o[7]);
    }
  }
}

extern "C" void kernel_launch(void* const* d_in, const int* in_sizes, int n_in,
                              void* d_out, int out_size, void* d_ws, size_t ws_size,
                              hipStream_t stream) {
  const float* x      = (const float*)d_in[0];
  const int*   ei     = (const int*)d_in[1];
  const float* W1     = (const float*)d_in[2];
  const float* a_src1 = (const float*)d_in[3];
  const float* a_dst1 = (const float*)d_in[4];
  const float* b1     = (const float*)d_in[5];
  const float* W2     = (const float*)d_in[6];
  const float* a_src2 = (const float*)d_in[7];
  const float* a_dst2 = (const float*)d_in[8];
  const float* b2     = (const float*)d_in[9];
  float* out = (float*)d_out;

  char* ws = (char*)d_ws;
  size_t off = 0;
  auto alloc = [&](size_t bytes) {
    void* p = ws + off;
    off = (off + bytes + 255) & ~(size_t)255;
    return p;
  };
  ushort* xh1       = (ushort*)alloc((size_t)N_NODES * 128 * 2);  // fp16 xp1
  ushort* h1h       = (ushort*)alloc((size_t)N_NODES * 128 * 2);  // fp16 layer-1 output
  ushort* xh2       = (ushort*)alloc((size_t)N_NODES * 64 * 2);   // fp16 xp2
  float*  al1       = (float*)alloc((size_t)N_NODES * 4 * 4);
  float*  al2       = (float*)alloc((size_t)N_NODES * 4 * 4);
  int*    row_start = (int*)alloc((size_t)(N_NODES + 1) * 4);
  int*    bbase     = (int*)alloc(256 * 4);
  int*    bcur      = (int*)alloc(NBUCK * 4);
  int*    sorted_src= (int*)alloc((size_t)EA * 4);
  uint32* ebuf      = (uint32*)h1h;   // alias: h1h not live until agg1; 196*BCAP*4 <= 12.8MB

  const int* src = ei;
  const int* dst = ei + N_EDGES;

  const int waveBlocks = (N_NODES * 64) / 256;
  const int partBlocks = (N_EDGES + EPB - 1) / EPB;
  const int gemmBlocks = (N_NODES + 63) / 64;

  // ---- CSR by destination (two-level scatter, single-read partB) ----
  init_bcur_kernel<<<1, 256, 0, stream>>>(bcur);
  partA_kernel<<<partBlocks, 256, 0, stream>>>(src, dst, bcur, ebuf);
  scan196_kernel<<<1, 256, 0, stream>>>(bcur, bbase, row_start);
  partB2_kernel<<<NBUCK, 256, 0, stream>>>(bcur, bbase, ebuf, row_start, sorted_src);

  // ---- layer 1 (gemm fuses the encoded passthrough copy) ----
  gemm_mfma_kernel<128, false, true><<<gemmBlocks, 256, 0, stream>>>(
      x, W1, a_src1, a_dst1, xh1, al1, out + (size_t)N_NODES * 64, N_NODES);
  agg_kernel<128, true><<<waveBlocks, 256, 0, stream>>>(xh1, al1, row_start, sorted_src, b1, h1h);

  // ---- layer 2 ----
  gemm_mfma_kernel<64, true, false><<<gemmBlocks, 256, 0, stream>>>(
      h1h, W2, a_src2, a_dst2, xh2, al2, nullptr, N_NODES);
  agg_kernel<64, false><<<waveBlocks, 256, 0, stream>>>(xh2, al2, row_start, sorted_src, b2, out);
}